// Round 2
// baseline (3959.045 us; speedup 1.0000x reference)
//
#include <hip/hip_runtime.h>
#include <hip/hip_bf16.h>
#include <hip/hip_fp16.h>
#include <math.h>

#define SEQ 2048
#define DMODEL 1024
#define NH 16
#define DHEAD 64
#define FFDIM 4096
#define NPOSE 128
#define MLPWID 32
#define EPSV 1e-5f
#define CHUNK 512
#define NCH (SEQ / CHUNK)

typedef unsigned short ushort_t;
typedef unsigned int uint_t;
typedef _Float16 f16;

union U2H4 { uint2 u; f16 h[4]; };

__device__ __forceinline__ float sigm(float x) {
    return 1.0f / (1.0f + __expf(-x));
}

// ---------------- RMSNorm: one block per row ----------------
__global__ __launch_bounds__(256) void rmsnorm_k(const float* __restrict__ x,
                                                 const float* __restrict__ w,
                                                 float* __restrict__ o) {
    int row = blockIdx.x;
    int tid = threadIdx.x;
    const float4* xr = (const float4*)(x + (size_t)row * DMODEL);
    float4 v = xr[tid];
    float ss = v.x * v.x + v.y * v.y + v.z * v.z + v.w * v.w;
#pragma unroll
    for (int d = 1; d < 64; d <<= 1) ss += __shfl_xor(ss, d, 64);
    __shared__ float red[4];
    int lane = tid & 63, wv = tid >> 6;
    if (lane == 0) red[wv] = ss;
    __syncthreads();
    float tot = red[0] + red[1] + red[2] + red[3];
    float r = rsqrtf(tot / (float)DMODEL + EPSV);
    const float4* wr = (const float4*)w;
    float4 wv4 = wr[tid];
    float4 out;
    out.x = v.x * r * wv4.x;
    out.y = v.y * r * wv4.y;
    out.z = v.z * r * wv4.z;
    out.w = v.w * r * wv4.w;
    ((float4*)(o + (size_t)row * DMODEL))[tid] = out;
}

// ---------------- generic f32 GEMM: C = A@B (+ add) ----------------
#define GBM 64
#define GBN 64
#define GBK 16
__global__ __launch_bounds__(256) void gemm_nn_k(const float* __restrict__ A,
                                                 const float* __restrict__ B,
                                                 const float* __restrict__ add,
                                                 float* __restrict__ C,
                                                 int M, int N, int K) {
    __shared__ float As[GBM][GBK + 1];
    __shared__ float Bs[GBK][GBN + 1];
    int tid = threadIdx.x;
    int tx = tid & 15, ty = tid >> 4;
    int bm = blockIdx.y * GBM, bn = blockIdx.x * GBN;
    float acc[4][4] = {};
    for (int k0 = 0; k0 < K; k0 += GBK) {
        {
            int idx = tid * 4;
            int r = idx >> 4, c = idx & 15;
            float4 a = *(const float4*)(A + (size_t)(bm + r) * K + k0 + c);
            As[r][c] = a.x; As[r][c + 1] = a.y; As[r][c + 2] = a.z; As[r][c + 3] = a.w;
        }
        {
            int idx = tid * 4;
            int r = idx >> 6, c = idx & 63;
            float4 b = *(const float4*)(B + (size_t)(k0 + r) * N + bn + c);
            Bs[r][c] = b.x; Bs[r][c + 1] = b.y; Bs[r][c + 2] = b.z; Bs[r][c + 3] = b.w;
        }
        __syncthreads();
#pragma unroll
        for (int kk = 0; kk < GBK; kk++) {
            float a[4], b[4];
#pragma unroll
            for (int i = 0; i < 4; i++) a[i] = As[ty * 4 + i][kk];
#pragma unroll
            for (int j = 0; j < 4; j++) b[j] = Bs[kk][tx * 4 + j];
#pragma unroll
            for (int i = 0; i < 4; i++)
#pragma unroll
                for (int j = 0; j < 4; j++) acc[i][j] += a[i] * b[j];
        }
        __syncthreads();
    }
#pragma unroll
    for (int i = 0; i < 4; i++) {
        int r = bm + ty * 4 + i;
#pragma unroll
        for (int j = 0; j < 4; j++) {
            int c = bn + tx * 4 + j;
            float vv = acc[i][j];
            if (add) vv += add[(size_t)r * N + c];
            C[(size_t)r * N + c] = vv;
        }
    }
}

// ---------------- scores (chunk): sc[h][i_local][j] = q_i.k_j/8, f16 ----------------
__global__ __launch_bounds__(256) void scores_k(const float* __restrict__ q,
                                                const float* __restrict__ k,
                                                f16* __restrict__ sc, int cb) {
    int h = blockIdx.z;
    int i0l = blockIdx.y * 64, j0 = blockIdx.x * 64;
    __shared__ float Qs[64][DHEAD + 1];
    __shared__ float Ks[64][DHEAD + 1];
    int tid = threadIdx.x;
    for (int l = tid * 4; l < 4096; l += 1024) {
        int r = l >> 6, c = l & 63;
        float4 a = *(const float4*)(q + (size_t)(cb + i0l + r) * DMODEL + h * DHEAD + c);
        Qs[r][c] = a.x; Qs[r][c + 1] = a.y; Qs[r][c + 2] = a.z; Qs[r][c + 3] = a.w;
        float4 b = *(const float4*)(k + (size_t)(j0 + r) * DMODEL + h * DHEAD + c);
        Ks[r][c] = b.x; Ks[r][c + 1] = b.y; Ks[r][c + 2] = b.z; Ks[r][c + 3] = b.w;
    }
    __syncthreads();
    int tx = tid & 15, ty = tid >> 4;
    float acc[4][4] = {};
#pragma unroll 8
    for (int kk = 0; kk < DHEAD; kk++) {
        float a[4], b[4];
#pragma unroll
        for (int i = 0; i < 4; i++) a[i] = Qs[ty * 4 + i][kk];
#pragma unroll
        for (int j = 0; j < 4; j++) b[j] = Ks[tx * 4 + j][kk];
#pragma unroll
        for (int i = 0; i < 4; i++)
#pragma unroll
            for (int j = 0; j < 4; j++) acc[i][j] += a[i] * b[j];
    }
#pragma unroll
    for (int i = 0; i < 4; i++)
#pragma unroll
        for (int j = 0; j < 4; j++) {
            size_t idx = ((size_t)h * CHUNK + i0l + ty * 4 + i) * SEQ + j0 + tx * 4 + j;
            sc[idx] = (f16)(acc[i][j] * 0.125f);
        }
}

// ---------------- logits_int: li[s][h*128+n] = q_h(s) . pos_emb[:,n] ----------------
__global__ __launch_bounds__(256) void copelogits_k(const float* __restrict__ q,
                                                    const float* __restrict__ pe,
                                                    float* __restrict__ li) {
    int s1 = blockIdx.x;
    int tid = threadIdx.x;
    __shared__ float PE[DHEAD * NPOSE];  // 32KB
    __shared__ float QR[DMODEL];         // 4KB
    for (int i = tid; i < DHEAD * NPOSE; i += 256) PE[i] = pe[i];
    for (int i = tid; i < DMODEL; i += 256) QR[i] = q[(size_t)s1 * DMODEL + i];
    __syncthreads();
#pragma unroll
    for (int j = 0; j < 8; j++) {
        int o = j * 256 + tid;
        int h = o >> 7, n = o & 127;
        const float* qh = &QR[h * DHEAD];
        float acc = 0.0f;
#pragma unroll 8
        for (int d = 0; d < DHEAD; d++) acc += qh[d] * PE[d * NPOSE + n];
        li[(size_t)s1 * (NH * NPOSE) + o] = acc;
    }
}

// ---------------- suffix scan of sigmoid(scores): packed pos -> pw ----------------
// one wave per (h, local row)
__global__ __launch_bounds__(256) void scan_k(const f16* __restrict__ sc,
                                              ushort_t* __restrict__ pw) {
    __shared__ f16 buf[4][SEQ];  // 16KB
    int wv = threadIdx.x >> 6, lane = threadIdx.x & 63;
    int task = blockIdx.x * 4 + wv;  // 0 .. NH*CHUNK-1
    int h = task >> 9;               // CHUNK=512
    int r = task & (CHUNK - 1);
    const uint2* s = (const uint2*)(sc + ((size_t)h * CHUNK + r) * SEQ);
    uint2* d = (uint2*)&buf[wv][0];
    for (int i = lane; i < SEQ / 4; i += 64) d[i] = s[i];
    ushort_t* pdst = pw + ((size_t)h * CHUNK + r) * SEQ;
    float carry = 0.0f;
    for (int c = SEQ / 64 - 1; c >= 0; c--) {
        float sv = (float)buf[wv][c * 64 + lane];
        float g = sigm(sv);
#pragma unroll
        for (int dd = 1; dd < 64; dd <<= 1) {
            float o = __shfl_down(g, dd, 64);
            g = (lane + dd < 64) ? g + o : g;
        }
        float total = __shfl(g, 0, 64);
        float pos = fminf(g + carry, 127.0f);
        carry += total;
        int fl = (int)pos;
        float fr = pos - (float)fl;
        int u9 = (int)(fr * 512.0f);
        if (u9 > 511) u9 = 511;
        pdst[c * 64 + lane] = (ushort_t)((fl << 9) | u9);
    }
}

// ---------------- pointwise MLP over heads; one block per local row ----------------
__global__ __launch_bounds__(256) void mlp_k(f16* __restrict__ sc,
                                             const ushort_t* __restrict__ pw,
                                             const float* __restrict__ li,
                                             const float* __restrict__ w1,
                                             const float* __restrict__ b1,
                                             const float* __restrict__ w2,
                                             const float* __restrict__ b2,
                                             int cb) {
    int r = blockIdx.x;      // local row
    int s1 = cb + r;
    int tid = threadIdx.x;
    __shared__ float Li[NH * NPOSE];       // 8KB
    __shared__ float W1s[2 * NH * MLPWID]; // 4KB
    __shared__ float B1s[MLPWID];
    __shared__ float W2s[MLPWID * NH];     // 2KB
    __shared__ float B2s[NH];
    for (int i = tid; i < NH * NPOSE; i += 256) Li[i] = li[(size_t)s1 * (NH * NPOSE) + i];
    for (int i = tid; i < 2 * NH * MLPWID; i += 256) W1s[i] = w1[i];
    if (tid < MLPWID) B1s[tid] = b1[tid];
    for (int i = tid; i < MLPWID * NH; i += 256) W2s[i] = w2[i];
    if (tid < NH) B2s[tid] = b2[tid];
    __syncthreads();
    for (int j8 = 0; j8 < SEQ / 256; j8++) {
        int t = j8 * 256 + tid;
        float comb[2 * NH];
#pragma unroll
        for (int h = 0; h < NH; h++) {
            size_t idx = ((size_t)h * CHUNK + r) * SEQ + t;
            comb[h] = (float)sc[idx];
            int pk = pw[idx];
            int fl = pk >> 9;
            float w = (float)(pk & 511) * (1.0f / 512.0f);
            float lf = Li[h * NPOSE + fl];
            float lc = Li[h * NPOSE + ((fl < NPOSE - 1) ? fl + 1 : NPOSE - 1)];
            comb[NH + h] = lc * w + lf * (1.0f - w);
        }
        float hm[MLPWID];
#pragma unroll
        for (int j = 0; j < MLPWID; j++) {
            float a = B1s[j];
#pragma unroll
            for (int i = 0; i < 2 * NH; i++) a += comb[i] * W1s[i * MLPWID + j];
            hm[j] = a * sigm(a);
        }
#pragma unroll
        for (int h = 0; h < NH; h++) {
            float dnn = B2s[h];
#pragma unroll
            for (int j = 0; j < MLPWID; j++) dnn += hm[j] * W2s[j * NH + h];
            sc[((size_t)h * CHUNK + r) * SEQ + t] = (f16)(comb[h] + dnn);
        }
    }
}

// ---------------- row max / softmax denom; one wave per (h, local row) ----------------
__global__ __launch_bounds__(256) void rowstat_k(const f16* __restrict__ sc,
                                                 float* __restrict__ rowmax,
                                                 float* __restrict__ rowsum,
                                                 int cb) {
    int wv = threadIdx.x >> 6, lane = threadIdx.x & 63;
    int task = blockIdx.x * 4 + wv;
    int h = task >> 9;
    int r = task & (CHUNK - 1);
    const uint2* s = (const uint2*)(sc + ((size_t)h * CHUNK + r) * SEQ);
    float vals[32];
    float m = -1e30f;
#pragma unroll
    for (int i = 0; i < 8; i++) {
        U2H4 u;
        u.u = s[i * 64 + lane];
#pragma unroll
        for (int j = 0; j < 4; j++) {
            float f = (float)u.h[j];
            vals[i * 4 + j] = f;
            m = fmaxf(m, f);
        }
    }
#pragma unroll
    for (int d = 1; d < 64; d <<= 1) m = fmaxf(m, __shfl_xor(m, d, 64));
    float sum = 0.0f;
#pragma unroll
    for (int i = 0; i < 32; i++) sum += __expf(vals[i] - m);
#pragma unroll
    for (int d = 1; d < 64; d <<= 1) sum += __shfl_xor(sum, d, 64);
    if (lane == 0) {
        rowmax[(size_t)h * SEQ + cb + r] = m;
        rowsum[(size_t)h * SEQ + cb + r] = sum;
    }
}

// ---------------- softmax-normalize + PV ----------------
__global__ __launch_bounds__(256) void pv_k(const f16* __restrict__ sc,
                                            const float* __restrict__ v,
                                            const float* __restrict__ rowmax,
                                            const float* __restrict__ rowsum,
                                            float* __restrict__ ao, int cb) {
    int h = blockIdx.y;
    int s0l = blockIdx.x * 64;
    __shared__ float P[64][65];
    __shared__ float Vt[64][65];
    __shared__ float rm[64];
    __shared__ float ri[64];
    int tid = threadIdx.x;
    int tx = tid & 15, ty = tid >> 4;
    if (tid < 64) {
        rm[tid] = rowmax[(size_t)h * SEQ + cb + s0l + tid];
        ri[tid] = 1.0f / rowsum[(size_t)h * SEQ + cb + s0l + tid];
    }
    __syncthreads();
    float acc[4][4] = {};
    for (int t0 = 0; t0 < SEQ; t0 += 64) {
        for (int l = tid; l < 4096; l += 256) {
            int r = l >> 6, c = l & 63;
            float lg = (float)sc[((size_t)h * CHUNK + s0l + r) * SEQ + t0 + c];
            P[r][c] = __expf(lg - rm[r]) * ri[r];
            Vt[r][c] = v[(size_t)(t0 + r) * DMODEL + h * DHEAD + c];
        }
        __syncthreads();
#pragma unroll 8
        for (int kk = 0; kk < 64; kk++) {
            float a[4], b[4];
#pragma unroll
            for (int i = 0; i < 4; i++) a[i] = P[ty * 4 + i][kk];
#pragma unroll
            for (int j = 0; j < 4; j++) b[j] = Vt[kk][tx * 4 + j];
#pragma unroll
            for (int i = 0; i < 4; i++)
#pragma unroll
                for (int j = 0; j < 4; j++) acc[i][j] += a[i] * b[j];
        }
        __syncthreads();
    }
#pragma unroll
    for (int i = 0; i < 4; i++)
#pragma unroll
        for (int j = 0; j < 4; j++)
            ao[(size_t)(cb + s0l + ty * 4 + i) * DMODEL + h * DHEAD + tx * 4 + j] = acc[i][j];
}

// ---------------- silu(g1)*g3 elementwise ----------------
__global__ __launch_bounds__(256) void silumul_k(float* __restrict__ g1,
                                                 const float* __restrict__ g3) {
    int i = blockIdx.x * 256 + threadIdx.x;
    float4 a = ((const float4*)g1)[i];
    float4 b = ((const float4*)g3)[i];
    a.x = a.x * sigm(a.x) * b.x;
    a.y = a.y * sigm(a.y) * b.y;
    a.z = a.z * sigm(a.z) * b.z;
    a.w = a.w * sigm(a.w) * b.w;
    ((float4*)g1)[i] = a;
}

extern "C" void kernel_launch(void* const* d_in, const int* in_sizes, int n_in,
                              void* d_out, int out_size, void* d_ws, size_t ws_size,
                              hipStream_t stream) {
    const float* x = (const float*)d_in[0];
    const float* wq = (const float*)d_in[1];
    const float* wk = (const float*)d_in[2];
    const float* wv = (const float*)d_in[3];
    const float* wo = (const float*)d_in[4];
    const float* pos_emb = (const float*)d_in[5];
    const float* mlp_w1 = (const float*)d_in[6];
    const float* mlp_b1 = (const float*)d_in[7];
    const float* mlp_w2 = (const float*)d_in[8];
    const float* mlp_b2 = (const float*)d_in[9];
    const float* ffn_w1 = (const float*)d_in[10];
    const float* ffn_w2 = (const float*)d_in[11];
    const float* ffn_w3 = (const float*)d_in[12];
    const float* attn_norm_w = (const float*)d_in[13];
    const float* ffn_norm_w = (const float*)d_in[14];
    float* out = (float*)d_out;

    char* ws = (char*)d_ws;
    const size_t MB = 1024 * 1024;
    float* nx = (float*)(ws + 0);              // 8MB  (reused for ffn norm)
    float* q = (float*)(ws + 8 * MB);          // 8MB
    float* k = (float*)(ws + 16 * MB);         // 8MB
    float* v = (float*)(ws + 24 * MB);         // 8MB  (reused as x1 after attention)
    float* li = (float*)(ws + 32 * MB);        // 16MB
    f16* sc = (f16*)(ws + 48 * MB);            // 32MB (per-chunk scores/logits)
    ushort_t* pw = (ushort_t*)(ws + 80 * MB);  // 32MB (packed pos)
    float* rowmax = (float*)(ws + 112 * MB);   // 128KB
    float* rowsum = (float*)(ws + 113 * MB);   // 128KB
    float* ao = (float*)(ws + 114 * MB);       // 8MB   -> peak 122MB
    float* x1 = (float*)(ws + 24 * MB);        // reuse v region
    float* g1 = (float*)(ws + 32 * MB);        // 32MB (reuse li/sc after attention)
    float* g3 = (float*)(ws + 64 * MB);        // 32MB (reuse sc/pw after attention)

    // 1. attn rmsnorm
    rmsnorm_k<<<SEQ, 256, 0, stream>>>(x, attn_norm_w, nx);
    // 2. QKV
    dim3 gqkv(DMODEL / GBN, SEQ / GBM);
    gemm_nn_k<<<gqkv, 256, 0, stream>>>(nx, wq, nullptr, q, SEQ, DMODEL, DMODEL);
    gemm_nn_k<<<gqkv, 256, 0, stream>>>(nx, wk, nullptr, k, SEQ, DMODEL, DMODEL);
    gemm_nn_k<<<gqkv, 256, 0, stream>>>(nx, wv, nullptr, v, SEQ, DMODEL, DMODEL);
    // 3. cope interp logits (all rows)
    copelogits_k<<<SEQ, 256, 0, stream>>>(q, pos_emb, li);
    // 4. per-chunk attention pipeline
    for (int ch = 0; ch < NCH; ch++) {
        int cb = ch * CHUNK;
        scores_k<<<dim3(SEQ / 64, CHUNK / 64, NH), 256, 0, stream>>>(q, k, sc, cb);
        scan_k<<<NH * CHUNK / 4, 256, 0, stream>>>(sc, pw);
        mlp_k<<<CHUNK, 256, 0, stream>>>(sc, pw, li, mlp_w1, mlp_b1, mlp_w2, mlp_b2, cb);
        rowstat_k<<<NH * CHUNK / 4, 256, 0, stream>>>(sc, rowmax, rowsum, cb);
        pv_k<<<dim3(CHUNK / 64, NH), 256, 0, stream>>>(sc, v, rowmax, rowsum, ao, cb);
    }
    // 5. out @ wo + x -> x1
    gemm_nn_k<<<gqkv, 256, 0, stream>>>(ao, wo, x, x1, SEQ, DMODEL, DMODEL);
    // 6. ffn rmsnorm
    rmsnorm_k<<<SEQ, 256, 0, stream>>>(x1, ffn_norm_w, nx);
    // 7. ffn
    dim3 gff1(FFDIM / GBN, SEQ / GBM);
    gemm_nn_k<<<gff1, 256, 0, stream>>>(nx, ffn_w1, nullptr, g1, SEQ, FFDIM, DMODEL);
    gemm_nn_k<<<gff1, 256, 0, stream>>>(nx, ffn_w3, nullptr, g3, SEQ, FFDIM, DMODEL);
    silumul_k<<<(SEQ * FFDIM / 4) / 256, 256, 0, stream>>>(g1, g3);
    gemm_nn_k<<<gqkv, 256, 0, stream>>>(g1, ffn_w2, x1, out, SEQ, DMODEL, FFDIM);
}

// Round 3
// 2838.620 us; speedup vs baseline: 1.3947x; 1.3947x over previous
//
#include <hip/hip_runtime.h>
#include <hip/hip_bf16.h>
#include <hip/hip_fp16.h>
#include <math.h>

#define SEQ 2048
#define DMODEL 1024
#define NH 16
#define DHEAD 64
#define FFDIM 4096
#define NPOSE 128
#define MLPWID 32
#define EPSV 1e-5f
#define CHUNK 512
#define NCH (SEQ / CHUNK)

typedef unsigned short ushort_t;
typedef unsigned int uint_t;
typedef _Float16 f16;
typedef __attribute__((ext_vector_type(8))) short bf16x8;
typedef __attribute__((ext_vector_type(4))) float f32x4;

union U2H4 { uint2 u; f16 h[4]; };
union U4S8 { uint4 u; ushort_t s[8]; };

__device__ __forceinline__ float sigm(float x) {
    return 1.0f / (1.0f + __expf(-x));
}
__device__ __forceinline__ ushort_t f2bf(float f) {
    uint_t u = __float_as_uint(f);
    u += 0x7fffu + ((u >> 16) & 1u);
    return (ushort_t)(u >> 16);
}
__device__ __forceinline__ float bf2f(ushort_t u) {
    return __uint_as_float(((uint_t)u) << 16);
}
__device__ __forceinline__ void gl_lds16(const void* g, void* l) {
    __builtin_amdgcn_global_load_lds((const __attribute__((address_space(1))) uint_t*)g,
                                     (__attribute__((address_space(3))) uint_t*)l, 16, 0, 0);
}

// ---------------- RMSNorm ----------------
__global__ __launch_bounds__(256) void rmsnorm_k(const float* __restrict__ x,
                                                 const float* __restrict__ w,
                                                 float* __restrict__ o) {
    int row = blockIdx.x;
    int tid = threadIdx.x;
    const float4* xr = (const float4*)(x + (size_t)row * DMODEL);
    float4 v = xr[tid];
    float ss = v.x * v.x + v.y * v.y + v.z * v.z + v.w * v.w;
#pragma unroll
    for (int d = 1; d < 64; d <<= 1) ss += __shfl_xor(ss, d, 64);
    __shared__ float red[4];
    int lane = tid & 63, wv = tid >> 6;
    if (lane == 0) red[wv] = ss;
    __syncthreads();
    float tot = red[0] + red[1] + red[2] + red[3];
    float r = rsqrtf(tot / (float)DMODEL + EPSV);
    const float4* wr = (const float4*)w;
    float4 wv4 = wr[tid];
    float4 out;
    out.x = v.x * r * wv4.x;
    out.y = v.y * r * wv4.y;
    out.z = v.z * r * wv4.z;
    out.w = v.w * r * wv4.w;
    ((float4*)(o + (size_t)row * DMODEL))[tid] = out;
}

// ---------------- f32 -> bf16 convert (8 elems/thread) ----------------
__global__ __launch_bounds__(256) void convbf_k(const float* __restrict__ in,
                                                ushort_t* __restrict__ out) {
    int i = blockIdx.x * 256 + threadIdx.x;
    float4 a = ((const float4*)in)[i * 2];
    float4 b = ((const float4*)in)[i * 2 + 1];
    U4S8 o;
    o.s[0] = f2bf(a.x); o.s[1] = f2bf(a.y); o.s[2] = f2bf(a.z); o.s[3] = f2bf(a.w);
    o.s[4] = f2bf(b.x); o.s[5] = f2bf(b.y); o.s[6] = f2bf(b.z); o.s[7] = f2bf(b.w);
    ((uint4*)out)[i] = o.u;
}

// ---------------- weight transpose+convert: f32[K][N] -> bf16[N][K] ----------------
__global__ __launch_bounds__(256) void transconv_k(const float* __restrict__ in,
                                                   ushort_t* __restrict__ out,
                                                   int K, int N) {
    __shared__ ushort_t T[64][72];
    int k0 = blockIdx.y * 64, n0 = blockIdx.x * 64;
    int tid = threadIdx.x;
    int r = tid >> 4, c4 = (tid & 15) * 4;
#pragma unroll
    for (int i = 0; i < 4; i++) {
        float4 v = *(const float4*)(in + (size_t)(k0 + r + i * 16) * N + n0 + c4);
        T[c4 + 0][r + i * 16] = f2bf(v.x);
        T[c4 + 1][r + i * 16] = f2bf(v.y);
        T[c4 + 2][r + i * 16] = f2bf(v.z);
        T[c4 + 3][r + i * 16] = f2bf(v.w);
    }
    __syncthreads();
    int n = tid >> 2, kk = (tid & 3) * 16;
    U4S8 o0, o1;
#pragma unroll
    for (int i = 0; i < 8; i++) { o0.s[i] = T[n][kk + i]; o1.s[i] = T[n][kk + 8 + i]; }
    uint4* dst = (uint4*)(out + (size_t)(n0 + n) * K + k0 + kk);
    dst[0] = o0.u;
    dst[1] = o1.u;
}

// ---------------- bf16 MFMA GEMM (TN): C[M][N] = A[M][K] @ Bt[N][K]^T (+add) ----------------
// grid (N/128, M/128), block 256 (4 waves, each 64x64)
__global__ __launch_bounds__(256) void gemm_bf16_k(const ushort_t* __restrict__ A,
                                                   const ushort_t* __restrict__ Bt,
                                                   const float* __restrict__ add,
                                                   void* __restrict__ Cout,
                                                   int M, int N, int K, int out_bf16) {
    __shared__ ushort_t Al[128 * 32];
    __shared__ ushort_t Bl[128 * 32];
    int tid = threadIdx.x;
    int lane = tid & 63, wave = tid >> 6;
    int brow = blockIdx.y * 128, bcol = blockIdx.x * 128;
    int wr = (wave >> 1) * 64, wc = (wave & 1) * 64;
    f32x4 acc[4][4];
#pragma unroll
    for (int m = 0; m < 4; m++)
#pragma unroll
        for (int n = 0; n < 4; n++) acc[m][n] = (f32x4){0.f, 0.f, 0.f, 0.f};

    const ushort_t* Ag = A + (size_t)(brow + (tid >> 2)) * K + (tid & 3) * 8;
    const ushort_t* Bg = Bt + (size_t)(bcol + (tid >> 2)) * K + (tid & 3) * 8;
    ushort_t* Ald = &Al[wave * 512];
    ushort_t* Bld = &Bl[wave * 512];
    size_t rstep = (size_t)64 * K;

    for (int k0 = 0; k0 < K; k0 += 32) {
        gl_lds16(Ag + k0, Ald);
        gl_lds16(Ag + k0 + rstep, Ald + 2048);
        gl_lds16(Bg + k0, Bld);
        gl_lds16(Bg + k0 + rstep, Bld + 2048);
        __syncthreads();
        bf16x8 af[4], bfr[4];
        int arow = wr + (lane & 15);
        int brw = wc + (lane & 15);
        int kof = (lane >> 4) * 8;
#pragma unroll
        for (int m = 0; m < 4; m++) af[m] = *(const bf16x8*)&Al[(arow + m * 16) * 32 + kof];
#pragma unroll
        for (int n = 0; n < 4; n++) bfr[n] = *(const bf16x8*)&Bl[(brw + n * 16) * 32 + kof];
#pragma unroll
        for (int m = 0; m < 4; m++)
#pragma unroll
            for (int n = 0; n < 4; n++)
                acc[m][n] = __builtin_amdgcn_mfma_f32_16x16x32_bf16(af[m], bfr[n], acc[m][n], 0, 0, 0);
        __syncthreads();
    }
    int crow0 = brow + wr + (lane >> 4) * 4;
    int ccol = bcol + wc + (lane & 15);
#pragma unroll
    for (int m = 0; m < 4; m++)
#pragma unroll
        for (int j = 0; j < 4; j++) {
            int row = crow0 + m * 16 + j;
#pragma unroll
            for (int n = 0; n < 4; n++) {
                int col = ccol + n * 16;
                float v = acc[m][n][j];
                if (add) v += add[(size_t)row * N + col];
                if (out_bf16) ((ushort_t*)Cout)[(size_t)row * N + col] = f2bf(v);
                else ((float*)Cout)[(size_t)row * N + col] = v;
            }
        }
}

// ---------------- scores (chunk): sc[h][i_local][j] = q_i.k_j/8, f16 ----------------
__global__ __launch_bounds__(256) void scores_k(const float* __restrict__ q,
                                                const float* __restrict__ k,
                                                f16* __restrict__ sc, int cb) {
    int h = blockIdx.z;
    int i0l = blockIdx.y * 64, j0 = blockIdx.x * 64;
    __shared__ float Qs[64][DHEAD + 1];
    __shared__ float Ks[64][DHEAD + 1];
    int tid = threadIdx.x;
    for (int l = tid * 4; l < 4096; l += 1024) {
        int r = l >> 6, c = l & 63;
        float4 a = *(const float4*)(q + (size_t)(cb + i0l + r) * DMODEL + h * DHEAD + c);
        Qs[r][c] = a.x; Qs[r][c + 1] = a.y; Qs[r][c + 2] = a.z; Qs[r][c + 3] = a.w;
        float4 b = *(const float4*)(k + (size_t)(j0 + r) * DMODEL + h * DHEAD + c);
        Ks[r][c] = b.x; Ks[r][c + 1] = b.y; Ks[r][c + 2] = b.z; Ks[r][c + 3] = b.w;
    }
    __syncthreads();
    int tx = tid & 15, ty = tid >> 4;
    float acc[4][4] = {};
#pragma unroll 8
    for (int kk = 0; kk < DHEAD; kk++) {
        float a[4], b[4];
#pragma unroll
        for (int i = 0; i < 4; i++) a[i] = Qs[ty * 4 + i][kk];
#pragma unroll
        for (int j = 0; j < 4; j++) b[j] = Ks[tx * 4 + j][kk];
#pragma unroll
        for (int i = 0; i < 4; i++)
#pragma unroll
            for (int j = 0; j < 4; j++) acc[i][j] += a[i] * b[j];
    }
#pragma unroll
    for (int i = 0; i < 4; i++)
#pragma unroll
        for (int j = 0; j < 4; j++) {
            size_t idx = ((size_t)h * CHUNK + i0l + ty * 4 + i) * SEQ + j0 + tx * 4 + j;
            sc[idx] = (f16)(acc[i][j] * 0.125f);
        }
}

// ---------------- logits_int -> f16: li[s][h*128+n] = q_h(s).pos_emb[:,n] ----------------
__global__ __launch_bounds__(256) void copelogits_k(const float* __restrict__ q,
                                                    const float* __restrict__ pe,
                                                    f16* __restrict__ li) {
    int s1 = blockIdx.x;
    int tid = threadIdx.x;
    __shared__ float PE[DHEAD * NPOSE];
    __shared__ float QR[DMODEL];
    for (int i = tid; i < DHEAD * NPOSE; i += 256) PE[i] = pe[i];
    for (int i = tid; i < DMODEL; i += 256) QR[i] = q[(size_t)s1 * DMODEL + i];
    __syncthreads();
#pragma unroll
    for (int j = 0; j < 8; j++) {
        int o = j * 256 + tid;
        int h = o >> 7, n = o & 127;
        const float* qh = &QR[h * DHEAD];
        float acc = 0.0f;
#pragma unroll 8
        for (int d = 0; d < DHEAD; d++) acc += qh[d] * PE[d * NPOSE + n];
        li[(size_t)s1 * (NH * NPOSE) + o] = (f16)acc;
    }
}

// ---------------- suffix scan: packed pos -> pw ----------------
__global__ __launch_bounds__(256) void scan_k(const f16* __restrict__ sc,
                                              ushort_t* __restrict__ pw) {
    __shared__ f16 buf[4][SEQ];
    int wv = threadIdx.x >> 6, lane = threadIdx.x & 63;
    int task = blockIdx.x * 4 + wv;
    int h = task >> 9;
    int r = task & (CHUNK - 1);
    const uint2* s = (const uint2*)(sc + ((size_t)h * CHUNK + r) * SEQ);
    uint2* d = (uint2*)&buf[wv][0];
    for (int i = lane; i < SEQ / 4; i += 64) d[i] = s[i];
    ushort_t* pdst = pw + ((size_t)h * CHUNK + r) * SEQ;
    float carry = 0.0f;
    for (int c = SEQ / 64 - 1; c >= 0; c--) {
        float sv = (float)buf[wv][c * 64 + lane];
        float g = sigm(sv);
#pragma unroll
        for (int dd = 1; dd < 64; dd <<= 1) {
            float o = __shfl_down(g, dd, 64);
            g = (lane + dd < 64) ? g + o : g;
        }
        float total = __shfl(g, 0, 64);
        float pos = fminf(g + carry, 127.0f);
        carry += total;
        int fl = (int)pos;
        float fr = pos - (float)fl;
        int u9 = (int)(fr * 512.0f);
        if (u9 > 511) u9 = 511;
        pdst[c * 64 + lane] = (ushort_t)((fl << 9) | u9);
    }
}

// ---------------- pointwise MLP over heads ----------------
__global__ __launch_bounds__(256) void mlp_k(f16* __restrict__ sc,
                                             const ushort_t* __restrict__ pw,
                                             const f16* __restrict__ li,
                                             const float* __restrict__ w1,
                                             const float* __restrict__ b1,
                                             const float* __restrict__ w2,
                                             const float* __restrict__ b2,
                                             int cb) {
    int r = blockIdx.x;
    int s1 = cb + r;
    int tid = threadIdx.x;
    __shared__ float Li[NH * NPOSE];
    __shared__ float W1s[2 * NH * MLPWID];
    __shared__ float B1s[MLPWID];
    __shared__ float W2s[MLPWID * NH];
    __shared__ float B2s[NH];
    for (int i = tid; i < NH * NPOSE; i += 256) Li[i] = (float)li[(size_t)s1 * (NH * NPOSE) + i];
    for (int i = tid; i < 2 * NH * MLPWID; i += 256) W1s[i] = w1[i];
    if (tid < MLPWID) B1s[tid] = b1[tid];
    for (int i = tid; i < MLPWID * NH; i += 256) W2s[i] = w2[i];
    if (tid < NH) B2s[tid] = b2[tid];
    __syncthreads();
    for (int j8 = 0; j8 < SEQ / 256; j8++) {
        int t = j8 * 256 + tid;
        float comb[2 * NH];
#pragma unroll
        for (int h = 0; h < NH; h++) {
            size_t idx = ((size_t)h * CHUNK + r) * SEQ + t;
            comb[h] = (float)sc[idx];
            int pk = pw[idx];
            int fl = pk >> 9;
            float w = (float)(pk & 511) * (1.0f / 512.0f);
            float lf = Li[h * NPOSE + fl];
            float lc = Li[h * NPOSE + ((fl < NPOSE - 1) ? fl + 1 : NPOSE - 1)];
            comb[NH + h] = lc * w + lf * (1.0f - w);
        }
        float hm[MLPWID];
#pragma unroll
        for (int j = 0; j < MLPWID; j++) {
            float a = B1s[j];
#pragma unroll
            for (int i = 0; i < 2 * NH; i++) a += comb[i] * W1s[i * MLPWID + j];
            hm[j] = a * sigm(a);
        }
#pragma unroll
        for (int h = 0; h < NH; h++) {
            float dnn = B2s[h];
#pragma unroll
            for (int j = 0; j < MLPWID; j++) dnn += hm[j] * W2s[j * NH + h];
            sc[((size_t)h * CHUNK + r) * SEQ + t] = (f16)(comb[h] + dnn);
        }
    }
}

// ---------------- row max / softmax denom ----------------
__global__ __launch_bounds__(256) void rowstat_k(const f16* __restrict__ sc,
                                                 float* __restrict__ rowmax,
                                                 float* __restrict__ rowsum,
                                                 int cb) {
    int wv = threadIdx.x >> 6, lane = threadIdx.x & 63;
    int task = blockIdx.x * 4 + wv;
    int h = task >> 9;
    int r = task & (CHUNK - 1);
    const uint2* s = (const uint2*)(sc + ((size_t)h * CHUNK + r) * SEQ);
    float vals[32];
    float m = -1e30f;
#pragma unroll
    for (int i = 0; i < 8; i++) {
        U2H4 u;
        u.u = s[i * 64 + lane];
#pragma unroll
        for (int j = 0; j < 4; j++) {
            float f = (float)u.h[j];
            vals[i * 4 + j] = f;
            m = fmaxf(m, f);
        }
    }
#pragma unroll
    for (int d = 1; d < 64; d <<= 1) m = fmaxf(m, __shfl_xor(m, d, 64));
    float sum = 0.0f;
#pragma unroll
    for (int i = 0; i < 32; i++) sum += __expf(vals[i] - m);
#pragma unroll
    for (int d = 1; d < 64; d <<= 1) sum += __shfl_xor(sum, d, 64);
    if (lane == 0) {
        rowmax[(size_t)h * SEQ + cb + r] = m;
        rowsum[(size_t)h * SEQ + cb + r] = sum;
    }
}

// ---------------- softmax-normalize + PV ----------------
__global__ __launch_bounds__(256) void pv_k(const f16* __restrict__ sc,
                                            const float* __restrict__ v,
                                            const float* __restrict__ rowmax,
                                            const float* __restrict__ rowsum,
                                            float* __restrict__ ao, int cb) {
    int h = blockIdx.y;
    int s0l = blockIdx.x * 64;
    __shared__ float P[64][65];
    __shared__ float Vt[64][65];
    __shared__ float rm[64];
    __shared__ float ri[64];
    int tid = threadIdx.x;
    int tx = tid & 15, ty = tid >> 4;
    if (tid < 64) {
        rm[tid] = rowmax[(size_t)h * SEQ + cb + s0l + tid];
        ri[tid] = 1.0f / rowsum[(size_t)h * SEQ + cb + s0l + tid];
    }
    __syncthreads();
    float acc[4][4] = {};
    for (int t0 = 0; t0 < SEQ; t0 += 64) {
        for (int l = tid; l < 4096; l += 256) {
            int r = l >> 6, c = l & 63;
            float lg = (float)sc[((size_t)h * CHUNK + s0l + r) * SEQ + t0 + c];
            P[r][c] = __expf(lg - rm[r]) * ri[r];
            Vt[r][c] = v[(size_t)(t0 + r) * DMODEL + h * DHEAD + c];
        }
        __syncthreads();
#pragma unroll 8
        for (int kk = 0; kk < 64; kk++) {
            float a[4], b[4];
#pragma unroll
            for (int i = 0; i < 4; i++) a[i] = P[ty * 4 + i][kk];
#pragma unroll
            for (int j = 0; j < 4; j++) b[j] = Vt[kk][tx * 4 + j];
#pragma unroll
            for (int i = 0; i < 4; i++)
#pragma unroll
                for (int j = 0; j < 4; j++) acc[i][j] += a[i] * b[j];
        }
        __syncthreads();
    }
#pragma unroll
    for (int i = 0; i < 4; i++)
#pragma unroll
        for (int j = 0; j < 4; j++)
            ao[(size_t)(cb + s0l + ty * 4 + i) * DMODEL + h * DHEAD + tx * 4 + j] = acc[i][j];
}

// ---------------- silu(g1)*g3, bf16 in/out (in place over g1) ----------------
__global__ __launch_bounds__(256) void silumul_bf_k(ushort_t* __restrict__ g1,
                                                    const ushort_t* __restrict__ g3) {
    int i = blockIdx.x * 256 + threadIdx.x;
    U4S8 a, b, o;
    a.u = ((const uint4*)g1)[i];
    b.u = ((const uint4*)g3)[i];
#pragma unroll
    for (int j = 0; j < 8; j++) {
        float x = bf2f(a.s[j]);
        float y = bf2f(b.s[j]);
        o.s[j] = f2bf(x * sigm(x) * y);
    }
    ((uint4*)g1)[i] = o.u;
}

extern "C" void kernel_launch(void* const* d_in, const int* in_sizes, int n_in,
                              void* d_out, int out_size, void* d_ws, size_t ws_size,
                              hipStream_t stream) {
    const float* x = (const float*)d_in[0];
    const float* wq = (const float*)d_in[1];
    const float* wk = (const float*)d_in[2];
    const float* wv = (const float*)d_in[3];
    const float* wo = (const float*)d_in[4];
    const float* pos_emb = (const float*)d_in[5];
    const float* mlp_w1 = (const float*)d_in[6];
    const float* mlp_b1 = (const float*)d_in[7];
    const float* mlp_w2 = (const float*)d_in[8];
    const float* mlp_b2 = (const float*)d_in[9];
    const float* ffn_w1 = (const float*)d_in[10];
    const float* ffn_w2 = (const float*)d_in[11];
    const float* ffn_w3 = (const float*)d_in[12];
    const float* attn_norm_w = (const float*)d_in[13];
    const float* ffn_norm_w = (const float*)d_in[14];
    float* out = (float*)d_out;

    char* ws = (char*)d_ws;
    const size_t MB = 1024 * 1024;
    float* nx = (float*)(ws + 0);                   // 8MB
    float* q = (float*)(ws + 8 * MB);               // 8MB
    float* k = (float*)(ws + 16 * MB);              // 8MB
    float* v = (float*)(ws + 24 * MB);              // 8MB (x1 after attention)
    ushort_t* nxb = (ushort_t*)(ws + 32 * MB);      // 4MB bf16
    f16* li = (f16*)(ws + 36 * MB);                 // 8MB f16
    float* rowmax = (float*)(ws + 44 * MB);         // 128KB
    float* rowsum = (float*)(ws + 44 * MB + 512 * 1024);
    float* ao = (float*)(ws + 45 * MB);             // 8MB
    // phase 1 weights
    ushort_t* wqt = (ushort_t*)(ws + 53 * MB);      // 2MB
    ushort_t* wkt = (ushort_t*)(ws + 55 * MB);
    ushort_t* wvt = (ushort_t*)(ws + 57 * MB);
    // phase 2 (overwrites wqt..)
    f16* sc = (f16*)(ws + 53 * MB);                 // 32MB
    ushort_t* pw = (ushort_t*)(ws + 85 * MB);       // 32MB -> top 117MB
    // phase B/C (over sc/pw, after attention)
    ushort_t* wot = (ushort_t*)(ws + 53 * MB);      // 2MB
    ushort_t* aob = (ushort_t*)(ws + 57 * MB);      // 4MB
    ushort_t* w1t = (ushort_t*)(ws + 61 * MB);      // 8MB
    ushort_t* w3t = (ushort_t*)(ws + 69 * MB);      // 8MB
    ushort_t* w2t = (ushort_t*)(ws + 77 * MB);      // 8MB
    ushort_t* g1b = (ushort_t*)(ws + 85 * MB);      // 16MB
    ushort_t* g3b = (ushort_t*)(ws + 101 * MB);     // 16MB -> top 117MB
    float* x1 = (float*)(ws + 24 * MB);

    // ---- phase 1: norms + QKV ----
    transconv_k<<<dim3(DMODEL / 64, DMODEL / 64), 256, 0, stream>>>(wq, wqt, DMODEL, DMODEL);
    transconv_k<<<dim3(DMODEL / 64, DMODEL / 64), 256, 0, stream>>>(wk, wkt, DMODEL, DMODEL);
    transconv_k<<<dim3(DMODEL / 64, DMODEL / 64), 256, 0, stream>>>(wv, wvt, DMODEL, DMODEL);
    rmsnorm_k<<<SEQ, 256, 0, stream>>>(x, attn_norm_w, nx);
    convbf_k<<<SEQ * DMODEL / 8 / 256, 256, 0, stream>>>(nx, nxb);
    dim3 gqkv(DMODEL / 128, SEQ / 128);
    gemm_bf16_k<<<gqkv, 256, 0, stream>>>(nxb, wqt, nullptr, q, SEQ, DMODEL, DMODEL, 0);
    gemm_bf16_k<<<gqkv, 256, 0, stream>>>(nxb, wkt, nullptr, k, SEQ, DMODEL, DMODEL, 0);
    gemm_bf16_k<<<gqkv, 256, 0, stream>>>(nxb, wvt, nullptr, v, SEQ, DMODEL, DMODEL, 0);
    copelogits_k<<<SEQ, 256, 0, stream>>>(q, pos_emb, li);

    // ---- phase 2: attention chunks ----
    for (int ch = 0; ch < NCH; ch++) {
        int cb = ch * CHUNK;
        scores_k<<<dim3(SEQ / 64, CHUNK / 64, NH), 256, 0, stream>>>(q, k, sc, cb);
        scan_k<<<NH * CHUNK / 4, 256, 0, stream>>>(sc, pw);
        mlp_k<<<CHUNK, 256, 0, stream>>>(sc, pw, li, mlp_w1, mlp_b1, mlp_w2, mlp_b2, cb);
        rowstat_k<<<NH * CHUNK / 4, 256, 0, stream>>>(sc, rowmax, rowsum, cb);
        pv_k<<<dim3(CHUNK / 64, NH), 256, 0, stream>>>(sc, v, rowmax, rowsum, ao, cb);
    }

    // ---- phase B: out @ wo + x ----
    transconv_k<<<dim3(DMODEL / 64, DMODEL / 64), 256, 0, stream>>>(wo, wot, DMODEL, DMODEL);
    convbf_k<<<SEQ * DMODEL / 8 / 256, 256, 0, stream>>>(ao, aob);
    gemm_bf16_k<<<gqkv, 256, 0, stream>>>(aob, wot, x, x1, SEQ, DMODEL, DMODEL, 0);

    // ---- phase C: FFN ----
    rmsnorm_k<<<SEQ, 256, 0, stream>>>(x1, ffn_norm_w, nx);
    convbf_k<<<SEQ * DMODEL / 8 / 256, 256, 0, stream>>>(nx, nxb);
    transconv_k<<<dim3(FFDIM / 64, DMODEL / 64), 256, 0, stream>>>(ffn_w1, w1t, DMODEL, FFDIM);
    transconv_k<<<dim3(FFDIM / 64, DMODEL / 64), 256, 0, stream>>>(ffn_w3, w3t, DMODEL, FFDIM);
    transconv_k<<<dim3(DMODEL / 64, FFDIM / 64), 256, 0, stream>>>(ffn_w2, w2t, FFDIM, DMODEL);
    dim3 gff(FFDIM / 128, SEQ / 128);
    gemm_bf16_k<<<gff, 256, 0, stream>>>(nxb, w1t, nullptr, g1b, SEQ, FFDIM, DMODEL, 1);
    gemm_bf16_k<<<gff, 256, 0, stream>>>(nxb, w3t, nullptr, g3b, SEQ, FFDIM, DMODEL, 1);
    silumul_bf_k<<<SEQ * FFDIM / 8 / 256, 256, 0, stream>>>(g1b, g3b);
    gemm_bf16_k<<<gqkv, 256, 0, stream>>>(g1b, w2t, x1, out, SEQ, DMODEL, FFDIM, 0);
}

// Round 6
// 1679.730 us; speedup vs baseline: 2.3570x; 1.6899x over previous
//
#include <hip/hip_runtime.h>
#include <hip/hip_bf16.h>
#include <hip/hip_fp16.h>
#include <math.h>

#define SEQ 2048
#define DMODEL 1024
#define NH 16
#define DHEAD 64
#define FFDIM 4096
#define NPOSE 128
#define MLPWID 32
#define EPSV 1e-5f
#define CHUNK 1024
#define NCH (SEQ / CHUNK)

typedef unsigned short ushort_t;
typedef unsigned int uint_t;
typedef _Float16 f16;
typedef __attribute__((ext_vector_type(8))) short bf16x8;
typedef __attribute__((ext_vector_type(4))) float f32x4;

union U2H4 { uint2 u; f16 h[4]; };
union U4S8 { uint4 u; ushort_t s[8]; };
union BF8 { bf16x8 v; ushort_t s[8]; uint2 u2[2]; };
union U1H2 { uint_t u; f16 h[2]; };

__device__ __forceinline__ float sigm(float x) {
    return 1.0f / (1.0f + __expf(-x));
}
__device__ __forceinline__ ushort_t f2bf(float f) {
    uint_t u = __float_as_uint(f);
    u += 0x7fffu + ((u >> 16) & 1u);
    return (ushort_t)(u >> 16);
}
__device__ __forceinline__ float bf2f(ushort_t u) {
    return __uint_as_float(((uint_t)u) << 16);
}
__device__ __forceinline__ void gl_lds16(const void* g, void* l) {
    __builtin_amdgcn_global_load_lds((const __attribute__((address_space(1))) uint_t*)g,
                                     (__attribute__((address_space(3))) uint_t*)l, 16, 0, 0);
}

// ---------------- RMSNorm ----------------
__global__ __launch_bounds__(256) void rmsnorm_k(const float* __restrict__ x,
                                                 const float* __restrict__ w,
                                                 float* __restrict__ o) {
    int row = blockIdx.x;
    int tid = threadIdx.x;
    const float4* xr = (const float4*)(x + (size_t)row * DMODEL);
    float4 v = xr[tid];
    float ss = v.x * v.x + v.y * v.y + v.z * v.z + v.w * v.w;
#pragma unroll
    for (int d = 1; d < 64; d <<= 1) ss += __shfl_xor(ss, d, 64);
    __shared__ float red[4];
    int lane = tid & 63, wv = tid >> 6;
    if (lane == 0) red[wv] = ss;
    __syncthreads();
    float tot = red[0] + red[1] + red[2] + red[3];
    float r = rsqrtf(tot / (float)DMODEL + EPSV);
    const float4* wr = (const float4*)w;
    float4 wv4 = wr[tid];
    float4 out;
    out.x = v.x * r * wv4.x;
    out.y = v.y * r * wv4.y;
    out.z = v.z * r * wv4.z;
    out.w = v.w * r * wv4.w;
    ((float4*)(o + (size_t)row * DMODEL))[tid] = out;
}

// ---------------- f32 -> bf16 convert ----------------
__global__ __launch_bounds__(256) void convbf_k(const float* __restrict__ in,
                                                ushort_t* __restrict__ out) {
    int i = blockIdx.x * 256 + threadIdx.x;
    float4 a = ((const float4*)in)[i * 2];
    float4 b = ((const float4*)in)[i * 2 + 1];
    U4S8 o;
    o.s[0] = f2bf(a.x); o.s[1] = f2bf(a.y); o.s[2] = f2bf(a.z); o.s[3] = f2bf(a.w);
    o.s[4] = f2bf(b.x); o.s[5] = f2bf(b.y); o.s[6] = f2bf(b.z); o.s[7] = f2bf(b.w);
    ((uint4*)out)[i] = o.u;
}

// ---------------- weight transpose+convert: f32[K][N] -> bf16[N][K] ----------------
__global__ __launch_bounds__(256) void transconv_k(const float* __restrict__ in,
                                                   ushort_t* __restrict__ out,
                                                   int K, int N) {
    __shared__ ushort_t T[64][72];
    int k0 = blockIdx.y * 64, n0 = blockIdx.x * 64;
    int tid = threadIdx.x;
    int r = tid >> 4, c4 = (tid & 15) * 4;
#pragma unroll
    for (int i = 0; i < 4; i++) {
        float4 v = *(const float4*)(in + (size_t)(k0 + r + i * 16) * N + n0 + c4);
        T[c4 + 0][r + i * 16] = f2bf(v.x);
        T[c4 + 1][r + i * 16] = f2bf(v.y);
        T[c4 + 2][r + i * 16] = f2bf(v.z);
        T[c4 + 3][r + i * 16] = f2bf(v.w);
    }
    __syncthreads();
    int n = tid >> 2, kk = (tid & 3) * 16;
    U4S8 o0, o1;
#pragma unroll
    for (int i = 0; i < 8; i++) { o0.s[i] = T[n][kk + i]; o1.s[i] = T[n][kk + 8 + i]; }
    uint4* dst = (uint4*)(out + (size_t)(n0 + n) * K + k0 + kk);
    dst[0] = o0.u;
    dst[1] = o1.u;
}

// ---------------- bf16 MFMA GEMM (TN) ----------------
__global__ __launch_bounds__(256) void gemm_bf16_k(const ushort_t* __restrict__ A,
                                                   const ushort_t* __restrict__ Bt,
                                                   const float* __restrict__ add,
                                                   void* __restrict__ Cout,
                                                   int M, int N, int K, int out_bf16) {
    __shared__ ushort_t Al[128 * 32];
    __shared__ ushort_t Bl[128 * 32];
    int tid = threadIdx.x;
    int lane = tid & 63, wave = tid >> 6;
    int brow = blockIdx.y * 128, bcol = blockIdx.x * 128;
    int wr = (wave >> 1) * 64, wc = (wave & 1) * 64;
    f32x4 acc[4][4];
#pragma unroll
    for (int m = 0; m < 4; m++)
#pragma unroll
        for (int n = 0; n < 4; n++) acc[m][n] = (f32x4){0.f, 0.f, 0.f, 0.f};

    const ushort_t* Ag = A + (size_t)(brow + (tid >> 2)) * K + (tid & 3) * 8;
    const ushort_t* Bg = Bt + (size_t)(bcol + (tid >> 2)) * K + (tid & 3) * 8;
    ushort_t* Ald = &Al[wave * 512];
    ushort_t* Bld = &Bl[wave * 512];
    size_t rstep = (size_t)64 * K;

    for (int k0 = 0; k0 < K; k0 += 32) {
        gl_lds16(Ag + k0, Ald);
        gl_lds16(Ag + k0 + rstep, Ald + 2048);
        gl_lds16(Bg + k0, Bld);
        gl_lds16(Bg + k0 + rstep, Bld + 2048);
        __syncthreads();
        bf16x8 af[4], bfr[4];
        int arow = wr + (lane & 15);
        int brw = wc + (lane & 15);
        int kof = (lane >> 4) * 8;
#pragma unroll
        for (int m = 0; m < 4; m++) af[m] = *(const bf16x8*)&Al[(arow + m * 16) * 32 + kof];
#pragma unroll
        for (int n = 0; n < 4; n++) bfr[n] = *(const bf16x8*)&Bl[(brw + n * 16) * 32 + kof];
#pragma unroll
        for (int m = 0; m < 4; m++)
#pragma unroll
            for (int n = 0; n < 4; n++)
                acc[m][n] = __builtin_amdgcn_mfma_f32_16x16x32_bf16(af[m], bfr[n], acc[m][n], 0, 0, 0);
        __syncthreads();
    }
    int crow0 = brow + wr + (lane >> 4) * 4;
    int ccol = bcol + wc + (lane & 15);
#pragma unroll
    for (int m = 0; m < 4; m++)
#pragma unroll
        for (int j = 0; j < 4; j++) {
            int row = crow0 + m * 16 + j;
#pragma unroll
            for (int n = 0; n < 4; n++) {
                int col = ccol + n * 16;
                float v = acc[m][n][j];
                if (add) v += add[(size_t)row * N + col];
                if (out_bf16) ((ushort_t*)Cout)[(size_t)row * N + col] = f2bf(v);
                else ((float*)Cout)[(size_t)row * N + col] = v;
            }
        }
}

// ---------------- scores (chunk): sc[h][i_local][j] = q_i.k_j/8, f16 ----------------
__global__ __launch_bounds__(256) void scores_k(const float* __restrict__ q,
                                                const float* __restrict__ k,
                                                f16* __restrict__ sc, int cb) {
    int h = blockIdx.z;
    int i0l = blockIdx.y * 64, j0 = blockIdx.x * 64;
    __shared__ float Qs[64][DHEAD + 1];
    __shared__ float Ks[64][DHEAD + 1];
    int tid = threadIdx.x;
    for (int l = tid * 4; l < 4096; l += 1024) {
        int r = l >> 6, c = l & 63;
        float4 a = *(const float4*)(q + (size_t)(cb + i0l + r) * DMODEL + h * DHEAD + c);
        Qs[r][c] = a.x; Qs[r][c + 1] = a.y; Qs[r][c + 2] = a.z; Qs[r][c + 3] = a.w;
        float4 b = *(const float4*)(k + (size_t)(j0 + r) * DMODEL + h * DHEAD + c);
        Ks[r][c] = b.x; Ks[r][c + 1] = b.y; Ks[r][c + 2] = b.z; Ks[r][c + 3] = b.w;
    }
    __syncthreads();
    int tx = tid & 15, ty = tid >> 4;
    float acc[4][4] = {};
#pragma unroll 8
    for (int kk = 0; kk < DHEAD; kk++) {
        float a[4], b[4];
#pragma unroll
        for (int i = 0; i < 4; i++) a[i] = Qs[ty * 4 + i][kk];
#pragma unroll
        for (int j = 0; j < 4; j++) b[j] = Ks[tx * 4 + j][kk];
#pragma unroll
        for (int i = 0; i < 4; i++)
#pragma unroll
            for (int j = 0; j < 4; j++) acc[i][j] += a[i] * b[j];
    }
#pragma unroll
    for (int i = 0; i < 4; i++)
#pragma unroll
        for (int j = 0; j < 4; j++) {
            size_t idx = ((size_t)h * CHUNK + i0l + ty * 4 + i) * SEQ + j0 + tx * 4 + j;
            sc[idx] = (f16)(acc[i][j] * 0.125f);
        }
}

// ---------------- logits_int -> f16 ----------------
__global__ __launch_bounds__(256) void copelogits_k(const float* __restrict__ q,
                                                    const float* __restrict__ pe,
                                                    f16* __restrict__ li) {
    int s1 = blockIdx.x;
    int tid = threadIdx.x;
    __shared__ float PE[DHEAD * NPOSE];
    __shared__ float QR[DMODEL];
    for (int i = tid; i < DHEAD * NPOSE; i += 256) PE[i] = pe[i];
    for (int i = tid; i < DMODEL; i += 256) QR[i] = q[(size_t)s1 * DMODEL + i];
    __syncthreads();
#pragma unroll
    for (int j = 0; j < 8; j++) {
        int o = j * 256 + tid;
        int h = o >> 7, n = o & 127;
        const float* qh = &QR[h * DHEAD];
        float acc = 0.0f;
#pragma unroll 8
        for (int d = 0; d < DHEAD; d++) acc += qh[d] * PE[d * NPOSE + n];
        li[(size_t)s1 * (NH * NPOSE) + o] = (f16)acc;
    }
}

// ---------------- fused CoPE: scan + bias + split-precision MFMA MLP ----------------
// LDS C rows: stride 2050 f16 (1025 dwords) -> A-frag reads hit all 32 banks.
#define CSTR 2050
__global__ __launch_bounds__(256) void cope_k(f16* __restrict__ sc,
                                              const f16* __restrict__ li,
                                              const float* __restrict__ w1,
                                              const float* __restrict__ b1,
                                              const float* __restrict__ w2,
                                              const float* __restrict__ b2,
                                              int cb) {
    __shared__ f16 C[32 * CSTR];            // 131200 B: rows 0-15 scores->logits, 16-31 bias
    __shared__ float Lif[NH * 129];         // 8256 B
    __shared__ ushort_t HMB[4][2][16 * 36]; // 9216 B: per-wave hm bounce, hi/lo
    int r = blockIdx.x;
    int tid = threadIdx.x;
    int lane = tid & 63, wv = tid >> 6;

    // stage scores global -> C[h][t]  (full row: SEQ f16 = 1024 dwords)
    for (int h = 0; h < NH; h++) {
        const uint_t* s32 = (const uint_t*)(sc + ((size_t)h * CHUNK + r) * SEQ);
        uint_t* d32 = (uint_t*)&C[h * CSTR];
        d32[tid] = s32[tid];
        d32[tid + 256] = s32[tid + 256];
        d32[tid + 512] = s32[tid + 512];
        d32[tid + 768] = s32[tid + 768];
    }
    {
        const f16* lsrc = li + (size_t)(cb + r) * (NH * NPOSE);
        for (int i = tid; i < NH * NPOSE; i += 256) {
            int h = i >> 7, n = i & 127;
            Lif[h * 129 + n] = (float)lsrc[i];
        }
    }
    __syncthreads();

    // suffix scan + bias interp: wave wv handles heads 4wv..4wv+3
    for (int hq = 0; hq < 4; hq++) {
        int h = wv * 4 + hq;
        f16* crow = &C[h * CSTR];
        f16* brow = &C[(16 + h) * CSTR];
        const float* lrow = &Lif[h * 129];
        float carry = 0.0f;
        for (int c = SEQ / 64 - 1; c >= 0; c--) {
            int t = c * 64 + lane;
            float sv = (float)crow[t];
            float g = sigm(sv);
#pragma unroll
            for (int dd = 1; dd < 64; dd <<= 1) {
                float o = __shfl_down(g, dd, 64);
                g = (lane + dd < 64) ? g + o : g;
            }
            float total = __shfl(g, 0, 64);
            float pos = fminf(g + carry, 127.0f);
            carry += total;
            int fl = (int)pos;
            float fr = pos - (float)fl;
            float lf = lrow[fl];
            float lc = lrow[(fl < NPOSE - 1) ? fl + 1 : NPOSE - 1];
            brow[t] = (f16)(lc * fr + lf * (1.0f - fr));
        }
    }
    __syncthreads();

    // MLP weight fragments -> registers, hi/lo split (once per block)
    int fkg = lane >> 4;   // k-group
    int fc = lane & 15;    // row/col within 16
    BF8 w1fH[2], w1fL[2], w2fH, w2fL;
    float b1v[2], b2v;
#pragma unroll
    for (int half = 0; half < 2; half++) {
#pragma unroll
        for (int j = 0; j < 8; j++) {
            float wval = w1[(fkg * 8 + j) * MLPWID + half * 16 + fc];
            ushort_t hb = f2bf(wval);
            w1fH[half].s[j] = hb;
            w1fL[half].s[j] = f2bf(wval - bf2f(hb));
        }
        b1v[half] = b1[half * 16 + fc];
    }
#pragma unroll
    for (int j = 0; j < 8; j++) {
        float wval = w2[(fkg * 8 + j) * NH + fc];
        ushort_t hb = f2bf(wval);
        w2fH.s[j] = hb;
        w2fL.s[j] = f2bf(wval - bf2f(hb));
    }
    b2v = b2[fc];

    // MFMA MLP over t-tiles of 16; wave wv does tiles wv, wv+4, ...
    // split-precision: a*w ~= aH*wH + aH*wL + aL*wH
    ushort_t* hmbH = HMB[wv][0];
    ushort_t* hmbL = HMB[wv][1];
    for (int tt = wv; tt < SEQ / 16; tt += 4) {
        int t0 = tt * 16;
        BF8 afH, afL;
#pragma unroll
        for (int j = 0; j < 8; j++) {
            int f = fkg * 8 + j;
            float val = (float)C[f * CSTR + t0 + fc];
            ushort_t hb = f2bf(val);
            afH.s[j] = hb;
            afL.s[j] = f2bf(val - bf2f(hb));
        }
        f32x4 acc0 = (f32x4){b1v[0], b1v[0], b1v[0], b1v[0]};
        f32x4 acc1 = (f32x4){b1v[1], b1v[1], b1v[1], b1v[1]};
        acc0 = __builtin_amdgcn_mfma_f32_16x16x32_bf16(afH.v, w1fH[0].v, acc0, 0, 0, 0);
        acc0 = __builtin_amdgcn_mfma_f32_16x16x32_bf16(afH.v, w1fL[0].v, acc0, 0, 0, 0);
        acc0 = __builtin_amdgcn_mfma_f32_16x16x32_bf16(afL.v, w1fH[0].v, acc0, 0, 0, 0);
        acc1 = __builtin_amdgcn_mfma_f32_16x16x32_bf16(afH.v, w1fH[1].v, acc1, 0, 0, 0);
        acc1 = __builtin_amdgcn_mfma_f32_16x16x32_bf16(afH.v, w1fL[1].v, acc1, 0, 0, 0);
        acc1 = __builtin_amdgcn_mfma_f32_16x16x32_bf16(afL.v, w1fH[1].v, acc1, 0, 0, 0);
        // silu -> hm, hi/lo bf16 into per-wave LDS bounce
#pragma unroll
        for (int j2 = 0; j2 < 4; j2++) {
            int p = fkg * 4 + j2;
            float h0 = acc0[j2]; h0 = h0 * sigm(h0);
            float h1 = acc1[j2]; h1 = h1 * sigm(h1);
            ushort_t h0b = f2bf(h0), h1b = f2bf(h1);
            hmbH[p * 36 + fc] = h0b;
            hmbH[p * 36 + 16 + fc] = h1b;
            hmbL[p * 36 + fc] = f2bf(h0 - bf2f(h0b));
            hmbL[p * 36 + 16 + fc] = f2bf(h1 - bf2f(h1b));
        }
        BF8 hfH, hfL;
        hfH.u2[0] = *(const uint2*)&hmbH[fc * 36 + fkg * 8];
        hfH.u2[1] = *(const uint2*)&hmbH[fc * 36 + fkg * 8 + 4];
        hfL.u2[0] = *(const uint2*)&hmbL[fc * 36 + fkg * 8];
        hfL.u2[1] = *(const uint2*)&hmbL[fc * 36 + fkg * 8 + 4];
        f32x4 acc2 = (f32x4){b2v, b2v, b2v, b2v};
        acc2 = __builtin_amdgcn_mfma_f32_16x16x32_bf16(hfH.v, w2fH.v, acc2, 0, 0, 0);
        acc2 = __builtin_amdgcn_mfma_f32_16x16x32_bf16(hfH.v, w2fL.v, acc2, 0, 0, 0);
        acc2 = __builtin_amdgcn_mfma_f32_16x16x32_bf16(hfL.v, w2fH.v, acc2, 0, 0, 0);
        // final logit = score + dyn, in place (lane: head=fc, t=t0+fkg*4+j2)
#pragma unroll
        for (int j2 = 0; j2 < 4; j2 += 2) {
            uint_t* pp = (uint_t*)&C[fc * CSTR + t0 + fkg * 4 + j2];
            U1H2 old, neu;
            old.u = *pp;
            neu.h[0] = (f16)((float)old.h[0] + acc2[j2]);
            neu.h[1] = (f16)((float)old.h[1] + acc2[j2 + 1]);
            *pp = neu.u;
        }
    }
    __syncthreads();

    // write final logits back (full row)
    for (int h = 0; h < NH; h++) {
        const uint_t* s32 = (const uint_t*)&C[h * CSTR];
        uint_t* d32 = (uint_t*)(sc + ((size_t)h * CHUNK + r) * SEQ);
        d32[tid] = s32[tid];
        d32[tid + 256] = s32[tid + 256];
        d32[tid + 512] = s32[tid + 512];
        d32[tid + 768] = s32[tid + 768];
    }
}

// ---------------- row max / softmax denom ----------------
__global__ __launch_bounds__(256) void rowstat_k(const f16* __restrict__ sc,
                                                 float* __restrict__ rowmax,
                                                 float* __restrict__ rowsum,
                                                 int cb) {
    int wv = threadIdx.x >> 6, lane = threadIdx.x & 63;
    int task = blockIdx.x * 4 + wv;
    int h = task / CHUNK;
    int r = task % CHUNK;
    const uint2* s = (const uint2*)(sc + ((size_t)h * CHUNK + r) * SEQ);
    float vals[32];
    float m = -1e30f;
#pragma unroll
    for (int i = 0; i < 8; i++) {
        U2H4 u;
        u.u = s[i * 64 + lane];
#pragma unroll
        for (int j = 0; j < 4; j++) {
            float f = (float)u.h[j];
            vals[i * 4 + j] = f;
            m = fmaxf(m, f);
        }
    }
#pragma unroll
    for (int d = 1; d < 64; d <<= 1) m = fmaxf(m, __shfl_xor(m, d, 64));
    float sum = 0.0f;
#pragma unroll
    for (int i = 0; i < 32; i++) sum += __expf(vals[i] - m);
#pragma unroll
    for (int d = 1; d < 64; d <<= 1) sum += __shfl_xor(sum, d, 64);
    if (lane == 0) {
        rowmax[(size_t)h * SEQ + cb + r] = m;
        rowsum[(size_t)h * SEQ + cb + r] = sum;
    }
}

// ---------------- softmax-normalize + PV ----------------
__global__ __launch_bounds__(256) void pv_k(const f16* __restrict__ sc,
                                            const float* __restrict__ v,
                                            const float* __restrict__ rowmax,
                                            const float* __restrict__ rowsum,
                                            float* __restrict__ ao, int cb) {
    int h = blockIdx.y;
    int s0l = blockIdx.x * 64;
    __shared__ float P[64][65];
    __shared__ float Vt[64][65];
    __shared__ float rm[64];
    __shared__ float ri[64];
    int tid = threadIdx.x;
    int tx = tid & 15, ty = tid >> 4;
    if (tid < 64) {
        rm[tid] = rowmax[(size_t)h * SEQ + cb + s0l + tid];
        ri[tid] = 1.0f / rowsum[(size_t)h * SEQ + cb + s0l + tid];
    }
    __syncthreads();
    float acc[4][4] = {};
    for (int t0 = 0; t0 < SEQ; t0 += 64) {
        for (int l = tid; l < 4096; l += 256) {
            int r = l >> 6, c = l & 63;
            float lg = (float)sc[((size_t)h * CHUNK + s0l + r) * SEQ + t0 + c];
            P[r][c] = __expf(lg - rm[r]) * ri[r];
            Vt[r][c] = v[(size_t)(t0 + r) * DMODEL + h * DHEAD + c];
        }
        __syncthreads();
#pragma unroll 8
        for (int kk = 0; kk < 64; kk++) {
            float a[4], b[4];
#pragma unroll
            for (int i = 0; i < 4; i++) a[i] = P[ty * 4 + i][kk];
#pragma unroll
            for (int j = 0; j < 4; j++) b[j] = Vt[kk][tx * 4 + j];
#pragma unroll
            for (int i = 0; i < 4; i++)
#pragma unroll
                for (int j = 0; j < 4; j++) acc[i][j] += a[i] * b[j];
        }
        __syncthreads();
    }
#pragma unroll
    for (int i = 0; i < 4; i++)
#pragma unroll
        for (int j = 0; j < 4; j++)
            ao[(size_t)(cb + s0l + ty * 4 + i) * DMODEL + h * DHEAD + tx * 4 + j] = acc[i][j];
}

// ---------------- silu(g1)*g3, bf16 ----------------
__global__ __launch_bounds__(256) void silumul_bf_k(ushort_t* __restrict__ g1,
                                                    const ushort_t* __restrict__ g3) {
    int i = blockIdx.x * 256 + threadIdx.x;
    U4S8 a, b, o;
    a.u = ((const uint4*)g1)[i];
    b.u = ((const uint4*)g3)[i];
#pragma unroll
    for (int j = 0; j < 8; j++) {
        float x = bf2f(a.s[j]);
        float y = bf2f(b.s[j]);
        o.s[j] = f2bf(x * sigm(x) * y);
    }
    ((uint4*)g1)[i] = o.u;
}

extern "C" void kernel_launch(void* const* d_in, const int* in_sizes, int n_in,
                              void* d_out, int out_size, void* d_ws, size_t ws_size,
                              hipStream_t stream) {
    const float* x = (const float*)d_in[0];
    const float* wq = (const float*)d_in[1];
    const float* wk = (const float*)d_in[2];
    const float* wv = (const float*)d_in[3];
    const float* wo = (const float*)d_in[4];
    const float* pos_emb = (const float*)d_in[5];
    const float* mlp_w1 = (const float*)d_in[6];
    const float* mlp_b1 = (const float*)d_in[7];
    const float* mlp_w2 = (const float*)d_in[8];
    const float* mlp_b2 = (const float*)d_in[9];
    const float* ffn_w1 = (const float*)d_in[10];
    const float* ffn_w2 = (const float*)d_in[11];
    const float* ffn_w3 = (const float*)d_in[12];
    const float* attn_norm_w = (const float*)d_in[13];
    const float* ffn_norm_w = (const float*)d_in[14];
    float* out = (float*)d_out;

    char* ws = (char*)d_ws;
    const size_t MB = 1024 * 1024;
    float* nx = (float*)(ws + 0);                   // 8MB
    float* q = (float*)(ws + 8 * MB);               // 8MB
    float* k = (float*)(ws + 16 * MB);              // 8MB
    float* v = (float*)(ws + 24 * MB);              // 8MB (x1 after attention)
    ushort_t* nxb = (ushort_t*)(ws + 32 * MB);      // 4MB bf16
    f16* li = (f16*)(ws + 36 * MB);                 // 8MB f16
    float* rowmax = (float*)(ws + 44 * MB);         // 128KB
    float* rowsum = (float*)(ws + 44 * MB + 512 * 1024);
    float* ao = (float*)(ws + 45 * MB);             // 8MB
    // phase 1 weights
    ushort_t* wqt = (ushort_t*)(ws + 53 * MB);      // 2MB
    ushort_t* wkt = (ushort_t*)(ws + 55 * MB);
    ushort_t* wvt = (ushort_t*)(ws + 57 * MB);
    // phase 2 (overwrites wqt..): per-chunk scores/logits, f16 [NH][CHUNK][SEQ]
    f16* sc = (f16*)(ws + 53 * MB);                 // 64MB -> top 117MB
    // phase B/C (over sc, after attention)
    ushort_t* wot = (ushort_t*)(ws + 53 * MB);      // 2MB
    ushort_t* aob = (ushort_t*)(ws + 57 * MB);      // 4MB
    ushort_t* w1t = (ushort_t*)(ws + 61 * MB);      // 8MB
    ushort_t* w3t = (ushort_t*)(ws + 69 * MB);      // 8MB
    ushort_t* w2t = (ushort_t*)(ws + 77 * MB);      // 8MB
    ushort_t* g1b = (ushort_t*)(ws + 85 * MB);      // 16MB
    ushort_t* g3b = (ushort_t*)(ws + 101 * MB);     // 16MB -> top 117MB
    float* x1 = (float*)(ws + 24 * MB);

    // ---- phase 1: norms + QKV ----
    transconv_k<<<dim3(DMODEL / 64, DMODEL / 64), 256, 0, stream>>>(wq, wqt, DMODEL, DMODEL);
    transconv_k<<<dim3(DMODEL / 64, DMODEL / 64), 256, 0, stream>>>(wk, wkt, DMODEL, DMODEL);
    transconv_k<<<dim3(DMODEL / 64, DMODEL / 64), 256, 0, stream>>>(wv, wvt, DMODEL, DMODEL);
    rmsnorm_k<<<SEQ, 256, 0, stream>>>(x, attn_norm_w, nx);
    convbf_k<<<SEQ * DMODEL / 8 / 256, 256, 0, stream>>>(nx, nxb);
    dim3 gqkv(DMODEL / 128, SEQ / 128);
    gemm_bf16_k<<<gqkv, 256, 0, stream>>>(nxb, wqt, nullptr, q, SEQ, DMODEL, DMODEL, 0);
    gemm_bf16_k<<<gqkv, 256, 0, stream>>>(nxb, wkt, nullptr, k, SEQ, DMODEL, DMODEL, 0);
    gemm_bf16_k<<<gqkv, 256, 0, stream>>>(nxb, wvt, nullptr, v, SEQ, DMODEL, DMODEL, 0);
    copelogits_k<<<SEQ, 256, 0, stream>>>(q, pos_emb, li);

    // ---- phase 2: attention chunks ----
    for (int ch = 0; ch < NCH; ch++) {
        int cb = ch * CHUNK;
        scores_k<<<dim3(SEQ / 64, CHUNK / 64, NH), 256, 0, stream>>>(q, k, sc, cb);
        cope_k<<<CHUNK, 256, 0, stream>>>(sc, li, mlp_w1, mlp_b1, mlp_w2, mlp_b2, cb);
        rowstat_k<<<NH * CHUNK / 4, 256, 0, stream>>>(sc, rowmax, rowsum, cb);
        pv_k<<<dim3(CHUNK / 64, NH), 256, 0, stream>>>(sc, v, rowmax, rowsum, ao, cb);
    }

    // ---- phase B: out @ wo + x ----
    transconv_k<<<dim3(DMODEL / 64, DMODEL / 64), 256, 0, stream>>>(wo, wot, DMODEL, DMODEL);
    convbf_k<<<SEQ * DMODEL / 8 / 256, 256, 0, stream>>>(ao, aob);
    gemm_bf16_k<<<gqkv, 256, 0, stream>>>(aob, wot, x, x1, SEQ, DMODEL, DMODEL, 0);

    // ---- phase C: FFN ----
    rmsnorm_k<<<SEQ, 256, 0, stream>>>(x1, ffn_norm_w, nx);
    convbf_k<<<SEQ * DMODEL / 8 / 256, 256, 0, stream>>>(nx, nxb);
    transconv_k<<<dim3(FFDIM / 64, DMODEL / 64), 256, 0, stream>>>(ffn_w1, w1t, DMODEL, FFDIM);
    transconv_k<<<dim3(FFDIM / 64, DMODEL / 64), 256, 0, stream>>>(ffn_w3, w3t, DMODEL, FFDIM);
    transconv_k<<<dim3(DMODEL / 64, FFDIM / 64), 256, 0, stream>>>(ffn_w2, w2t, FFDIM, DMODEL);
    dim3 gff(FFDIM / 128, SEQ / 128);
    gemm_bf16_k<<<gff, 256, 0, stream>>>(nxb, w1t, nullptr, g1b, SEQ, FFDIM, DMODEL, 1);
    gemm_bf16_k<<<gff, 256, 0, stream>>>(nxb, w3t, nullptr, g3b, SEQ, FFDIM, DMODEL, 1);
    silumul_bf_k<<<SEQ * FFDIM / 8 / 256, 256, 0, stream>>>(g1b, g3b);
    gemm_bf16_k<<<gqkv, 256, 0, stream>>>(g1b, w2t, x1, out, SEQ, DMODEL, FFDIM, 0);
}

// Round 7
// 877.154 us; speedup vs baseline: 4.5135x; 1.9150x over previous
//
#include <hip/hip_runtime.h>
#include <hip/hip_bf16.h>
#include <hip/hip_fp16.h>
#include <math.h>

#define SEQ 2048
#define DMODEL 1024
#define NH 16
#define DHEAD 64
#define FFDIM 4096
#define NPOSE 128
#define MLPWID 32
#define EPSV 1e-5f
#define CHUNK 512
#define NCH (SEQ / CHUNK)

typedef unsigned short ushort_t;
typedef unsigned int uint_t;
typedef _Float16 f16;
typedef __attribute__((ext_vector_type(8))) short bf16x8;
typedef __attribute__((ext_vector_type(4))) float f32x4;

union U2H4 { uint2 u; f16 h[4]; };
union U4S8 { uint4 u; ushort_t s[8]; };
union U4H8 { uint4 u; f16 h[8]; };
union BF8 { bf16x8 v; ushort_t s[8]; uint2 u2[2]; };
union U1H2 { uint_t u; f16 h[2]; };

__device__ __forceinline__ float sigm(float x) {
    return 1.0f / (1.0f + __expf(-x));
}
__device__ __forceinline__ ushort_t f2bf(float f) {
    uint_t u = __float_as_uint(f);
    u += 0x7fffu + ((u >> 16) & 1u);
    return (ushort_t)(u >> 16);
}
__device__ __forceinline__ float bf2f(ushort_t u) {
    return __uint_as_float(((uint_t)u) << 16);
}
__device__ __forceinline__ void gl_lds16(const void* g, void* l) {
    __builtin_amdgcn_global_load_lds((const __attribute__((address_space(1))) uint_t*)g,
                                     (__attribute__((address_space(3))) uint_t*)l, 16, 0, 0);
}

// ---------------- RMSNorm ----------------
__global__ __launch_bounds__(256) void rmsnorm_k(const float* __restrict__ x,
                                                 const float* __restrict__ w,
                                                 float* __restrict__ o) {
    int row = blockIdx.x;
    int tid = threadIdx.x;
    const float4* xr = (const float4*)(x + (size_t)row * DMODEL);
    float4 v = xr[tid];
    float ss = v.x * v.x + v.y * v.y + v.z * v.z + v.w * v.w;
#pragma unroll
    for (int d = 1; d < 64; d <<= 1) ss += __shfl_xor(ss, d, 64);
    __shared__ float red[4];
    int lane = tid & 63, wv = tid >> 6;
    if (lane == 0) red[wv] = ss;
    __syncthreads();
    float tot = red[0] + red[1] + red[2] + red[3];
    float r = rsqrtf(tot / (float)DMODEL + EPSV);
    const float4* wr = (const float4*)w;
    float4 wv4 = wr[tid];
    float4 out;
    out.x = v.x * r * wv4.x;
    out.y = v.y * r * wv4.y;
    out.z = v.z * r * wv4.z;
    out.w = v.w * r * wv4.w;
    ((float4*)(o + (size_t)row * DMODEL))[tid] = out;
}

// ---------------- f32 -> bf16 convert ----------------
__global__ __launch_bounds__(256) void convbf_k(const float* __restrict__ in,
                                                ushort_t* __restrict__ out) {
    int i = blockIdx.x * 256 + threadIdx.x;
    float4 a = ((const float4*)in)[i * 2];
    float4 b = ((const float4*)in)[i * 2 + 1];
    U4S8 o;
    o.s[0] = f2bf(a.x); o.s[1] = f2bf(a.y); o.s[2] = f2bf(a.z); o.s[3] = f2bf(a.w);
    o.s[4] = f2bf(b.x); o.s[5] = f2bf(b.y); o.s[6] = f2bf(b.z); o.s[7] = f2bf(b.w);
    ((uint4*)out)[i] = o.u;
}

// ---------------- f32 -> bf16 hi/lo split ----------------
__global__ __launch_bounds__(256) void convsplit_k(const float* __restrict__ in,
                                                   ushort_t* __restrict__ hi,
                                                   ushort_t* __restrict__ lo) {
    int i = blockIdx.x * 256 + threadIdx.x;
    float4 a = ((const float4*)in)[i * 2];
    float4 b = ((const float4*)in)[i * 2 + 1];
    float vv[8] = {a.x, a.y, a.z, a.w, b.x, b.y, b.z, b.w};
    U4S8 oh, ol;
#pragma unroll
    for (int j = 0; j < 8; j++) {
        ushort_t h = f2bf(vv[j]);
        oh.s[j] = h;
        ol.s[j] = f2bf(vv[j] - bf2f(h));
    }
    ((uint4*)hi)[i] = oh.u;
    ((uint4*)lo)[i] = ol.u;
}

// ---------------- V transpose: vb[SEQ][DMODEL] bf16 -> vt[NH][DHEAD][SEQ] ----------------
__global__ __launch_bounds__(256) void tv_k(const ushort_t* __restrict__ vb,
                                            ushort_t* __restrict__ vt) {
    int h = blockIdx.y, t0 = blockIdx.x * 64;
    __shared__ ushort_t T[64][76];
    int tid = threadIdx.x;
#pragma unroll
    for (int it = 0; it < 2; it++) {
        int a = tid + it * 256;
        int t = a >> 3, c8 = (a & 7) * 8;
        U4S8 v;
        v.u = *(const uint4*)(vb + (size_t)(t0 + t) * DMODEL + h * 64 + c8);
#pragma unroll
        for (int j = 0; j < 8; j++) T[c8 + j][t] = v.s[j];
    }
    __syncthreads();
#pragma unroll
    for (int it = 0; it < 2; it++) {
        int a = tid + it * 256;
        int d = a >> 3, c8 = (a & 7) * 8;
        U4S8 o;
#pragma unroll
        for (int j = 0; j < 8; j++) o.s[j] = T[d][c8 + j];
        *(uint4*)(vt + ((size_t)h * 64 + d) * SEQ + t0 + c8) = o.u;
    }
}

// ---------------- weight transpose+convert: f32[K][N] -> bf16[N][K] ----------------
__global__ __launch_bounds__(256) void transconv_k(const float* __restrict__ in,
                                                   ushort_t* __restrict__ out,
                                                   int K, int N) {
    __shared__ ushort_t T[64][72];
    int k0 = blockIdx.y * 64, n0 = blockIdx.x * 64;
    int tid = threadIdx.x;
    int r = tid >> 4, c4 = (tid & 15) * 4;
#pragma unroll
    for (int i = 0; i < 4; i++) {
        float4 v = *(const float4*)(in + (size_t)(k0 + r + i * 16) * N + n0 + c4);
        T[c4 + 0][r + i * 16] = f2bf(v.x);
        T[c4 + 1][r + i * 16] = f2bf(v.y);
        T[c4 + 2][r + i * 16] = f2bf(v.z);
        T[c4 + 3][r + i * 16] = f2bf(v.w);
    }
    __syncthreads();
    int n = tid >> 2, kk = (tid & 3) * 16;
    U4S8 o0, o1;
#pragma unroll
    for (int i = 0; i < 8; i++) { o0.s[i] = T[n][kk + i]; o1.s[i] = T[n][kk + 8 + i]; }
    uint4* dst = (uint4*)(out + (size_t)(n0 + n) * K + k0 + kk);
    dst[0] = o0.u;
    dst[1] = o1.u;
}

// ---------------- bf16 MFMA GEMM (TN) ----------------
__global__ __launch_bounds__(256) void gemm_bf16_k(const ushort_t* __restrict__ A,
                                                   const ushort_t* __restrict__ Bt,
                                                   const float* __restrict__ add,
                                                   void* __restrict__ Cout,
                                                   int M, int N, int K, int out_bf16) {
    __shared__ ushort_t Al[128 * 32];
    __shared__ ushort_t Bl[128 * 32];
    int tid = threadIdx.x;
    int lane = tid & 63, wave = tid >> 6;
    int brow = blockIdx.y * 128, bcol = blockIdx.x * 128;
    int wr = (wave >> 1) * 64, wc = (wave & 1) * 64;
    f32x4 acc[4][4];
#pragma unroll
    for (int m = 0; m < 4; m++)
#pragma unroll
        for (int n = 0; n < 4; n++) acc[m][n] = (f32x4){0.f, 0.f, 0.f, 0.f};

    const ushort_t* Ag = A + (size_t)(brow + (tid >> 2)) * K + (tid & 3) * 8;
    const ushort_t* Bg = Bt + (size_t)(bcol + (tid >> 2)) * K + (tid & 3) * 8;
    ushort_t* Ald = &Al[wave * 512];
    ushort_t* Bld = &Bl[wave * 512];
    size_t rstep = (size_t)64 * K;

    for (int k0 = 0; k0 < K; k0 += 32) {
        gl_lds16(Ag + k0, Ald);
        gl_lds16(Ag + k0 + rstep, Ald + 2048);
        gl_lds16(Bg + k0, Bld);
        gl_lds16(Bg + k0 + rstep, Bld + 2048);
        __syncthreads();
        bf16x8 af[4], bfr[4];
        int arow = wr + (lane & 15);
        int brw = wc + (lane & 15);
        int kof = (lane >> 4) * 8;
#pragma unroll
        for (int m = 0; m < 4; m++) af[m] = *(const bf16x8*)&Al[(arow + m * 16) * 32 + kof];
#pragma unroll
        for (int n = 0; n < 4; n++) bfr[n] = *(const bf16x8*)&Bl[(brw + n * 16) * 32 + kof];
#pragma unroll
        for (int m = 0; m < 4; m++)
#pragma unroll
            for (int n = 0; n < 4; n++)
                acc[m][n] = __builtin_amdgcn_mfma_f32_16x16x32_bf16(af[m], bfr[n], acc[m][n], 0, 0, 0);
        __syncthreads();
    }
    int crow0 = brow + wr + (lane >> 4) * 4;
    int ccol = bcol + wc + (lane & 15);
#pragma unroll
    for (int m = 0; m < 4; m++)
#pragma unroll
        for (int j = 0; j < 4; j++) {
            int row = crow0 + m * 16 + j;
#pragma unroll
            for (int n = 0; n < 4; n++) {
                int col = ccol + n * 16;
                float v = acc[m][n][j];
                if (add) v += add[(size_t)row * N + col];
                if (out_bf16) ((ushort_t*)Cout)[(size_t)row * N + col] = f2bf(v);
                else ((float*)Cout)[(size_t)row * N + col] = v;
            }
        }
}

// ---------------- MFMA scores: sc[h][il][j] = (qh+ql)_i . kb_j / 8 ----------------
__global__ __launch_bounds__(256) void scoresm_k(const ushort_t* __restrict__ qh,
                                                 const ushort_t* __restrict__ ql,
                                                 const ushort_t* __restrict__ kb,
                                                 f16* __restrict__ sc, int cb) {
    int h = blockIdx.z;
    int il0 = blockIdx.y * 64;      // local query row
    int j0 = blockIdx.x * 64;
    __shared__ ushort_t Qh[64][72];
    __shared__ ushort_t Ql[64][72];
    __shared__ ushort_t Kb[64][72];
    int tid = threadIdx.x;
    {
        int r = tid >> 2, c0 = (tid & 3) * 16;
        const ushort_t* p;
        p = qh + (size_t)(cb + il0 + r) * DMODEL + h * 64 + c0;
        *(uint4*)&Qh[r][c0] = *(const uint4*)p;
        *(uint4*)&Qh[r][c0 + 8] = *(const uint4*)(p + 8);
        p = ql + (size_t)(cb + il0 + r) * DMODEL + h * 64 + c0;
        *(uint4*)&Ql[r][c0] = *(const uint4*)p;
        *(uint4*)&Ql[r][c0 + 8] = *(const uint4*)(p + 8);
        p = kb + (size_t)(j0 + r) * DMODEL + h * 64 + c0;
        *(uint4*)&Kb[r][c0] = *(const uint4*)p;
        *(uint4*)&Kb[r][c0 + 8] = *(const uint4*)(p + 8);
    }
    __syncthreads();
    int lane = tid & 63, wave = tid >> 6;
    int wr = (wave >> 1) * 32, wc = (wave & 1) * 32;
    f32x4 acc[2][2];
#pragma unroll
    for (int m = 0; m < 2; m++)
#pragma unroll
        for (int n = 0; n < 2; n++) acc[m][n] = (f32x4){0.f, 0.f, 0.f, 0.f};
#pragma unroll
    for (int ks = 0; ks < 2; ks++) {
        int kof = ks * 32 + (lane >> 4) * 8;
        bf16x8 aH[2], aL[2], bK[2];
#pragma unroll
        for (int m = 0; m < 2; m++) {
            int ar = wr + m * 16 + (lane & 15);
            aH[m] = *(const bf16x8*)&Qh[ar][kof];
            aL[m] = *(const bf16x8*)&Ql[ar][kof];
        }
#pragma unroll
        for (int n = 0; n < 2; n++) bK[n] = *(const bf16x8*)&Kb[wc + n * 16 + (lane & 15)][kof];
#pragma unroll
        for (int m = 0; m < 2; m++)
#pragma unroll
            for (int n = 0; n < 2; n++) {
                acc[m][n] = __builtin_amdgcn_mfma_f32_16x16x32_bf16(aH[m], bK[n], acc[m][n], 0, 0, 0);
                acc[m][n] = __builtin_amdgcn_mfma_f32_16x16x32_bf16(aL[m], bK[n], acc[m][n], 0, 0, 0);
            }
    }
#pragma unroll
    for (int m = 0; m < 2; m++)
#pragma unroll
        for (int j = 0; j < 4; j++) {
            int il = il0 + wr + m * 16 + (lane >> 4) * 4 + j;
#pragma unroll
            for (int n = 0; n < 2; n++) {
                int jj = j0 + wc + n * 16 + (lane & 15);
                sc[((size_t)h * CHUNK + il) * SEQ + jj] = (f16)(acc[m][n][j] * 0.125f);
            }
        }
}

// ---------------- logits_int -> f16 ----------------
__global__ __launch_bounds__(256) void copelogits_k(const float* __restrict__ q,
                                                    const float* __restrict__ pe,
                                                    f16* __restrict__ li) {
    int s1 = blockIdx.x;
    int tid = threadIdx.x;
    __shared__ float PE[DHEAD * NPOSE];
    __shared__ float QR[DMODEL];
    for (int i = tid; i < DHEAD * NPOSE; i += 256) PE[i] = pe[i];
    for (int i = tid; i < DMODEL; i += 256) QR[i] = q[(size_t)s1 * DMODEL + i];
    __syncthreads();
#pragma unroll
    for (int j = 0; j < 8; j++) {
        int o = j * 256 + tid;
        int h = o >> 7, n = o & 127;
        const float* qhp = &QR[h * DHEAD];
        float acc = 0.0f;
#pragma unroll 8
        for (int d = 0; d < DHEAD; d++) acc += qhp[d] * PE[d * NPOSE + n];
        li[(size_t)s1 * (NH * NPOSE) + o] = (f16)acc;
    }
}

// ---------------- fused CoPE: scan + bias + MFMA MLP + rowstat (512 thr) ----------------
#define CSTR 2050
__global__ __launch_bounds__(512) void cope_k(f16* __restrict__ sc,
                                              const f16* __restrict__ li,
                                              const float* __restrict__ w1,
                                              const float* __restrict__ b1,
                                              const float* __restrict__ w2,
                                              const float* __restrict__ b2,
                                              float* __restrict__ rowmax,
                                              float* __restrict__ rowsum,
                                              int cb) {
    __shared__ f16 C[32 * CSTR];            // 131200 B
    __shared__ float Lif[NH * 129];         // 8256 B
    __shared__ ushort_t HMB[8][2][16 * 36]; // 18432 B  -> 157888 total
    int r = blockIdx.x;
    int tid = threadIdx.x;
    int lane = tid & 63, wv = tid >> 6;

    // stage scores (16 rows x 1024 dwords)
    for (int h = 0; h < NH; h++) {
        const uint_t* s32 = (const uint_t*)(sc + ((size_t)h * CHUNK + r) * SEQ);
        uint_t* d32 = (uint_t*)&C[h * CSTR];
        d32[tid] = s32[tid];
        d32[tid + 512] = s32[tid + 512];
    }
    {
        const f16* lsrc = li + (size_t)(cb + r) * (NH * NPOSE);
        for (int i = tid; i < NH * NPOSE; i += 512) {
            Lif[(i >> 7) * 129 + (i & 127)] = (float)lsrc[i];
        }
    }
    __syncthreads();

    // suffix scan: wave wv handles heads 2wv, 2wv+1 with interleaved chains
    {
        int h0 = wv * 2, h1 = h0 + 1;
        f16* c0 = &C[h0 * CSTR];
        f16* c1 = &C[h1 * CSTR];
        f16* bias0 = &C[(16 + h0) * CSTR];
        f16* bias1 = &C[(16 + h1) * CSTR];
        const float* l0 = &Lif[h0 * 129];
        const float* l1 = &Lif[h1 * 129];
        float carry0 = 0.0f, carry1 = 0.0f;
        for (int c = SEQ / 64 - 1; c >= 0; c--) {
            int t = c * 64 + lane;
            float g0 = sigm((float)c0[t]);
            float g1 = sigm((float)c1[t]);
#pragma unroll
            for (int dd = 1; dd < 64; dd <<= 1) {
                float o0 = __shfl_down(g0, dd, 64);
                float o1 = __shfl_down(g1, dd, 64);
                bool ok = (lane + dd < 64);
                g0 = ok ? g0 + o0 : g0;
                g1 = ok ? g1 + o1 : g1;
            }
            float tot0 = __shfl(g0, 0, 64);
            float tot1 = __shfl(g1, 0, 64);
            float pos0 = fminf(g0 + carry0, 127.0f); carry0 += tot0;
            float pos1 = fminf(g1 + carry1, 127.0f); carry1 += tot1;
            int fl0 = (int)pos0; float fr0 = pos0 - (float)fl0;
            int fl1 = (int)pos1; float fr1 = pos1 - (float)fl1;
            bias0[t] = (f16)(l0[(fl0 < 127) ? fl0 + 1 : 127] * fr0 + l0[fl0] * (1.0f - fr0));
            bias1[t] = (f16)(l1[(fl1 < 127) ? fl1 + 1 : 127] * fr1 + l1[fl1] * (1.0f - fr1));
        }
    }
    __syncthreads();

    // MLP weight fragments, hi/lo split
    int fkg = lane >> 4;
    int fc = lane & 15;
    BF8 w1fH[2], w1fL[2], w2fH, w2fL;
    float b1v[2], b2v;
#pragma unroll
    for (int half = 0; half < 2; half++) {
#pragma unroll
        for (int j = 0; j < 8; j++) {
            float wval = w1[(fkg * 8 + j) * MLPWID + half * 16 + fc];
            ushort_t hb = f2bf(wval);
            w1fH[half].s[j] = hb;
            w1fL[half].s[j] = f2bf(wval - bf2f(hb));
        }
        b1v[half] = b1[half * 16 + fc];
    }
#pragma unroll
    for (int j = 0; j < 8; j++) {
        float wval = w2[(fkg * 8 + j) * NH + fc];
        ushort_t hb = f2bf(wval);
        w2fH.s[j] = hb;
        w2fL.s[j] = f2bf(wval - bf2f(hb));
    }
    b2v = b2[fc];

    ushort_t* hmbH = HMB[wv][0];
    ushort_t* hmbL = HMB[wv][1];
    for (int tt = wv; tt < SEQ / 16; tt += 8) {
        int t0 = tt * 16;
        BF8 afH, afL;
#pragma unroll
        for (int j = 0; j < 8; j++) {
            int f = fkg * 8 + j;
            float val = (float)C[f * CSTR + t0 + fc];
            ushort_t hb = f2bf(val);
            afH.s[j] = hb;
            afL.s[j] = f2bf(val - bf2f(hb));
        }
        f32x4 acc0 = (f32x4){b1v[0], b1v[0], b1v[0], b1v[0]};
        f32x4 acc1 = (f32x4){b1v[1], b1v[1], b1v[1], b1v[1]};
        acc0 = __builtin_amdgcn_mfma_f32_16x16x32_bf16(afH.v, w1fH[0].v, acc0, 0, 0, 0);
        acc0 = __builtin_amdgcn_mfma_f32_16x16x32_bf16(afH.v, w1fL[0].v, acc0, 0, 0, 0);
        acc0 = __builtin_amdgcn_mfma_f32_16x16x32_bf16(afL.v, w1fH[0].v, acc0, 0, 0, 0);
        acc1 = __builtin_amdgcn_mfma_f32_16x16x32_bf16(afH.v, w1fH[1].v, acc1, 0, 0, 0);
        acc1 = __builtin_amdgcn_mfma_f32_16x16x32_bf16(afH.v, w1fL[1].v, acc1, 0, 0, 0);
        acc1 = __builtin_amdgcn_mfma_f32_16x16x32_bf16(afL.v, w1fH[1].v, acc1, 0, 0, 0);
#pragma unroll
        for (int j2 = 0; j2 < 4; j2++) {
            int p = fkg * 4 + j2;
            float h0 = acc0[j2]; h0 = h0 * sigm(h0);
            float h1 = acc1[j2]; h1 = h1 * sigm(h1);
            ushort_t h0b = f2bf(h0), h1b = f2bf(h1);
            hmbH[p * 36 + fc] = h0b;
            hmbH[p * 36 + 16 + fc] = h1b;
            hmbL[p * 36 + fc] = f2bf(h0 - bf2f(h0b));
            hmbL[p * 36 + 16 + fc] = f2bf(h1 - bf2f(h1b));
        }
        BF8 hfH, hfL;
        hfH.u2[0] = *(const uint2*)&hmbH[fc * 36 + fkg * 8];
        hfH.u2[1] = *(const uint2*)&hmbH[fc * 36 + fkg * 8 + 4];
        hfL.u2[0] = *(const uint2*)&hmbL[fc * 36 + fkg * 8];
        hfL.u2[1] = *(const uint2*)&hmbL[fc * 36 + fkg * 8 + 4];
        f32x4 acc2 = (f32x4){b2v, b2v, b2v, b2v};
        acc2 = __builtin_amdgcn_mfma_f32_16x16x32_bf16(hfH.v, w2fH.v, acc2, 0, 0, 0);
        acc2 = __builtin_amdgcn_mfma_f32_16x16x32_bf16(hfH.v, w2fL.v, acc2, 0, 0, 0);
        acc2 = __builtin_amdgcn_mfma_f32_16x16x32_bf16(hfL.v, w2fH.v, acc2, 0, 0, 0);
#pragma unroll
        for (int j2 = 0; j2 < 4; j2 += 2) {
            uint_t* pp = (uint_t*)&C[fc * CSTR + t0 + fkg * 4 + j2];
            U1H2 old, neu;
            old.u = *pp;
            neu.h[0] = (f16)((float)old.h[0] + acc2[j2]);
            neu.h[1] = (f16)((float)old.h[1] + acc2[j2 + 1]);
            *pp = neu.u;
        }
    }
    __syncthreads();

    // fused rowstat: wave wv -> heads 2wv, 2wv+1
#pragma unroll
    for (int hh = 0; hh < 2; hh++) {
        int h = wv * 2 + hh;
        const f16* row = &C[h * CSTR];
        float m = -1e30f;
        for (int c = 0; c < SEQ / 64; c++) m = fmaxf(m, (float)row[c * 64 + lane]);
#pragma unroll
        for (int d = 1; d < 64; d <<= 1) m = fmaxf(m, __shfl_xor(m, d, 64));
        float s = 0.0f;
        for (int c = 0; c < SEQ / 64; c++) s += __expf((float)row[c * 64 + lane] - m);
#pragma unroll
        for (int d = 1; d < 64; d <<= 1) s += __shfl_xor(s, d, 64);
        if (lane == 0) {
            rowmax[(size_t)h * SEQ + cb + r] = m;
            rowsum[(size_t)h * SEQ + cb + r] = s;
        }
    }

    // write back logits
    for (int h = 0; h < NH; h++) {
        const uint_t* s32 = (const uint_t*)&C[h * CSTR];
        uint_t* d32 = (uint_t*)(sc + ((size_t)h * CHUNK + r) * SEQ);
        d32[tid] = s32[tid];
        d32[tid + 512] = s32[tid + 512];
    }
}

// ---------------- MFMA softmax+PV: ao[s][h*64+d] ----------------
__global__ __launch_bounds__(256) void pvm_k(const f16* __restrict__ sc,
                                             const ushort_t* __restrict__ vt,
                                             const float* __restrict__ rowmax,
                                             const float* __restrict__ rowsum,
                                             float* __restrict__ ao, int cb) {
    int h = blockIdx.y;
    int s0 = blockIdx.x * 32;   // local row in chunk
    __shared__ ushort_t P[32][72];
    __shared__ ushort_t Vt[64][72];
    __shared__ float rm[32];
    __shared__ float ri[32];
    int tid = threadIdx.x;
    int lane = tid & 63, wave = tid >> 6;
    if (tid < 32) {
        rm[tid] = rowmax[(size_t)h * SEQ + cb + s0 + tid];
        ri[tid] = 1.0f / rowsum[(size_t)h * SEQ + cb + s0 + tid];
    }
    __syncthreads();
    int wr = (wave >> 1) * 16, wc = (wave & 1) * 32;
    f32x4 acc[2];
    acc[0] = (f32x4){0.f, 0.f, 0.f, 0.f};
    acc[1] = (f32x4){0.f, 0.f, 0.f, 0.f};
    int pr = tid >> 3, pc = (tid & 7) * 8;       // P stage: 32 rows x 8 segs
    int vr = tid >> 2, vc = (tid & 3) * 16;      // Vt stage: 64 rows x 4 segs
    for (int t0 = 0; t0 < SEQ; t0 += 64) {
        {
            U4H8 lg;
            lg.u = *(const uint4*)(sc + ((size_t)h * CHUNK + s0 + pr) * SEQ + t0 + pc);
            float rmv = rm[pr], riv = ri[pr];
            U4S8 o;
#pragma unroll
            for (int j = 0; j < 8; j++) o.s[j] = f2bf(__expf((float)lg.h[j] - rmv) * riv);
            *(uint4*)&P[pr][pc] = o.u;
            const ushort_t* vp = vt + ((size_t)h * 64 + vr) * SEQ + t0 + vc;
            *(uint4*)&Vt[vr][vc] = *(const uint4*)vp;
            *(uint4*)&Vt[vr][vc + 8] = *(const uint4*)(vp + 8);
        }
        __syncthreads();
#pragma unroll
        for (int ks = 0; ks < 2; ks++) {
            int kof = ks * 32 + (lane >> 4) * 8;
            bf16x8 pa = *(const bf16x8*)&P[wr + (lane & 15)][kof];
#pragma unroll
            for (int n = 0; n < 2; n++) {
                bf16x8 vb = *(const bf16x8*)&Vt[wc + n * 16 + (lane & 15)][kof];
                acc[n] = __builtin_amdgcn_mfma_f32_16x16x32_bf16(pa, vb, acc[n], 0, 0, 0);
            }
        }
        __syncthreads();
    }
#pragma unroll
    for (int j = 0; j < 4; j++) {
        int s = cb + s0 + wr + (lane >> 4) * 4 + j;
#pragma unroll
        for (int n = 0; n < 2; n++) {
            int d = h * 64 + wc + n * 16 + (lane & 15);
            ao[(size_t)s * DMODEL + d] = acc[n][j];
        }
    }
}

// ---------------- silu(g1)*g3, bf16 ----------------
__global__ __launch_bounds__(256) void silumul_bf_k(ushort_t* __restrict__ g1,
                                                    const ushort_t* __restrict__ g3) {
    int i = blockIdx.x * 256 + threadIdx.x;
    U4S8 a, b, o;
    a.u = ((const uint4*)g1)[i];
    b.u = ((const uint4*)g3)[i];
#pragma unroll
    for (int j = 0; j < 8; j++) {
        float x = bf2f(a.s[j]);
        float y = bf2f(b.s[j]);
        o.s[j] = f2bf(x * sigm(x) * y);
    }
    ((uint4*)g1)[i] = o.u;
}

extern "C" void kernel_launch(void* const* d_in, const int* in_sizes, int n_in,
                              void* d_out, int out_size, void* d_ws, size_t ws_size,
                              hipStream_t stream) {
    const float* x = (const float*)d_in[0];
    const float* wq = (const float*)d_in[1];
    const float* wk = (const float*)d_in[2];
    const float* wv = (const float*)d_in[3];
    const float* wo = (const float*)d_in[4];
    const float* pos_emb = (const float*)d_in[5];
    const float* mlp_w1 = (const float*)d_in[6];
    const float* mlp_b1 = (const float*)d_in[7];
    const float* mlp_w2 = (const float*)d_in[8];
    const float* mlp_b2 = (const float*)d_in[9];
    const float* ffn_w1 = (const float*)d_in[10];
    const float* ffn_w2 = (const float*)d_in[11];
    const float* ffn_w3 = (const float*)d_in[12];
    const float* attn_norm_w = (const float*)d_in[13];
    const float* ffn_norm_w = (const float*)d_in[14];
    float* out = (float*)d_out;

    char* ws = (char*)d_ws;
    const size_t MB = 1024 * 1024;
    float* nx = (float*)(ws + 0);                    // 0-8
    float* q = (float*)(ws + 8 * MB);                // 8-16
    ushort_t* qh = (ushort_t*)(ws + 16 * MB);        // 16-20
    ushort_t* ql = (ushort_t*)(ws + 20 * MB);        // 20-24
    ushort_t* kb = (ushort_t*)(ws + 24 * MB);        // 24-28
    ushort_t* vb = (ushort_t*)(ws + 28 * MB);        // 28-32
    ushort_t* vt = (ushort_t*)(ws + 32 * MB);        // 32-36
    ushort_t* nxb = (ushort_t*)(ws + 36 * MB);       // 36-40 (phase 1)
    f16* li = (f16*)(ws + 40 * MB);                  // 40-48
    float* rowmax = (float*)(ws + 48 * MB);          // 128KB
    float* rowsum = (float*)(ws + 48 * MB + 512 * 1024);
    float* ao = (float*)(ws + 49 * MB);              // 49-57
    float* x1 = (float*)(ws + 57 * MB);              // 57-65
    // phase 1 weights (dead after QKV)
    ushort_t* wqt = (ushort_t*)(ws + 65 * MB);       // 65-67
    ushort_t* wkt = (ushort_t*)(ws + 67 * MB);       // 67-69
    ushort_t* wvt = (ushort_t*)(ws + 69 * MB);       // 69-71
    // phase 2: scores/logits f16 [NH][CHUNK][SEQ]
    f16* sc = (f16*)(ws + 65 * MB);                  // 65-97
    // phase B
    ushort_t* wot = (ushort_t*)(ws + 65 * MB);       // 65-67
    ushort_t* aob = (ushort_t*)(ws + 67 * MB);       // 67-71
    // phase C
    ushort_t* nxb2 = (ushort_t*)(ws + 16 * MB);      // over dead qh
    ushort_t* g1b = (ushort_t*)(ws + 20 * MB);       // 20-36
    ushort_t* g3b = (ushort_t*)(ws + 36 * MB);       // 36-52
    ushort_t* w1t = (ushort_t*)(ws + 71 * MB);       // 71-79
    ushort_t* w3t = (ushort_t*)(ws + 79 * MB);       // 79-87
    ushort_t* w2t = (ushort_t*)(ws + 87 * MB);       // 87-95

    // ---- phase 1: norms + QKV ----
    transconv_k<<<dim3(DMODEL / 64, DMODEL / 64), 256, 0, stream>>>(wq, wqt, DMODEL, DMODEL);
    transconv_k<<<dim3(DMODEL / 64, DMODEL / 64), 256, 0, stream>>>(wk, wkt, DMODEL, DMODEL);
    transconv_k<<<dim3(DMODEL / 64, DMODEL / 64), 256, 0, stream>>>(wv, wvt, DMODEL, DMODEL);
    rmsnorm_k<<<SEQ, 256, 0, stream>>>(x, attn_norm_w, nx);
    convbf_k<<<SEQ * DMODEL / 8 / 256, 256, 0, stream>>>(nx, nxb);
    dim3 gqkv(DMODEL / 128, SEQ / 128);
    gemm_bf16_k<<<gqkv, 256, 0, stream>>>(nxb, wqt, nullptr, q, SEQ, DMODEL, DMODEL, 0);
    gemm_bf16_k<<<gqkv, 256, 0, stream>>>(nxb, wkt, nullptr, kb, SEQ, DMODEL, DMODEL, 1);
    gemm_bf16_k<<<gqkv, 256, 0, stream>>>(nxb, wvt, nullptr, vb, SEQ, DMODEL, DMODEL, 1);
    copelogits_k<<<SEQ, 256, 0, stream>>>(q, pos_emb, li);
    convsplit_k<<<SEQ * DMODEL / 8 / 256, 256, 0, stream>>>(q, qh, ql);
    tv_k<<<dim3(SEQ / 64, NH), 256, 0, stream>>>(vb, vt);

    // ---- phase 2: attention chunks ----
    for (int ch = 0; ch < NCH; ch++) {
        int cb = ch * CHUNK;
        scoresm_k<<<dim3(SEQ / 64, CHUNK / 64, NH), 256, 0, stream>>>(qh, ql, kb, sc, cb);
        cope_k<<<CHUNK, 512, 0, stream>>>(sc, li, mlp_w1, mlp_b1, mlp_w2, mlp_b2,
                                          rowmax, rowsum, cb);
        pvm_k<<<dim3(CHUNK / 32, NH), 256, 0, stream>>>(sc, vt, rowmax, rowsum, ao, cb);
    }

    // ---- phase B: out @ wo + x ----
    transconv_k<<<dim3(DMODEL / 64, DMODEL / 64), 256, 0, stream>>>(wo, wot, DMODEL, DMODEL);
    convbf_k<<<SEQ * DMODEL / 8 / 256, 256, 0, stream>>>(ao, aob);
    gemm_bf16_k<<<gqkv, 256, 0, stream>>>(aob, wot, x, x1, SEQ, DMODEL, DMODEL, 0);

    // ---- phase C: FFN ----
    rmsnorm_k<<<SEQ, 256, 0, stream>>>(x1, ffn_norm_w, nx);
    convbf_k<<<SEQ * DMODEL / 8 / 256, 256, 0, stream>>>(nx, nxb2);
    transconv_k<<<dim3(FFDIM / 64, DMODEL / 64), 256, 0, stream>>>(ffn_w1, w1t, DMODEL, FFDIM);
    transconv_k<<<dim3(FFDIM / 64, DMODEL / 64), 256, 0, stream>>>(ffn_w3, w3t, DMODEL, FFDIM);
    transconv_k<<<dim3(DMODEL / 64, FFDIM / 64), 256, 0, stream>>>(ffn_w2, w2t, FFDIM, DMODEL);
    dim3 gff(FFDIM / 128, SEQ / 128);
    gemm_bf16_k<<<gff, 256, 0, stream>>>(nxb2, w1t, nullptr, g1b, SEQ, FFDIM, DMODEL, 1);
    gemm_bf16_k<<<gff, 256, 0, stream>>>(nxb2, w3t, nullptr, g3b, SEQ, FFDIM, DMODEL, 1);
    silumul_bf_k<<<SEQ * FFDIM / 8 / 256, 256, 0, stream>>>(g1b, g3b);
    gemm_bf16_k<<<gqkv, 256, 0, stream>>>(g1b, w2t, x1, out, SEQ, DMODEL, FFDIM, 0);
}

// Round 8
// 832.700 us; speedup vs baseline: 4.7545x; 1.0534x over previous
//
#include <hip/hip_runtime.h>
#include <hip/hip_bf16.h>
#include <hip/hip_fp16.h>
#include <math.h>

#define SEQ 2048
#define DMODEL 1024
#define NH 16
#define DHEAD 64
#define FFDIM 4096
#define NPOSE 128
#define MLPWID 32
#define EPSV 1e-5f
#define CHUNK 512
#define NCH (SEQ / CHUNK)

typedef unsigned short ushort_t;
typedef unsigned int uint_t;
typedef _Float16 f16;
typedef __attribute__((ext_vector_type(8))) short bf16x8;
typedef __attribute__((ext_vector_type(4))) float f32x4;

union U2H4 { uint2 u; f16 h[4]; };
union U4S8 { uint4 u; ushort_t s[8]; };
union U4H8 { uint4 u; f16 h[8]; };
union U2S4 { uint2 u; ushort_t s[4]; };
union BF8 { bf16x8 v; ushort_t s[8]; uint2 u2[2]; };
union U1H2 { uint_t u; f16 h[2]; };

__device__ __forceinline__ float sigm(float x) {
    return 1.0f / (1.0f + __expf(-x));
}
__device__ __forceinline__ ushort_t f2bf(float f) {
    uint_t u = __float_as_uint(f);
    u += 0x7fffu + ((u >> 16) & 1u);
    return (ushort_t)(u >> 16);
}
__device__ __forceinline__ float bf2f(ushort_t u) {
    return __uint_as_float(((uint_t)u) << 16);
}
__device__ __forceinline__ void gl_lds16(const void* g, void* l) {
    __builtin_amdgcn_global_load_lds((const __attribute__((address_space(1))) uint_t*)g,
                                     (__attribute__((address_space(3))) uint_t*)l, 16, 0, 0);
}

// ---------------- RMSNorm, bf16 out ----------------
__global__ __launch_bounds__(256) void rmsnormbf_k(const float* __restrict__ x,
                                                   const float* __restrict__ w,
                                                   ushort_t* __restrict__ o) {
    int row = blockIdx.x;
    int tid = threadIdx.x;
    const float4* xr = (const float4*)(x + (size_t)row * DMODEL);
    float4 v = xr[tid];
    float ss = v.x * v.x + v.y * v.y + v.z * v.z + v.w * v.w;
#pragma unroll
    for (int d = 1; d < 64; d <<= 1) ss += __shfl_xor(ss, d, 64);
    __shared__ float red[4];
    int lane = tid & 63, wv = tid >> 6;
    if (lane == 0) red[wv] = ss;
    __syncthreads();
    float tot = red[0] + red[1] + red[2] + red[3];
    float r = rsqrtf(tot / (float)DMODEL + EPSV);
    const float4* wr = (const float4*)w;
    float4 wv4 = wr[tid];
    U2S4 ob;
    ob.s[0] = f2bf(v.x * r * wv4.x);
    ob.s[1] = f2bf(v.y * r * wv4.y);
    ob.s[2] = f2bf(v.z * r * wv4.z);
    ob.s[3] = f2bf(v.w * r * wv4.w);
    ((uint2*)(o + (size_t)row * DMODEL))[tid] = ob.u;
}

// ---------------- V transpose: vb[SEQ][DMODEL] bf16 -> vt[NH][DHEAD][SEQ] ----------------
__global__ __launch_bounds__(256) void tv_k(const ushort_t* __restrict__ vb,
                                            ushort_t* __restrict__ vt) {
    int h = blockIdx.y, t0 = blockIdx.x * 64;
    __shared__ ushort_t T[64][76];
    int tid = threadIdx.x;
#pragma unroll
    for (int it = 0; it < 2; it++) {
        int a = tid + it * 256;
        int t = a >> 3, c8 = (a & 7) * 8;
        U4S8 v;
        v.u = *(const uint4*)(vb + (size_t)(t0 + t) * DMODEL + h * 64 + c8);
#pragma unroll
        for (int j = 0; j < 8; j++) T[c8 + j][t] = v.s[j];
    }
    __syncthreads();
#pragma unroll
    for (int it = 0; it < 2; it++) {
        int a = tid + it * 256;
        int d = a >> 3, c8 = (a & 7) * 8;
        U4S8 o;
#pragma unroll
        for (int j = 0; j < 8; j++) o.s[j] = T[d][c8 + j];
        *(uint4*)(vt + ((size_t)h * 64 + d) * SEQ + t0 + c8) = o.u;
    }
}

// ---------------- weight transpose+convert: f32[K][N] -> bf16[N][K] ----------------
__global__ __launch_bounds__(256) void transconv_k(const float* __restrict__ in,
                                                   ushort_t* __restrict__ out,
                                                   int K, int N) {
    __shared__ ushort_t T[64][72];
    int k0 = blockIdx.y * 64, n0 = blockIdx.x * 64;
    int tid = threadIdx.x;
    int r = tid >> 4, c4 = (tid & 15) * 4;
#pragma unroll
    for (int i = 0; i < 4; i++) {
        float4 v = *(const float4*)(in + (size_t)(k0 + r + i * 16) * N + n0 + c4);
        T[c4 + 0][r + i * 16] = f2bf(v.x);
        T[c4 + 1][r + i * 16] = f2bf(v.y);
        T[c4 + 2][r + i * 16] = f2bf(v.z);
        T[c4 + 3][r + i * 16] = f2bf(v.w);
    }
    __syncthreads();
    int n = tid >> 2, kk = (tid & 3) * 16;
    U4S8 o0, o1;
#pragma unroll
    for (int i = 0; i < 8; i++) { o0.s[i] = T[n][kk + i]; o1.s[i] = T[n][kk + 8 + i]; }
    uint4* dst = (uint4*)(out + (size_t)(n0 + n) * K + k0 + kk);
    dst[0] = o0.u;
    dst[1] = o1.u;
}

// ---------------- bf16 MFMA GEMM (TN), XCD-swizzled, multi-mode epilogue ----------------
// mode 0: f32 out (+add). mode 1: bf16 out. mode 2: qkv split (Cout=qh, p1=ql, p2=kb, p3=vb).
// mode 3: Cout bf16 in/out, out = silu(Cout)*acc.
__global__ __launch_bounds__(256) void gemm_bf16_k(const ushort_t* __restrict__ A,
                                                   const ushort_t* __restrict__ Bt,
                                                   const float* __restrict__ add,
                                                   void* __restrict__ Cout,
                                                   int M, int N, int K, int mode,
                                                   ushort_t* __restrict__ p1,
                                                   ushort_t* __restrict__ p2,
                                                   ushort_t* __restrict__ p3) {
    __shared__ ushort_t Al[128 * 32];
    __shared__ ushort_t Bl[128 * 32];
    int tid = threadIdx.x;
    int lane = tid & 63, wave = tid >> 6;
    int gx = gridDim.x, gy = gridDim.y;
    int nwg = gx * gy;
    int bx = blockIdx.x, by = blockIdx.y;
    if ((nwg & 7) == 0) {
        // XCD-chunked, column-major (B-panel-sharing) remap
        int flat = by * gx + bx;
        int cpx = nwg >> 3;
        int l = (flat & 7) * cpx + (flat >> 3);
        bx = l / gy;
        by = l % gy;
    }
    int brow = by * 128, bcol = bx * 128;
    int wr = (wave >> 1) * 64, wc = (wave & 1) * 64;
    f32x4 acc[4][4];
#pragma unroll
    for (int m = 0; m < 4; m++)
#pragma unroll
        for (int n = 0; n < 4; n++) acc[m][n] = (f32x4){0.f, 0.f, 0.f, 0.f};

    const ushort_t* Ag = A + (size_t)(brow + (tid >> 2)) * K + (tid & 3) * 8;
    const ushort_t* Bg = Bt + (size_t)(bcol + (tid >> 2)) * K + (tid & 3) * 8;
    ushort_t* Ald = &Al[wave * 512];
    ushort_t* Bld = &Bl[wave * 512];
    size_t rstep = (size_t)64 * K;

    for (int k0 = 0; k0 < K; k0 += 32) {
        gl_lds16(Ag + k0, Ald);
        gl_lds16(Ag + k0 + rstep, Ald + 2048);
        gl_lds16(Bg + k0, Bld);
        gl_lds16(Bg + k0 + rstep, Bld + 2048);
        __syncthreads();
        bf16x8 af[4], bfr[4];
        int arow = wr + (lane & 15);
        int brw = wc + (lane & 15);
        int kof = (lane >> 4) * 8;
#pragma unroll
        for (int m = 0; m < 4; m++) af[m] = *(const bf16x8*)&Al[(arow + m * 16) * 32 + kof];
#pragma unroll
        for (int n = 0; n < 4; n++) bfr[n] = *(const bf16x8*)&Bl[(brw + n * 16) * 32 + kof];
#pragma unroll
        for (int m = 0; m < 4; m++)
#pragma unroll
            for (int n = 0; n < 4; n++)
                acc[m][n] = __builtin_amdgcn_mfma_f32_16x16x32_bf16(af[m], bfr[n], acc[m][n], 0, 0, 0);
        __syncthreads();
    }
    int crow0 = brow + wr + (lane >> 4) * 4;
    int ccol = bcol + wc + (lane & 15);
#pragma unroll
    for (int m = 0; m < 4; m++)
#pragma unroll
        for (int j = 0; j < 4; j++) {
            int row = crow0 + m * 16 + j;
#pragma unroll
            for (int n = 0; n < 4; n++) {
                int col = ccol + n * 16;
                float v = acc[m][n][j];
                if (mode == 0) {
                    if (add) v += add[(size_t)row * N + col];
                    ((float*)Cout)[(size_t)row * N + col] = v;
                } else if (mode == 1) {
                    ((ushort_t*)Cout)[(size_t)row * N + col] = f2bf(v);
                } else if (mode == 2) {
                    size_t o = (size_t)row * DMODEL;
                    if (col < DMODEL) {
                        ushort_t hb = f2bf(v);
                        ((ushort_t*)Cout)[o + col] = hb;
                        p1[o + col] = f2bf(v - bf2f(hb));
                    } else if (col < 2 * DMODEL) {
                        p2[o + col - DMODEL] = f2bf(v);
                    } else {
                        p3[o + col - 2 * DMODEL] = f2bf(v);
                    }
                } else {
                    size_t idx = (size_t)row * N + col;
                    ushort_t* g = (ushort_t*)Cout;
                    float gv = bf2f(g[idx]);
                    g[idx] = f2bf(gv * sigm(gv) * v);
                }
            }
        }
}

// ---------------- MFMA scores: sc[h][il][j] = (qh+ql)_i . kb_j / 8 ----------------
__global__ __launch_bounds__(256) void scoresm_k(const ushort_t* __restrict__ qh,
                                                 const ushort_t* __restrict__ ql,
                                                 const ushort_t* __restrict__ kb,
                                                 f16* __restrict__ sc, int cb) {
    int h = blockIdx.z;
    int il0 = blockIdx.y * 64;
    int j0 = blockIdx.x * 64;
    __shared__ ushort_t Qh[64][72];
    __shared__ ushort_t Ql[64][72];
    __shared__ ushort_t Kb[64][72];
    int tid = threadIdx.x;
    {
        int r = tid >> 2, c0 = (tid & 3) * 16;
        const ushort_t* p;
        p = qh + (size_t)(cb + il0 + r) * DMODEL + h * 64 + c0;
        *(uint4*)&Qh[r][c0] = *(const uint4*)p;
        *(uint4*)&Qh[r][c0 + 8] = *(const uint4*)(p + 8);
        p = ql + (size_t)(cb + il0 + r) * DMODEL + h * 64 + c0;
        *(uint4*)&Ql[r][c0] = *(const uint4*)p;
        *(uint4*)&Ql[r][c0 + 8] = *(const uint4*)(p + 8);
        p = kb + (size_t)(j0 + r) * DMODEL + h * 64 + c0;
        *(uint4*)&Kb[r][c0] = *(const uint4*)p;
        *(uint4*)&Kb[r][c0 + 8] = *(const uint4*)(p + 8);
    }
    __syncthreads();
    int lane = tid & 63, wave = tid >> 6;
    int wr = (wave >> 1) * 32, wc = (wave & 1) * 32;
    f32x4 acc[2][2];
#pragma unroll
    for (int m = 0; m < 2; m++)
#pragma unroll
        for (int n = 0; n < 2; n++) acc[m][n] = (f32x4){0.f, 0.f, 0.f, 0.f};
#pragma unroll
    for (int ks = 0; ks < 2; ks++) {
        int kof = ks * 32 + (lane >> 4) * 8;
        bf16x8 aH[2], aL[2], bK[2];
#pragma unroll
        for (int m = 0; m < 2; m++) {
            int ar = wr + m * 16 + (lane & 15);
            aH[m] = *(const bf16x8*)&Qh[ar][kof];
            aL[m] = *(const bf16x8*)&Ql[ar][kof];
        }
#pragma unroll
        for (int n = 0; n < 2; n++) bK[n] = *(const bf16x8*)&Kb[wc + n * 16 + (lane & 15)][kof];
#pragma unroll
        for (int m = 0; m < 2; m++)
#pragma unroll
            for (int n = 0; n < 2; n++) {
                acc[m][n] = __builtin_amdgcn_mfma_f32_16x16x32_bf16(aH[m], bK[n], acc[m][n], 0, 0, 0);
                acc[m][n] = __builtin_amdgcn_mfma_f32_16x16x32_bf16(aL[m], bK[n], acc[m][n], 0, 0, 0);
            }
    }
#pragma unroll
    for (int m = 0; m < 2; m++)
#pragma unroll
        for (int j = 0; j < 4; j++) {
            int il = il0 + wr + m * 16 + (lane >> 4) * 4 + j;
#pragma unroll
            for (int n = 0; n < 2; n++) {
                int jj = j0 + wc + n * 16 + (lane & 15);
                sc[((size_t)h * CHUNK + il) * SEQ + jj] = (f16)(acc[m][n][j] * 0.125f);
            }
        }
}

// ---------------- logits_int -> f16 (reads qh+ql) ----------------
__global__ __launch_bounds__(256) void copelogits_k(const ushort_t* __restrict__ qh,
                                                    const ushort_t* __restrict__ ql,
                                                    const float* __restrict__ pe,
                                                    f16* __restrict__ li) {
    int s1 = blockIdx.x;
    int tid = threadIdx.x;
    __shared__ float PE[DHEAD * NPOSE];
    __shared__ float QR[DMODEL];
    for (int i = tid; i < DHEAD * NPOSE; i += 256) PE[i] = pe[i];
    for (int i = tid; i < DMODEL; i += 256)
        QR[i] = bf2f(qh[(size_t)s1 * DMODEL + i]) + bf2f(ql[(size_t)s1 * DMODEL + i]);
    __syncthreads();
#pragma unroll
    for (int j = 0; j < 8; j++) {
        int o = j * 256 + tid;
        int h = o >> 7, n = o & 127;
        const float* qhp = &QR[h * DHEAD];
        float acc = 0.0f;
#pragma unroll 8
        for (int d = 0; d < DHEAD; d++) acc += qhp[d] * PE[d * NPOSE + n];
        li[(size_t)s1 * (NH * NPOSE) + o] = (f16)acc;
    }
}

// ---------------- fused CoPE: scan + bias + MFMA MLP + rowstat (512 thr) ----------------
#define CSTR 2050
__global__ __launch_bounds__(512) void cope_k(f16* __restrict__ sc,
                                              const f16* __restrict__ li,
                                              const float* __restrict__ w1,
                                              const float* __restrict__ b1,
                                              const float* __restrict__ w2,
                                              const float* __restrict__ b2,
                                              float* __restrict__ rowmax,
                                              float* __restrict__ rowsum,
                                              int cb) {
    __shared__ f16 C[32 * CSTR];
    __shared__ float Lif[NH * 129];
    __shared__ ushort_t HMB[8][2][16 * 36];
    int r = blockIdx.x;
    int tid = threadIdx.x;
    int lane = tid & 63, wv = tid >> 6;

    for (int h = 0; h < NH; h++) {
        const uint_t* s32 = (const uint_t*)(sc + ((size_t)h * CHUNK + r) * SEQ);
        uint_t* d32 = (uint_t*)&C[h * CSTR];
        d32[tid] = s32[tid];
        d32[tid + 512] = s32[tid + 512];
    }
    {
        const f16* lsrc = li + (size_t)(cb + r) * (NH * NPOSE);
        for (int i = tid; i < NH * NPOSE; i += 512) {
            Lif[(i >> 7) * 129 + (i & 127)] = (float)lsrc[i];
        }
    }
    __syncthreads();

    {
        int h0 = wv * 2, h1 = h0 + 1;
        f16* c0 = &C[h0 * CSTR];
        f16* c1 = &C[h1 * CSTR];
        f16* bias0 = &C[(16 + h0) * CSTR];
        f16* bias1 = &C[(16 + h1) * CSTR];
        const float* l0 = &Lif[h0 * 129];
        const float* l1 = &Lif[h1 * 129];
        float carry0 = 0.0f, carry1 = 0.0f;
        for (int c = SEQ / 64 - 1; c >= 0; c--) {
            int t = c * 64 + lane;
            float g0 = sigm((float)c0[t]);
            float g1 = sigm((float)c1[t]);
#pragma unroll
            for (int dd = 1; dd < 64; dd <<= 1) {
                float o0 = __shfl_down(g0, dd, 64);
                float o1 = __shfl_down(g1, dd, 64);
                bool ok = (lane + dd < 64);
                g0 = ok ? g0 + o0 : g0;
                g1 = ok ? g1 + o1 : g1;
            }
            float tot0 = __shfl(g0, 0, 64);
            float tot1 = __shfl(g1, 0, 64);
            float pos0 = fminf(g0 + carry0, 127.0f); carry0 += tot0;
            float pos1 = fminf(g1 + carry1, 127.0f); carry1 += tot1;
            int fl0 = (int)pos0; float fr0 = pos0 - (float)fl0;
            int fl1 = (int)pos1; float fr1 = pos1 - (float)fl1;
            bias0[t] = (f16)(l0[(fl0 < 127) ? fl0 + 1 : 127] * fr0 + l0[fl0] * (1.0f - fr0));
            bias1[t] = (f16)(l1[(fl1 < 127) ? fl1 + 1 : 127] * fr1 + l1[fl1] * (1.0f - fr1));
        }
    }
    __syncthreads();

    int fkg = lane >> 4;
    int fc = lane & 15;
    BF8 w1fH[2], w1fL[2], w2fH, w2fL;
    float b1v[2], b2v;
#pragma unroll
    for (int half = 0; half < 2; half++) {
#pragma unroll
        for (int j = 0; j < 8; j++) {
            float wval = w1[(fkg * 8 + j) * MLPWID + half * 16 + fc];
            ushort_t hb = f2bf(wval);
            w1fH[half].s[j] = hb;
            w1fL[half].s[j] = f2bf(wval - bf2f(hb));
        }
        b1v[half] = b1[half * 16 + fc];
    }
#pragma unroll
    for (int j = 0; j < 8; j++) {
        float wval = w2[(fkg * 8 + j) * NH + fc];
        ushort_t hb = f2bf(wval);
        w2fH.s[j] = hb;
        w2fL.s[j] = f2bf(wval - bf2f(hb));
    }
    b2v = b2[fc];

    ushort_t* hmbH = HMB[wv][0];
    ushort_t* hmbL = HMB[wv][1];
    for (int tt = wv; tt < SEQ / 16; tt += 8) {
        int t0 = tt * 16;
        BF8 afH, afL;
#pragma unroll
        for (int j = 0; j < 8; j++) {
            int f = fkg * 8 + j;
            float val = (float)C[f * CSTR + t0 + fc];
            ushort_t hb = f2bf(val);
            afH.s[j] = hb;
            afL.s[j] = f2bf(val - bf2f(hb));
        }
        f32x4 acc0 = (f32x4){b1v[0], b1v[0], b1v[0], b1v[0]};
        f32x4 acc1 = (f32x4){b1v[1], b1v[1], b1v[1], b1v[1]};
        acc0 = __builtin_amdgcn_mfma_f32_16x16x32_bf16(afH.v, w1fH[0].v, acc0, 0, 0, 0);
        acc0 = __builtin_amdgcn_mfma_f32_16x16x32_bf16(afH.v, w1fL[0].v, acc0, 0, 0, 0);
        acc0 = __builtin_amdgcn_mfma_f32_16x16x32_bf16(afL.v, w1fH[0].v, acc0, 0, 0, 0);
        acc1 = __builtin_amdgcn_mfma_f32_16x16x32_bf16(afH.v, w1fH[1].v, acc1, 0, 0, 0);
        acc1 = __builtin_amdgcn_mfma_f32_16x16x32_bf16(afH.v, w1fL[1].v, acc1, 0, 0, 0);
        acc1 = __builtin_amdgcn_mfma_f32_16x16x32_bf16(afL.v, w1fH[1].v, acc1, 0, 0, 0);
#pragma unroll
        for (int j2 = 0; j2 < 4; j2++) {
            int p = fkg * 4 + j2;
            float h0 = acc0[j2]; h0 = h0 * sigm(h0);
            float h1 = acc1[j2]; h1 = h1 * sigm(h1);
            ushort_t h0b = f2bf(h0), h1b = f2bf(h1);
            hmbH[p * 36 + fc] = h0b;
            hmbH[p * 36 + 16 + fc] = h1b;
            hmbL[p * 36 + fc] = f2bf(h0 - bf2f(h0b));
            hmbL[p * 36 + 16 + fc] = f2bf(h1 - bf2f(h1b));
        }
        BF8 hfH, hfL;
        hfH.u2[0] = *(const uint2*)&hmbH[fc * 36 + fkg * 8];
        hfH.u2[1] = *(const uint2*)&hmbH[fc * 36 + fkg * 8 + 4];
        hfL.u2[0] = *(const uint2*)&hmbL[fc * 36 + fkg * 8];
        hfL.u2[1] = *(const uint2*)&hmbL[fc * 36 + fkg * 8 + 4];
        f32x4 acc2 = (f32x4){b2v, b2v, b2v, b2v};
        acc2 = __builtin_amdgcn_mfma_f32_16x16x32_bf16(hfH.v, w2fH.v, acc2, 0, 0, 0);
        acc2 = __builtin_amdgcn_mfma_f32_16x16x32_bf16(hfH.v, w2fL.v, acc2, 0, 0, 0);
        acc2 = __builtin_amdgcn_mfma_f32_16x16x32_bf16(hfL.v, w2fH.v, acc2, 0, 0, 0);
#pragma unroll
        for (int j2 = 0; j2 < 4; j2 += 2) {
            uint_t* pp = (uint_t*)&C[fc * CSTR + t0 + fkg * 4 + j2];
            U1H2 old, neu;
            old.u = *pp;
            neu.h[0] = (f16)((float)old.h[0] + acc2[j2]);
            neu.h[1] = (f16)((float)old.h[1] + acc2[j2 + 1]);
            *pp = neu.u;
        }
    }
    __syncthreads();

#pragma unroll
    for (int hh = 0; hh < 2; hh++) {
        int h = wv * 2 + hh;
        const f16* row = &C[h * CSTR];
        float m = -1e30f;
        for (int c = 0; c < SEQ / 64; c++) m = fmaxf(m, (float)row[c * 64 + lane]);
#pragma unroll
        for (int d = 1; d < 64; d <<= 1) m = fmaxf(m, __shfl_xor(m, d, 64));
        float s = 0.0f;
        for (int c = 0; c < SEQ / 64; c++) s += __expf((float)row[c * 64 + lane] - m);
#pragma unroll
        for (int d = 1; d < 64; d <<= 1) s += __shfl_xor(s, d, 64);
        if (lane == 0) {
            rowmax[(size_t)h * SEQ + cb + r] = m;
            rowsum[(size_t)h * SEQ + cb + r] = s;
        }
    }

    for (int h = 0; h < NH; h++) {
        const uint_t* s32 = (const uint_t*)&C[h * CSTR];
        uint_t* d32 = (uint_t*)(sc + ((size_t)h * CHUNK + r) * SEQ);
        d32[tid] = s32[tid];
        d32[tid + 512] = s32[tid + 512];
    }
}

// ---------------- MFMA softmax+PV -> aob bf16 ----------------
__global__ __launch_bounds__(256) void pvm_k(const f16* __restrict__ sc,
                                             const ushort_t* __restrict__ vt,
                                             const float* __restrict__ rowmax,
                                             const float* __restrict__ rowsum,
                                             ushort_t* __restrict__ aob, int cb) {
    int h = blockIdx.y;
    int s0 = blockIdx.x * 32;
    __shared__ ushort_t P[32][72];
    __shared__ ushort_t Vt[64][72];
    __shared__ float rm[32];
    __shared__ float ri[32];
    int tid = threadIdx.x;
    int lane = tid & 63, wave = tid >> 6;
    if (tid < 32) {
        rm[tid] = rowmax[(size_t)h * SEQ + cb + s0 + tid];
        ri[tid] = 1.0f / rowsum[(size_t)h * SEQ + cb + s0 + tid];
    }
    __syncthreads();
    int wr = (wave >> 1) * 16, wc = (wave & 1) * 32;
    f32x4 acc[2];
    acc[0] = (f32x4){0.f, 0.f, 0.f, 0.f};
    acc[1] = (f32x4){0.f, 0.f, 0.f, 0.f};
    int pr = tid >> 3, pc = (tid & 7) * 8;
    int vr = tid >> 2, vc = (tid & 3) * 16;
    for (int t0 = 0; t0 < SEQ; t0 += 64) {
        {
            U4H8 lg;
            lg.u = *(const uint4*)(sc + ((size_t)h * CHUNK + s0 + pr) * SEQ + t0 + pc);
            float rmv = rm[pr], riv = ri[pr];
            U4S8 o;
#pragma unroll
            for (int j = 0; j < 8; j++) o.s[j] = f2bf(__expf((float)lg.h[j] - rmv) * riv);
            *(uint4*)&P[pr][pc] = o.u;
            const ushort_t* vp = vt + ((size_t)h * 64 + vr) * SEQ + t0 + vc;
            *(uint4*)&Vt[vr][vc] = *(const uint4*)vp;
            *(uint4*)&Vt[vr][vc + 8] = *(const uint4*)(vp + 8);
        }
        __syncthreads();
#pragma unroll
        for (int ks = 0; ks < 2; ks++) {
            int kof = ks * 32 + (lane >> 4) * 8;
            bf16x8 pa = *(const bf16x8*)&P[wr + (lane & 15)][kof];
#pragma unroll
            for (int n = 0; n < 2; n++) {
                bf16x8 vb = *(const bf16x8*)&Vt[wc + n * 16 + (lane & 15)][kof];
                acc[n] = __builtin_amdgcn_mfma_f32_16x16x32_bf16(pa, vb, acc[n], 0, 0, 0);
            }
        }
        __syncthreads();
    }
#pragma unroll
    for (int j = 0; j < 4; j++) {
        int s = cb + s0 + wr + (lane >> 4) * 4 + j;
#pragma unroll
        for (int n = 0; n < 2; n++) {
            int d = h * 64 + wc + n * 16 + (lane & 15);
            aob[(size_t)s * DMODEL + d] = f2bf(acc[n][j]);
        }
    }
}

extern "C" void kernel_launch(void* const* d_in, const int* in_sizes, int n_in,
                              void* d_out, int out_size, void* d_ws, size_t ws_size,
                              hipStream_t stream) {
    const float* x = (const float*)d_in[0];
    const float* wq = (const float*)d_in[1];
    const float* wk = (const float*)d_in[2];
    const float* wv = (const float*)d_in[3];
    const float* wo = (const float*)d_in[4];
    const float* pos_emb = (const float*)d_in[5];
    const float* mlp_w1 = (const float*)d_in[6];
    const float* mlp_b1 = (const float*)d_in[7];
    const float* mlp_w2 = (const float*)d_in[8];
    const float* mlp_b2 = (const float*)d_in[9];
    const float* ffn_w1 = (const float*)d_in[10];
    const float* ffn_w2 = (const float*)d_in[11];
    const float* ffn_w3 = (const float*)d_in[12];
    const float* attn_norm_w = (const float*)d_in[13];
    const float* ffn_norm_w = (const float*)d_in[14];
    float* out = (float*)d_out;

    char* ws = (char*)d_ws;
    const size_t MB = 1024 * 1024;
    ushort_t* nxb = (ushort_t*)(ws + 0);             // 0-4
    ushort_t* qh = (ushort_t*)(ws + 4 * MB);         // 4-8   (phase C: nxb2)
    ushort_t* ql = (ushort_t*)(ws + 8 * MB);         // 8-12  (phase C: g1b 8-24)
    ushort_t* kb = (ushort_t*)(ws + 12 * MB);        // 12-16
    ushort_t* vb = (ushort_t*)(ws + 16 * MB);        // 16-20
    ushort_t* vt = (ushort_t*)(ws + 20 * MB);        // 20-24
    f16* li = (f16*)(ws + 24 * MB);                  // 24-32
    float* rowmax = (float*)(ws + 32 * MB);          // 128KB
    float* rowsum = (float*)(ws + 32 * MB + 512 * 1024);
    ushort_t* aob = (ushort_t*)(ws + 33 * MB);       // 33-37
    float* x1 = (float*)(ws + 37 * MB);              // 37-45
    ushort_t* wqkvt = (ushort_t*)(ws + 45 * MB);     // 45-51 (phase 1)
    f16* sc = (f16*)(ws + 45 * MB);                  // 45-77 (phase 2)
    ushort_t* wot = (ushort_t*)(ws + 45 * MB);       // 45-47 (phase B)
    ushort_t* w1t = (ushort_t*)(ws + 47 * MB);       // 47-55 (phase C)
    ushort_t* w3t = (ushort_t*)(ws + 55 * MB);       // 55-63
    ushort_t* w2t = (ushort_t*)(ws + 63 * MB);       // 63-71 -> peak 77MB
    ushort_t* nxb2 = (ushort_t*)(ws + 4 * MB);
    ushort_t* g1b = (ushort_t*)(ws + 8 * MB);        // 8-24

    // ---- phase 1: norm + fused QKV ----
    transconv_k<<<dim3(DMODEL / 64, DMODEL / 64), 256, 0, stream>>>(wq, wqkvt, DMODEL, DMODEL);
    transconv_k<<<dim3(DMODEL / 64, DMODEL / 64), 256, 0, stream>>>(wk, wqkvt + 1024 * 1024, DMODEL, DMODEL);
    transconv_k<<<dim3(DMODEL / 64, DMODEL / 64), 256, 0, stream>>>(wv, wqkvt + 2 * 1024 * 1024, DMODEL, DMODEL);
    rmsnormbf_k<<<SEQ, 256, 0, stream>>>(x, attn_norm_w, nxb);
    gemm_bf16_k<<<dim3(3 * DMODEL / 128, SEQ / 128), 256, 0, stream>>>(
        nxb, wqkvt, nullptr, qh, SEQ, 3 * DMODEL, DMODEL, 2, ql, kb, vb);
    copelogits_k<<<SEQ, 256, 0, stream>>>(qh, ql, pos_emb, li);
    tv_k<<<dim3(SEQ / 64, NH), 256, 0, stream>>>(vb, vt);

    // ---- phase 2: attention chunks ----
    for (int ch = 0; ch < NCH; ch++) {
        int cb = ch * CHUNK;
        scoresm_k<<<dim3(SEQ / 64, CHUNK / 64, NH), 256, 0, stream>>>(qh, ql, kb, sc, cb);
        cope_k<<<CHUNK, 512, 0, stream>>>(sc, li, mlp_w1, mlp_b1, mlp_w2, mlp_b2,
                                          rowmax, rowsum, cb);
        pvm_k<<<dim3(CHUNK / 32, NH), 256, 0, stream>>>(sc, vt, rowmax, rowsum, aob, cb);
    }

    // ---- phase B: out @ wo + x ----
    transconv_k<<<dim3(DMODEL / 64, DMODEL / 64), 256, 0, stream>>>(wo, wot, DMODEL, DMODEL);
    gemm_bf16_k<<<dim3(DMODEL / 128, SEQ / 128), 256, 0, stream>>>(
        aob, wot, x, x1, SEQ, DMODEL, DMODEL, 0, nullptr, nullptr, nullptr);

    // ---- phase C: FFN ----
    rmsnormbf_k<<<SEQ, 256, 0, stream>>>(x1, ffn_norm_w, nxb2);
    transconv_k<<<dim3(FFDIM / 64, DMODEL / 64), 256, 0, stream>>>(ffn_w1, w1t, DMODEL, FFDIM);
    transconv_k<<<dim3(FFDIM / 64, DMODEL / 64), 256, 0, stream>>>(ffn_w3, w3t, DMODEL, FFDIM);
    transconv_k<<<dim3(DMODEL / 64, FFDIM / 64), 256, 0, stream>>>(ffn_w2, w2t, FFDIM, DMODEL);
    dim3 gff(FFDIM / 128, SEQ / 128);
    gemm_bf16_k<<<gff, 256, 0, stream>>>(nxb2, w1t, nullptr, g1b, SEQ, FFDIM, DMODEL, 1,
                                         nullptr, nullptr, nullptr);
    gemm_bf16_k<<<gff, 256, 0, stream>>>(nxb2, w3t, nullptr, g1b, SEQ, FFDIM, DMODEL, 3,
                                         nullptr, nullptr, nullptr);
    gemm_bf16_k<<<dim3(DMODEL / 128, SEQ / 128), 256, 0, stream>>>(
        g1b, w2t, x1, out, SEQ, DMODEL, FFDIM, 0, nullptr, nullptr, nullptr);
}

// Round 9
// 724.468 us; speedup vs baseline: 5.4648x; 1.1494x over previous
//
#include <hip/hip_runtime.h>
#include <hip/hip_bf16.h>
#include <hip/hip_fp16.h>
#include <math.h>

#define SEQ 2048
#define DMODEL 1024
#define NH 16
#define DHEAD 64
#define FFDIM 4096
#define NPOSE 128
#define MLPWID 32
#define EPSV 1e-5f
#define CHUNK 512
#define NCH (SEQ / CHUNK)

typedef unsigned short ushort_t;
typedef unsigned int uint_t;
typedef _Float16 f16;
typedef __attribute__((ext_vector_type(8))) short bf16x8;
typedef __attribute__((ext_vector_type(4))) float f32x4;

union U2H4 { uint2 u; f16 h[4]; };
union U4S8 { uint4 u; ushort_t s[8]; };
union U4H8 { uint4 u; f16 h[8]; };
union U2S4 { uint2 u; ushort_t s[4]; };
union BF8 { bf16x8 v; ushort_t s[8]; uint2 u2[2]; };
union U1H2 { uint_t u; f16 h[2]; };

__device__ __forceinline__ float sigm(float x) {
    return 1.0f / (1.0f + __expf(-x));
}
__device__ __forceinline__ ushort_t f2bf(float f) {
    uint_t u = __float_as_uint(f);
    u += 0x7fffu + ((u >> 16) & 1u);
    return (ushort_t)(u >> 16);
}
__device__ __forceinline__ float bf2f(ushort_t u) {
    return __uint_as_float(((uint_t)u) << 16);
}
__device__ __forceinline__ void gl_lds16(const void* g, void* l) {
    __builtin_amdgcn_global_load_lds((const __attribute__((address_space(1))) uint_t*)g,
                                     (__attribute__((address_space(3))) uint_t*)l, 16, 0, 0);
}

// ---------------- RMSNorm, bf16 out ----------------
__global__ __launch_bounds__(256) void rmsnormbf_k(const float* __restrict__ x,
                                                   const float* __restrict__ w,
                                                   ushort_t* __restrict__ o) {
    int row = blockIdx.x;
    int tid = threadIdx.x;
    const float4* xr = (const float4*)(x + (size_t)row * DMODEL);
    float4 v = xr[tid];
    float ss = v.x * v.x + v.y * v.y + v.z * v.z + v.w * v.w;
#pragma unroll
    for (int d = 1; d < 64; d <<= 1) ss += __shfl_xor(ss, d, 64);
    __shared__ float red[4];
    int lane = tid & 63, wv = tid >> 6;
    if (lane == 0) red[wv] = ss;
    __syncthreads();
    float tot = red[0] + red[1] + red[2] + red[3];
    float r = rsqrtf(tot / (float)DMODEL + EPSV);
    const float4* wr = (const float4*)w;
    float4 wv4 = wr[tid];
    U2S4 ob;
    ob.s[0] = f2bf(v.x * r * wv4.x);
    ob.s[1] = f2bf(v.y * r * wv4.y);
    ob.s[2] = f2bf(v.z * r * wv4.z);
    ob.s[3] = f2bf(v.w * r * wv4.w);
    ((uint2*)(o + (size_t)row * DMODEL))[tid] = ob.u;
}

// ---------------- V transpose: vb[SEQ][DMODEL] bf16 -> vt[NH][DHEAD][SEQ] ----------------
__global__ __launch_bounds__(256) void tv_k(const ushort_t* __restrict__ vb,
                                            ushort_t* __restrict__ vt) {
    int h = blockIdx.y, t0 = blockIdx.x * 64;
    __shared__ ushort_t T[64][76];
    int tid = threadIdx.x;
#pragma unroll
    for (int it = 0; it < 2; it++) {
        int a = tid + it * 256;
        int t = a >> 3, c8 = (a & 7) * 8;
        U4S8 v;
        v.u = *(const uint4*)(vb + (size_t)(t0 + t) * DMODEL + h * 64 + c8);
#pragma unroll
        for (int j = 0; j < 8; j++) T[c8 + j][t] = v.s[j];
    }
    __syncthreads();
#pragma unroll
    for (int it = 0; it < 2; it++) {
        int a = tid + it * 256;
        int d = a >> 3, c8 = (a & 7) * 8;
        U4S8 o;
#pragma unroll
        for (int j = 0; j < 8; j++) o.s[j] = T[d][c8 + j];
        *(uint4*)(vt + ((size_t)h * 64 + d) * SEQ + t0 + c8) = o.u;
    }
}

// ---------------- weight transpose+convert: f32[K][N] -> bf16[N][K] ----------------
__global__ __launch_bounds__(256) void transconv_k(const float* __restrict__ in,
                                                   ushort_t* __restrict__ out,
                                                   int K, int N) {
    __shared__ ushort_t T[64][72];
    int k0 = blockIdx.y * 64, n0 = blockIdx.x * 64;
    int tid = threadIdx.x;
    int r = tid >> 4, c4 = (tid & 15) * 4;
#pragma unroll
    for (int i = 0; i < 4; i++) {
        float4 v = *(const float4*)(in + (size_t)(k0 + r + i * 16) * N + n0 + c4);
        T[c4 + 0][r + i * 16] = f2bf(v.x);
        T[c4 + 1][r + i * 16] = f2bf(v.y);
        T[c4 + 2][r + i * 16] = f2bf(v.z);
        T[c4 + 3][r + i * 16] = f2bf(v.w);
    }
    __syncthreads();
    int n = tid >> 2, kk = (tid & 3) * 16;
    U4S8 o0, o1;
#pragma unroll
    for (int i = 0; i < 8; i++) { o0.s[i] = T[n][kk + i]; o1.s[i] = T[n][kk + 8 + i]; }
    uint4* dst = (uint4*)(out + (size_t)(n0 + n) * K + k0 + kk);
    dst[0] = o0.u;
    dst[1] = o1.u;
}

// ---------------- w1/w3 transpose+convert, row-interleaved (16-col groups) ----------------
// out row for w1 col c: (c>>4)*32 + (c&15); for w3: +16. out[N'=2*N rows][K]
__global__ __launch_bounds__(256) void transconv2_k(const float* __restrict__ w1,
                                                    const float* __restrict__ w3,
                                                    ushort_t* __restrict__ out,
                                                    int K, int N) {
    __shared__ ushort_t T[64][72];
    int k0 = blockIdx.y * 64, n0 = blockIdx.x * 64;
    int tid = threadIdx.x;
    int r = tid >> 4, c4 = (tid & 15) * 4;
    int n = tid >> 2, kk = (tid & 3) * 16;
#pragma unroll
    for (int half = 0; half < 2; half++) {
        const float* in = half ? w3 : w1;
#pragma unroll
        for (int i = 0; i < 4; i++) {
            float4 v = *(const float4*)(in + (size_t)(k0 + r + i * 16) * N + n0 + c4);
            T[c4 + 0][r + i * 16] = f2bf(v.x);
            T[c4 + 1][r + i * 16] = f2bf(v.y);
            T[c4 + 2][r + i * 16] = f2bf(v.z);
            T[c4 + 3][r + i * 16] = f2bf(v.w);
        }
        __syncthreads();
        int gc = n0 + n;
        int rp = (gc >> 4) * 32 + (gc & 15) + half * 16;
        U4S8 o0, o1;
#pragma unroll
        for (int i = 0; i < 8; i++) { o0.s[i] = T[n][kk + i]; o1.s[i] = T[n][kk + 8 + i]; }
        uint4* dst = (uint4*)(out + (size_t)rp * K + k0 + kk);
        dst[0] = o0.u;
        dst[1] = o1.u;
        __syncthreads();
    }
}

// ---------------- bf16 MFMA GEMM 128x128 (TN), XCD-swizzled ----------------
// mode 0: f32 out (+add). mode 1: bf16 out. mode 4: w1w3-interleaved silu-mul,
//   out bf16 [M][N/2], colOut=(c>>5)*16+(c&15), pairs acc[m][n]/acc[m][n+1].
__global__ __launch_bounds__(256) void gemm_bf16_k(const ushort_t* __restrict__ A,
                                                   const ushort_t* __restrict__ Bt,
                                                   const float* __restrict__ add,
                                                   void* __restrict__ Cout,
                                                   int M, int N, int K, int mode) {
    __shared__ ushort_t Al[128 * 32];
    __shared__ ushort_t Bl[128 * 32];
    int tid = threadIdx.x;
    int lane = tid & 63, wave = tid >> 6;
    int gx = gridDim.x, gy = gridDim.y;
    int nwg = gx * gy;
    int bx = blockIdx.x, by = blockIdx.y;
    if ((nwg & 7) == 0) {
        int flat = by * gx + bx;
        int cpx = nwg >> 3;
        int l = (flat & 7) * cpx + (flat >> 3);
        bx = l / gy;
        by = l % gy;
    }
    int brow = by * 128, bcol = bx * 128;
    int wr = (wave >> 1) * 64, wc = (wave & 1) * 64;
    f32x4 acc[4][4];
#pragma unroll
    for (int m = 0; m < 4; m++)
#pragma unroll
        for (int n = 0; n < 4; n++) acc[m][n] = (f32x4){0.f, 0.f, 0.f, 0.f};

    const ushort_t* Ag = A + (size_t)(brow + (tid >> 2)) * K + (tid & 3) * 8;
    const ushort_t* Bg = Bt + (size_t)(bcol + (tid >> 2)) * K + (tid & 3) * 8;
    ushort_t* Ald = &Al[wave * 512];
    ushort_t* Bld = &Bl[wave * 512];
    size_t rstep = (size_t)64 * K;

    for (int k0 = 0; k0 < K; k0 += 32) {
        gl_lds16(Ag + k0, Ald);
        gl_lds16(Ag + k0 + rstep, Ald + 2048);
        gl_lds16(Bg + k0, Bld);
        gl_lds16(Bg + k0 + rstep, Bld + 2048);
        __syncthreads();
        bf16x8 af[4], bfr[4];
        int arow = wr + (lane & 15);
        int brw = wc + (lane & 15);
        int kof = (lane >> 4) * 8;
#pragma unroll
        for (int m = 0; m < 4; m++) af[m] = *(const bf16x8*)&Al[(arow + m * 16) * 32 + kof];
#pragma unroll
        for (int n = 0; n < 4; n++) bfr[n] = *(const bf16x8*)&Bl[(brw + n * 16) * 32 + kof];
#pragma unroll
        for (int m = 0; m < 4; m++)
#pragma unroll
            for (int n = 0; n < 4; n++)
                acc[m][n] = __builtin_amdgcn_mfma_f32_16x16x32_bf16(af[m], bfr[n], acc[m][n], 0, 0, 0);
        __syncthreads();
    }
    int crow0 = brow + wr + (lane >> 4) * 4;
    int ccol = bcol + wc + (lane & 15);
#pragma unroll
    for (int m = 0; m < 4; m++)
#pragma unroll
        for (int j = 0; j < 4; j++) {
            int row = crow0 + m * 16 + j;
            if (mode == 4) {
#pragma unroll
                for (int n = 0; n < 4; n += 2) {
                    int c = ccol + n * 16;
                    int colOut = (c >> 5) * 16 + (c & 15);
                    float v1 = acc[m][n][j];
                    float v3 = acc[m][n + 1][j];
                    ((ushort_t*)Cout)[(size_t)row * (N / 2) + colOut] =
                        f2bf(v1 * sigm(v1) * v3);
                }
            } else {
#pragma unroll
                for (int n = 0; n < 4; n++) {
                    int col = ccol + n * 16;
                    float v = acc[m][n][j];
                    if (mode == 0) {
                        if (add) v += add[(size_t)row * N + col];
                        ((float*)Cout)[(size_t)row * N + col] = v;
                    } else {
                        ((ushort_t*)Cout)[(size_t)row * N + col] = f2bf(v);
                    }
                }
            }
        }
}

// ---------------- bf16 MFMA GEMM 64x64 (TN), XCD-swizzled ----------------
// mode 0: f32 out (+add). mode 1: bf16. mode 2: qkv split (Cout=qh,p1=ql,p2=kb,p3=vb).
__global__ __launch_bounds__(256) void gemm64_k(const ushort_t* __restrict__ A,
                                                const ushort_t* __restrict__ Bt,
                                                const float* __restrict__ add,
                                                void* __restrict__ Cout,
                                                int M, int N, int K, int mode,
                                                ushort_t* __restrict__ p1,
                                                ushort_t* __restrict__ p2,
                                                ushort_t* __restrict__ p3) {
    __shared__ ushort_t Al[64 * 32];
    __shared__ ushort_t Bl[64 * 32];
    int tid = threadIdx.x;
    int lane = tid & 63, wave = tid >> 6;
    int gx = gridDim.x, gy = gridDim.y;
    int nwg = gx * gy;
    int bx = blockIdx.x, by = blockIdx.y;
    if ((nwg & 7) == 0) {
        int flat = by * gx + bx;
        int cpx = nwg >> 3;
        int l = (flat & 7) * cpx + (flat >> 3);
        bx = l / gy;
        by = l % gy;
    }
    int brow = by * 64, bcol = bx * 64;
    int wr = (wave >> 1) * 32, wc = (wave & 1) * 32;
    f32x4 acc[2][2];
#pragma unroll
    for (int m = 0; m < 2; m++)
#pragma unroll
        for (int n = 0; n < 2; n++) acc[m][n] = (f32x4){0.f, 0.f, 0.f, 0.f};

    const ushort_t* Ag = A + (size_t)(brow + (tid >> 2)) * K + (tid & 3) * 8;
    const ushort_t* Bg = Bt + (size_t)(bcol + (tid >> 2)) * K + (tid & 3) * 8;
    ushort_t* Ald = &Al[wave * 512];
    ushort_t* Bld = &Bl[wave * 512];

    for (int k0 = 0; k0 < K; k0 += 32) {
        gl_lds16(Ag + k0, Ald);
        gl_lds16(Bg + k0, Bld);
        __syncthreads();
        bf16x8 af[2], bfr[2];
        int kof = (lane >> 4) * 8;
#pragma unroll
        for (int m = 0; m < 2; m++)
            af[m] = *(const bf16x8*)&Al[(wr + m * 16 + (lane & 15)) * 32 + kof];
#pragma unroll
        for (int n = 0; n < 2; n++)
            bfr[n] = *(const bf16x8*)&Bl[(wc + n * 16 + (lane & 15)) * 32 + kof];
#pragma unroll
        for (int m = 0; m < 2; m++)
#pragma unroll
            for (int n = 0; n < 2; n++)
                acc[m][n] = __builtin_amdgcn_mfma_f32_16x16x32_bf16(af[m], bfr[n], acc[m][n], 0, 0, 0);
        __syncthreads();
    }
    int crow0 = brow + wr + (lane >> 4) * 4;
    int ccol = bcol + wc + (lane & 15);
#pragma unroll
    for (int m = 0; m < 2; m++)
#pragma unroll
        for (int j = 0; j < 2 * 2; j++) {
            int row = crow0 + m * 16 + j;
#pragma unroll
            for (int n = 0; n < 2; n++) {
                int col = ccol + n * 16;
                float v = acc[m][n][j];
                if (mode == 0) {
                    if (add) v += add[(size_t)row * N + col];
                    ((float*)Cout)[(size_t)row * N + col] = v;
                } else if (mode == 1) {
                    ((ushort_t*)Cout)[(size_t)row * N + col] = f2bf(v);
                } else {
                    size_t o = (size_t)row * DMODEL;
                    if (col < DMODEL) {
                        ushort_t hb = f2bf(v);
                        ((ushort_t*)Cout)[o + col] = hb;
                        p1[o + col] = f2bf(v - bf2f(hb));
                    } else if (col < 2 * DMODEL) {
                        p2[o + col - DMODEL] = f2bf(v);
                    } else {
                        p3[o + col - 2 * DMODEL] = f2bf(v);
                    }
                }
            }
        }
}

// ---------------- MFMA scores: sc[h][il][j] = (qh+ql)_i . kb_j / 8 ----------------
__global__ __launch_bounds__(256) void scoresm_k(const ushort_t* __restrict__ qh,
                                                 const ushort_t* __restrict__ ql,
                                                 const ushort_t* __restrict__ kb,
                                                 f16* __restrict__ sc, int cb) {
    int h = blockIdx.z;
    int il0 = blockIdx.y * 64;
    int j0 = blockIdx.x * 64;
    __shared__ ushort_t Qh[64][72];
    __shared__ ushort_t Ql[64][72];
    __shared__ ushort_t Kb[64][72];
    int tid = threadIdx.x;
    {
        int r = tid >> 2, c0 = (tid & 3) * 16;
        const ushort_t* p;
        p = qh + (size_t)(cb + il0 + r) * DMODEL + h * 64 + c0;
        *(uint4*)&Qh[r][c0] = *(const uint4*)p;
        *(uint4*)&Qh[r][c0 + 8] = *(const uint4*)(p + 8);
        p = ql + (size_t)(cb + il0 + r) * DMODEL + h * 64 + c0;
        *(uint4*)&Ql[r][c0] = *(const uint4*)p;
        *(uint4*)&Ql[r][c0 + 8] = *(const uint4*)(p + 8);
        p = kb + (size_t)(j0 + r) * DMODEL + h * 64 + c0;
        *(uint4*)&Kb[r][c0] = *(const uint4*)p;
        *(uint4*)&Kb[r][c0 + 8] = *(const uint4*)(p + 8);
    }
    __syncthreads();
    int lane = tid & 63, wave = tid >> 6;
    int wr = (wave >> 1) * 32, wc = (wave & 1) * 32;
    f32x4 acc[2][2];
#pragma unroll
    for (int m = 0; m < 2; m++)
#pragma unroll
        for (int n = 0; n < 2; n++) acc[m][n] = (f32x4){0.f, 0.f, 0.f, 0.f};
#pragma unroll
    for (int ks = 0; ks < 2; ks++) {
        int kof = ks * 32 + (lane >> 4) * 8;
        bf16x8 aH[2], aL[2], bK[2];
#pragma unroll
        for (int m = 0; m < 2; m++) {
            int ar = wr + m * 16 + (lane & 15);
            aH[m] = *(const bf16x8*)&Qh[ar][kof];
            aL[m] = *(const bf16x8*)&Ql[ar][kof];
        }
#pragma unroll
        for (int n = 0; n < 2; n++) bK[n] = *(const bf16x8*)&Kb[wc + n * 16 + (lane & 15)][kof];
#pragma unroll
        for (int m = 0; m < 2; m++)
#pragma unroll
            for (int n = 0; n < 2; n++) {
                acc[m][n] = __builtin_amdgcn_mfma_f32_16x16x32_bf16(aH[m], bK[n], acc[m][n], 0, 0, 0);
                acc[m][n] = __builtin_amdgcn_mfma_f32_16x16x32_bf16(aL[m], bK[n], acc[m][n], 0, 0, 0);
            }
    }
#pragma unroll
    for (int m = 0; m < 2; m++)
#pragma unroll
        for (int j = 0; j < 4; j++) {
            int il = il0 + wr + m * 16 + (lane >> 4) * 4 + j;
#pragma unroll
            for (int n = 0; n < 2; n++) {
                int jj = j0 + wc + n * 16 + (lane & 15);
                sc[((size_t)h * CHUNK + il) * SEQ + jj] = (f16)(acc[m][n][j] * 0.125f);
            }
        }
}

// ---------------- logits_int -> f16 (reads qh+ql) ----------------
__global__ __launch_bounds__(256) void copelogits_k(const ushort_t* __restrict__ qh,
                                                    const ushort_t* __restrict__ ql,
                                                    const float* __restrict__ pe,
                                                    f16* __restrict__ li) {
    int s1 = blockIdx.x;
    int tid = threadIdx.x;
    __shared__ float PE[DHEAD * NPOSE];
    __shared__ float QR[DMODEL];
    for (int i = tid; i < DHEAD * NPOSE; i += 256) PE[i] = pe[i];
    for (int i = tid; i < DMODEL; i += 256)
        QR[i] = bf2f(qh[(size_t)s1 * DMODEL + i]) + bf2f(ql[(size_t)s1 * DMODEL + i]);
    __syncthreads();
#pragma unroll
    for (int j = 0; j < 8; j++) {
        int o = j * 256 + tid;
        int h = o >> 7, n = o & 127;
        const float* qhp = &QR[h * DHEAD];
        float acc = 0.0f;
#pragma unroll 8
        for (int d = 0; d < DHEAD; d++) acc += qhp[d] * PE[d * NPOSE + n];
        li[(size_t)s1 * (NH * NPOSE) + o] = (f16)acc;
    }
}

// ---------------- fused CoPE: scan + bias + MFMA MLP + rowstat (512 thr) ----------------
#define CSTR 2050
__global__ __launch_bounds__(512) void cope_k(f16* __restrict__ sc,
                                              const f16* __restrict__ li,
                                              const float* __restrict__ w1,
                                              const float* __restrict__ b1,
                                              const float* __restrict__ w2,
                                              const float* __restrict__ b2,
                                              float* __restrict__ rowmax,
                                              float* __restrict__ rowsum,
                                              int cb) {
    __shared__ f16 C[32 * CSTR];
    __shared__ float Lif[NH * 129];
    __shared__ ushort_t HMB[8][2][16 * 36];
    int r = blockIdx.x;
    int tid = threadIdx.x;
    int lane = tid & 63, wv = tid >> 6;

    for (int h = 0; h < NH; h++) {
        const uint_t* s32 = (const uint_t*)(sc + ((size_t)h * CHUNK + r) * SEQ);
        uint_t* d32 = (uint_t*)&C[h * CSTR];
        d32[tid] = s32[tid];
        d32[tid + 512] = s32[tid + 512];
    }
    {
        const f16* lsrc = li + (size_t)(cb + r) * (NH * NPOSE);
        for (int i = tid; i < NH * NPOSE; i += 512) {
            Lif[(i >> 7) * 129 + (i & 127)] = (float)lsrc[i];
        }
    }
    __syncthreads();

    {
        int h0 = wv * 2, h1 = h0 + 1;
        f16* c0 = &C[h0 * CSTR];
        f16* c1 = &C[h1 * CSTR];
        f16* bias0 = &C[(16 + h0) * CSTR];
        f16* bias1 = &C[(16 + h1) * CSTR];
        const float* l0 = &Lif[h0 * 129];
        const float* l1 = &Lif[h1 * 129];
        float carry0 = 0.0f, carry1 = 0.0f;
        for (int c = SEQ / 64 - 1; c >= 0; c--) {
            int t = c * 64 + lane;
            float g0 = sigm((float)c0[t]);
            float g1 = sigm((float)c1[t]);
#pragma unroll
            for (int dd = 1; dd < 64; dd <<= 1) {
                float o0 = __shfl_down(g0, dd, 64);
                float o1 = __shfl_down(g1, dd, 64);
                bool ok = (lane + dd < 64);
                g0 = ok ? g0 + o0 : g0;
                g1 = ok ? g1 + o1 : g1;
            }
            float tot0 = __shfl(g0, 0, 64);
            float tot1 = __shfl(g1, 0, 64);
            float pos0 = fminf(g0 + carry0, 127.0f); carry0 += tot0;
            float pos1 = fminf(g1 + carry1, 127.0f); carry1 += tot1;
            int fl0 = (int)pos0; float fr0 = pos0 - (float)fl0;
            int fl1 = (int)pos1; float fr1 = pos1 - (float)fl1;
            bias0[t] = (f16)(l0[(fl0 < 127) ? fl0 + 1 : 127] * fr0 + l0[fl0] * (1.0f - fr0));
            bias1[t] = (f16)(l1[(fl1 < 127) ? fl1 + 1 : 127] * fr1 + l1[fl1] * (1.0f - fr1));
        }
    }
    __syncthreads();

    int fkg = lane >> 4;
    int fc = lane & 15;
    BF8 w1fH[2], w1fL[2], w2fH, w2fL;
    float b1v[2], b2v;
#pragma unroll
    for (int half = 0; half < 2; half++) {
#pragma unroll
        for (int j = 0; j < 8; j++) {
            float wval = w1[(fkg * 8 + j) * MLPWID + half * 16 + fc];
            ushort_t hb = f2bf(wval);
            w1fH[half].s[j] = hb;
            w1fL[half].s[j] = f2bf(wval - bf2f(hb));
        }
        b1v[half] = b1[half * 16 + fc];
    }
#pragma unroll
    for (int j = 0; j < 8; j++) {
        float wval = w2[(fkg * 8 + j) * NH + fc];
        ushort_t hb = f2bf(wval);
        w2fH.s[j] = hb;
        w2fL.s[j] = f2bf(wval - bf2f(hb));
    }
    b2v = b2[fc];

    ushort_t* hmbH = HMB[wv][0];
    ushort_t* hmbL = HMB[wv][1];
    for (int tt = wv; tt < SEQ / 16; tt += 8) {
        int t0 = tt * 16;
        BF8 afH, afL;
#pragma unroll
        for (int j = 0; j < 8; j++) {
            int f = fkg * 8 + j;
            float val = (float)C[f * CSTR + t0 + fc];
            ushort_t hb = f2bf(val);
            afH.s[j] = hb;
            afL.s[j] = f2bf(val - bf2f(hb));
        }
        f32x4 acc0 = (f32x4){b1v[0], b1v[0], b1v[0], b1v[0]};
        f32x4 acc1 = (f32x4){b1v[1], b1v[1], b1v[1], b1v[1]};
        acc0 = __builtin_amdgcn_mfma_f32_16x16x32_bf16(afH.v, w1fH[0].v, acc0, 0, 0, 0);
        acc0 = __builtin_amdgcn_mfma_f32_16x16x32_bf16(afH.v, w1fL[0].v, acc0, 0, 0, 0);
        acc0 = __builtin_amdgcn_mfma_f32_16x16x32_bf16(afL.v, w1fH[0].v, acc0, 0, 0, 0);
        acc1 = __builtin_amdgcn_mfma_f32_16x16x32_bf16(afH.v, w1fH[1].v, acc1, 0, 0, 0);
        acc1 = __builtin_amdgcn_mfma_f32_16x16x32_bf16(afH.v, w1fL[1].v, acc1, 0, 0, 0);
        acc1 = __builtin_amdgcn_mfma_f32_16x16x32_bf16(afL.v, w1fH[1].v, acc1, 0, 0, 0);
#pragma unroll
        for (int j2 = 0; j2 < 4; j2++) {
            int p = fkg * 4 + j2;
            float h0 = acc0[j2]; h0 = h0 * sigm(h0);
            float h1 = acc1[j2]; h1 = h1 * sigm(h1);
            ushort_t h0b = f2bf(h0), h1b = f2bf(h1);
            hmbH[p * 36 + fc] = h0b;
            hmbH[p * 36 + 16 + fc] = h1b;
            hmbL[p * 36 + fc] = f2bf(h0 - bf2f(h0b));
            hmbL[p * 36 + 16 + fc] = f2bf(h1 - bf2f(h1b));
        }
        BF8 hfH, hfL;
        hfH.u2[0] = *(const uint2*)&hmbH[fc * 36 + fkg * 8];
        hfH.u2[1] = *(const uint2*)&hmbH[fc * 36 + fkg * 8 + 4];
        hfL.u2[0] = *(const uint2*)&hmbL[fc * 36 + fkg * 8];
        hfL.u2[1] = *(const uint2*)&hmbL[fc * 36 + fkg * 8 + 4];
        f32x4 acc2 = (f32x4){b2v, b2v, b2v, b2v};
        acc2 = __builtin_amdgcn_mfma_f32_16x16x32_bf16(hfH.v, w2fH.v, acc2, 0, 0, 0);
        acc2 = __builtin_amdgcn_mfma_f32_16x16x32_bf16(hfH.v, w2fL.v, acc2, 0, 0, 0);
        acc2 = __builtin_amdgcn_mfma_f32_16x16x32_bf16(hfL.v, w2fH.v, acc2, 0, 0, 0);
#pragma unroll
        for (int j2 = 0; j2 < 4; j2 += 2) {
            uint_t* pp = (uint_t*)&C[fc * CSTR + t0 + fkg * 4 + j2];
            U1H2 old, neu;
            old.u = *pp;
            neu.h[0] = (f16)((float)old.h[0] + acc2[j2]);
            neu.h[1] = (f16)((float)old.h[1] + acc2[j2 + 1]);
            *pp = neu.u;
        }
    }
    __syncthreads();

#pragma unroll
    for (int hh = 0; hh < 2; hh++) {
        int h = wv * 2 + hh;
        const f16* row = &C[h * CSTR];
        float m = -1e30f;
        for (int c = 0; c < SEQ / 64; c++) m = fmaxf(m, (float)row[c * 64 + lane]);
#pragma unroll
        for (int d = 1; d < 64; d <<= 1) m = fmaxf(m, __shfl_xor(m, d, 64));
        float s = 0.0f;
        for (int c = 0; c < SEQ / 64; c++) s += __expf((float)row[c * 64 + lane] - m);
#pragma unroll
        for (int d = 1; d < 64; d <<= 1) s += __shfl_xor(s, d, 64);
        if (lane == 0) {
            rowmax[(size_t)h * SEQ + cb + r] = m;
            rowsum[(size_t)h * SEQ + cb + r] = s;
        }
    }

    for (int h = 0; h < NH; h++) {
        const uint_t* s32 = (const uint_t*)&C[h * CSTR];
        uint_t* d32 = (uint_t*)(sc + ((size_t)h * CHUNK + r) * SEQ);
        d32[tid] = s32[tid];
        d32[tid + 512] = s32[tid + 512];
    }
}

// ---------------- MFMA softmax+PV -> aob bf16 ----------------
__global__ __launch_bounds__(256) void pvm_k(const f16* __restrict__ sc,
                                             const ushort_t* __restrict__ vt,
                                             const float* __restrict__ rowmax,
                                             const float* __restrict__ rowsum,
                                             ushort_t* __restrict__ aob, int cb) {
    int h = blockIdx.y;
    int s0 = blockIdx.x * 32;
    __shared__ ushort_t P[32][72];
    __shared__ ushort_t Vt[64][72];
    __shared__ float rm[32];
    __shared__ float ri[32];
    int tid = threadIdx.x;
    int lane = tid & 63, wave = tid >> 6;
    if (tid < 32) {
        rm[tid] = rowmax[(size_t)h * SEQ + cb + s0 + tid];
        ri[tid] = 1.0f / rowsum[(size_t)h * SEQ + cb + s0 + tid];
    }
    __syncthreads();
    int wr = (wave >> 1) * 16, wc = (wave & 1) * 32;
    f32x4 acc[2];
    acc[0] = (f32x4){0.f, 0.f, 0.f, 0.f};
    acc[1] = (f32x4){0.f, 0.f, 0.f, 0.f};
    int pr = tid >> 3, pc = (tid & 7) * 8;
    int vr = tid >> 2, vc = (tid & 3) * 16;
    for (int t0 = 0; t0 < SEQ; t0 += 64) {
        {
            U4H8 lg;
            lg.u = *(const uint4*)(sc + ((size_t)h * CHUNK + s0 + pr) * SEQ + t0 + pc);
            float rmv = rm[pr], riv = ri[pr];
            U4S8 o;
#pragma unroll
            for (int j = 0; j < 8; j++) o.s[j] = f2bf(__expf((float)lg.h[j] - rmv) * riv);
            *(uint4*)&P[pr][pc] = o.u;
            const ushort_t* vp = vt + ((size_t)h * 64 + vr) * SEQ + t0 + vc;
            *(uint4*)&Vt[vr][vc] = *(const uint4*)vp;
            *(uint4*)&Vt[vr][vc + 8] = *(const uint4*)(vp + 8);
        }
        __syncthreads();
#pragma unroll
        for (int ks = 0; ks < 2; ks++) {
            int kof = ks * 32 + (lane >> 4) * 8;
            bf16x8 pa = *(const bf16x8*)&P[wr + (lane & 15)][kof];
#pragma unroll
            for (int n = 0; n < 2; n++) {
                bf16x8 vb = *(const bf16x8*)&Vt[wc + n * 16 + (lane & 15)][kof];
                acc[n] = __builtin_amdgcn_mfma_f32_16x16x32_bf16(pa, vb, acc[n], 0, 0, 0);
            }
        }
        __syncthreads();
    }
#pragma unroll
    for (int j = 0; j < 4; j++) {
        int s = cb + s0 + wr + (lane >> 4) * 4 + j;
#pragma unroll
        for (int n = 0; n < 2; n++) {
            int d = h * 64 + wc + n * 16 + (lane & 15);
            aob[(size_t)s * DMODEL + d] = f2bf(acc[n][j]);
        }
    }
}

extern "C" void kernel_launch(void* const* d_in, const int* in_sizes, int n_in,
                              void* d_out, int out_size, void* d_ws, size_t ws_size,
                              hipStream_t stream) {
    const float* x = (const float*)d_in[0];
    const float* wq = (const float*)d_in[1];
    const float* wk = (const float*)d_in[2];
    const float* wv = (const float*)d_in[3];
    const float* wo = (const float*)d_in[4];
    const float* pos_emb = (const float*)d_in[5];
    const float* mlp_w1 = (const float*)d_in[6];
    const float* mlp_b1 = (const float*)d_in[7];
    const float* mlp_w2 = (const float*)d_in[8];
    const float* mlp_b2 = (const float*)d_in[9];
    const float* ffn_w1 = (const float*)d_in[10];
    const float* ffn_w2 = (const float*)d_in[11];
    const float* ffn_w3 = (const float*)d_in[12];
    const float* attn_norm_w = (const float*)d_in[13];
    const float* ffn_norm_w = (const float*)d_in[14];
    float* out = (float*)d_out;

    char* ws = (char*)d_ws;
    const size_t MB = 1024 * 1024;
    ushort_t* nxb = (ushort_t*)(ws + 0);             // 0-4
    ushort_t* qh = (ushort_t*)(ws + 4 * MB);         // 4-8   (phase C: nxb2)
    ushort_t* ql = (ushort_t*)(ws + 8 * MB);         // 8-12  (phase C: g1b 8-24)
    ushort_t* kb = (ushort_t*)(ws + 12 * MB);        // 12-16
    ushort_t* vb = (ushort_t*)(ws + 16 * MB);        // 16-20
    ushort_t* vt = (ushort_t*)(ws + 20 * MB);        // 20-24
    f16* li = (f16*)(ws + 24 * MB);                  // 24-32
    float* rowmax = (float*)(ws + 32 * MB);          // 128KB
    float* rowsum = (float*)(ws + 32 * MB + 512 * 1024);
    ushort_t* aob = (ushort_t*)(ws + 33 * MB);       // 33-37
    float* x1 = (float*)(ws + 37 * MB);              // 37-45
    ushort_t* wqkvt = (ushort_t*)(ws + 45 * MB);     // 45-51 (phase 1)
    f16* sc = (f16*)(ws + 45 * MB);                  // 45-77 (phase 2)
    ushort_t* wot = (ushort_t*)(ws + 45 * MB);       // 45-47 (phase B)
    ushort_t* w13t = (ushort_t*)(ws + 47 * MB);      // 47-63 (interleaved, 16MB)
    ushort_t* w2t = (ushort_t*)(ws + 63 * MB);       // 63-71 -> peak 77MB
    ushort_t* nxb2 = (ushort_t*)(ws + 4 * MB);
    ushort_t* g1b = (ushort_t*)(ws + 8 * MB);        // 8-24

    // ---- phase 1: norm + fused QKV (64-tile, 1536 blocks) ----
    transconv_k<<<dim3(DMODEL / 64, DMODEL / 64), 256, 0, stream>>>(wq, wqkvt, DMODEL, DMODEL);
    transconv_k<<<dim3(DMODEL / 64, DMODEL / 64), 256, 0, stream>>>(wk, wqkvt + 1024 * 1024, DMODEL, DMODEL);
    transconv_k<<<dim3(DMODEL / 64, DMODEL / 64), 256, 0, stream>>>(wv, wqkvt + 2 * 1024 * 1024, DMODEL, DMODEL);
    rmsnormbf_k<<<SEQ, 256, 0, stream>>>(x, attn_norm_w, nxb);
    gemm64_k<<<dim3(3 * DMODEL / 64, SEQ / 64), 256, 0, stream>>>(
        nxb, wqkvt, nullptr, qh, SEQ, 3 * DMODEL, DMODEL, 2, ql, kb, vb);
    copelogits_k<<<SEQ, 256, 0, stream>>>(qh, ql, pos_emb, li);
    tv_k<<<dim3(SEQ / 64, NH), 256, 0, stream>>>(vb, vt);

    // ---- phase 2: attention chunks ----
    for (int ch = 0; ch < NCH; ch++) {
        int cb = ch * CHUNK;
        scoresm_k<<<dim3(SEQ / 64, CHUNK / 64, NH), 256, 0, stream>>>(qh, ql, kb, sc, cb);
        cope_k<<<CHUNK, 512, 0, stream>>>(sc, li, mlp_w1, mlp_b1, mlp_w2, mlp_b2,
                                          rowmax, rowsum, cb);
        pvm_k<<<dim3(CHUNK / 32, NH), 256, 0, stream>>>(sc, vt, rowmax, rowsum, aob, cb);
    }

    // ---- phase B: out @ wo + x (64-tile, 512 blocks) ----
    transconv_k<<<dim3(DMODEL / 64, DMODEL / 64), 256, 0, stream>>>(wo, wot, DMODEL, DMODEL);
    gemm64_k<<<dim3(DMODEL / 64, SEQ / 64), 256, 0, stream>>>(
        aob, wot, x, x1, SEQ, DMODEL, DMODEL, 0, nullptr, nullptr, nullptr);

    // ---- phase C: FFN ----
    rmsnormbf_k<<<SEQ, 256, 0, stream>>>(x1, ffn_norm_w, nxb2);
    transconv2_k<<<dim3(FFDIM / 64, DMODEL / 64), 256, 0, stream>>>(ffn_w1, ffn_w3, w13t, DMODEL, FFDIM);
    transconv_k<<<dim3(DMODEL / 64, FFDIM / 64), 256, 0, stream>>>(ffn_w2, w2t, FFDIM, DMODEL);
    // fused w1+w3 GEMM (128-tile, 1024 blocks), silu-mul epilogue -> g1b [SEQ][FFDIM] bf16
    gemm_bf16_k<<<dim3(2 * FFDIM / 128, SEQ / 128), 256, 0, stream>>>(
        nxb2, w13t, nullptr, g1b, SEQ, 2 * FFDIM, DMODEL, 4);
    // w2 GEMM (64-tile, 512 blocks, K=4096)
    gemm64_k<<<dim3(DMODEL / 64, SEQ / 64), 256, 0, stream>>>(
        g1b, w2t, x1, out, SEQ, DMODEL, FFDIM, 0, nullptr, nullptr, nullptr);
}

// Round 10
// 663.198 us; speedup vs baseline: 5.9696x; 1.0924x over previous
//
#include <hip/hip_runtime.h>
#include <hip/hip_bf16.h>
#include <hip/hip_fp16.h>
#include <math.h>

#define SEQ 2048
#define DMODEL 1024
#define NH 16
#define DHEAD 64
#define FFDIM 4096
#define NPOSE 128
#define MLPWID 32
#define EPSV 1e-5f
#define CHUNK 512
#define NCH (SEQ / CHUNK)

typedef unsigned short ushort_t;
typedef unsigned int uint_t;
typedef _Float16 f16;
typedef __attribute__((ext_vector_type(8))) short bf16x8;
typedef __attribute__((ext_vector_type(4))) float f32x4;

union U2H4 { uint2 u; f16 h[4]; };
union U4S8 { uint4 u; ushort_t s[8]; };
union U4H8 { uint4 u; f16 h[8]; };
union U2S4 { uint2 u; ushort_t s[4]; };
union BF8 { bf16x8 v; ushort_t s[8]; uint2 u2[2]; };
union U1H2 { uint_t u; f16 h[2]; };

__device__ __forceinline__ float sigm(float x) {
    return 1.0f / (1.0f + __expf(-x));
}
__device__ __forceinline__ ushort_t f2bf(float f) {
    uint_t u = __float_as_uint(f);
    u += 0x7fffu + ((u >> 16) & 1u);
    return (ushort_t)(u >> 16);
}
__device__ __forceinline__ float bf2f(ushort_t u) {
    return __uint_as_float(((uint_t)u) << 16);
}
__device__ __forceinline__ void gl_lds16(const void* g, void* l) {
    __builtin_amdgcn_global_load_lds((const __attribute__((address_space(1))) uint_t*)g,
                                     (__attribute__((address_space(3))) uint_t*)l, 16, 0, 0);
}

// ---------------- RMSNorm, bf16 out ----------------
__global__ __launch_bounds__(256) void rmsnormbf_k(const float* __restrict__ x,
                                                   const float* __restrict__ w,
                                                   ushort_t* __restrict__ o) {
    int row = blockIdx.x;
    int tid = threadIdx.x;
    const float4* xr = (const float4*)(x + (size_t)row * DMODEL);
    float4 v = xr[tid];
    float ss = v.x * v.x + v.y * v.y + v.z * v.z + v.w * v.w;
#pragma unroll
    for (int d = 1; d < 64; d <<= 1) ss += __shfl_xor(ss, d, 64);
    __shared__ float red[4];
    int lane = tid & 63, wv = tid >> 6;
    if (lane == 0) red[wv] = ss;
    __syncthreads();
    float tot = red[0] + red[1] + red[2] + red[3];
    float r = rsqrtf(tot / (float)DMODEL + EPSV);
    const float4* wr = (const float4*)w;
    float4 wv4 = wr[tid];
    U2S4 ob;
    ob.s[0] = f2bf(v.x * r * wv4.x);
    ob.s[1] = f2bf(v.y * r * wv4.y);
    ob.s[2] = f2bf(v.z * r * wv4.z);
    ob.s[3] = f2bf(v.w * r * wv4.w);
    ((uint2*)(o + (size_t)row * DMODEL))[tid] = ob.u;
}

// ---------------- V transpose: vb[SEQ][DMODEL] bf16 -> vt[NH][DHEAD][SEQ] ----------------
__global__ __launch_bounds__(256) void tv_k(const ushort_t* __restrict__ vb,
                                            ushort_t* __restrict__ vt) {
    int h = blockIdx.y, t0 = blockIdx.x * 64;
    __shared__ ushort_t T[64][76];
    int tid = threadIdx.x;
#pragma unroll
    for (int it = 0; it < 2; it++) {
        int a = tid + it * 256;
        int t = a >> 3, c8 = (a & 7) * 8;
        U4S8 v;
        v.u = *(const uint4*)(vb + (size_t)(t0 + t) * DMODEL + h * 64 + c8);
#pragma unroll
        for (int j = 0; j < 8; j++) T[c8 + j][t] = v.s[j];
    }
    __syncthreads();
#pragma unroll
    for (int it = 0; it < 2; it++) {
        int a = tid + it * 256;
        int d = a >> 3, c8 = (a & 7) * 8;
        U4S8 o;
#pragma unroll
        for (int j = 0; j < 8; j++) o.s[j] = T[d][c8 + j];
        *(uint4*)(vt + ((size_t)h * 64 + d) * SEQ + t0 + c8) = o.u;
    }
}

// ---------------- weight transpose+convert: f32[K][N] -> bf16[N][K] ----------------
__global__ __launch_bounds__(256) void transconv_k(const float* __restrict__ in,
                                                   ushort_t* __restrict__ out,
                                                   int K, int N) {
    __shared__ ushort_t T[64][72];
    int k0 = blockIdx.y * 64, n0 = blockIdx.x * 64;
    int tid = threadIdx.x;
    int r = tid >> 4, c4 = (tid & 15) * 4;
#pragma unroll
    for (int i = 0; i < 4; i++) {
        float4 v = *(const float4*)(in + (size_t)(k0 + r + i * 16) * N + n0 + c4);
        T[c4 + 0][r + i * 16] = f2bf(v.x);
        T[c4 + 1][r + i * 16] = f2bf(v.y);
        T[c4 + 2][r + i * 16] = f2bf(v.z);
        T[c4 + 3][r + i * 16] = f2bf(v.w);
    }
    __syncthreads();
    int n = tid >> 2, kk = (tid & 3) * 16;
    U4S8 o0, o1;
#pragma unroll
    for (int i = 0; i < 8; i++) { o0.s[i] = T[n][kk + i]; o1.s[i] = T[n][kk + 8 + i]; }
    uint4* dst = (uint4*)(out + (size_t)(n0 + n) * K + k0 + kk);
    dst[0] = o0.u;
    dst[1] = o1.u;
}

// ---------------- w1/w3 transpose+convert, row-interleaved (16-col groups) ----------------
__global__ __launch_bounds__(256) void transconv2_k(const float* __restrict__ w1,
                                                    const float* __restrict__ w3,
                                                    ushort_t* __restrict__ out,
                                                    int K, int N) {
    __shared__ ushort_t T[64][72];
    int k0 = blockIdx.y * 64, n0 = blockIdx.x * 64;
    int tid = threadIdx.x;
    int r = tid >> 4, c4 = (tid & 15) * 4;
    int n = tid >> 2, kk = (tid & 3) * 16;
#pragma unroll
    for (int half = 0; half < 2; half++) {
        const float* in = half ? w3 : w1;
#pragma unroll
        for (int i = 0; i < 4; i++) {
            float4 v = *(const float4*)(in + (size_t)(k0 + r + i * 16) * N + n0 + c4);
            T[c4 + 0][r + i * 16] = f2bf(v.x);
            T[c4 + 1][r + i * 16] = f2bf(v.y);
            T[c4 + 2][r + i * 16] = f2bf(v.z);
            T[c4 + 3][r + i * 16] = f2bf(v.w);
        }
        __syncthreads();
        int gc = n0 + n;
        int rp = (gc >> 4) * 32 + (gc & 15) + half * 16;
        U4S8 o0, o1;
#pragma unroll
        for (int i = 0; i < 8; i++) { o0.s[i] = T[n][kk + i]; o1.s[i] = T[n][kk + 8 + i]; }
        uint4* dst = (uint4*)(out + (size_t)rp * K + k0 + kk);
        dst[0] = o0.u;
        dst[1] = o1.u;
        __syncthreads();
    }
}

// ---------------- bf16 MFMA GEMM 128x128 (TN), XCD-swizzled ----------------
// mode 0: f32 out (+add). mode 1: bf16 out. mode 4: w1w3-interleaved silu-mul.
__global__ __launch_bounds__(256) void gemm_bf16_k(const ushort_t* __restrict__ A,
                                                   const ushort_t* __restrict__ Bt,
                                                   const float* __restrict__ add,
                                                   void* __restrict__ Cout,
                                                   int M, int N, int K, int mode) {
    __shared__ ushort_t Al[128 * 32];
    __shared__ ushort_t Bl[128 * 32];
    int tid = threadIdx.x;
    int lane = tid & 63, wave = tid >> 6;
    int gx = gridDim.x, gy = gridDim.y;
    int nwg = gx * gy;
    int bx = blockIdx.x, by = blockIdx.y;
    if ((nwg & 7) == 0) {
        int flat = by * gx + bx;
        int cpx = nwg >> 3;
        int l = (flat & 7) * cpx + (flat >> 3);
        bx = l / gy;
        by = l % gy;
    }
    int brow = by * 128, bcol = bx * 128;
    int wr = (wave >> 1) * 64, wc = (wave & 1) * 64;
    f32x4 acc[4][4];
#pragma unroll
    for (int m = 0; m < 4; m++)
#pragma unroll
        for (int n = 0; n < 4; n++) acc[m][n] = (f32x4){0.f, 0.f, 0.f, 0.f};

    const ushort_t* Ag = A + (size_t)(brow + (tid >> 2)) * K + (tid & 3) * 8;
    const ushort_t* Bg = Bt + (size_t)(bcol + (tid >> 2)) * K + (tid & 3) * 8;
    ushort_t* Ald = &Al[wave * 512];
    ushort_t* Bld = &Bl[wave * 512];
    size_t rstep = (size_t)64 * K;

    for (int k0 = 0; k0 < K; k0 += 32) {
        gl_lds16(Ag + k0, Ald);
        gl_lds16(Ag + k0 + rstep, Ald + 2048);
        gl_lds16(Bg + k0, Bld);
        gl_lds16(Bg + k0 + rstep, Bld + 2048);
        __syncthreads();
        bf16x8 af[4], bfr[4];
        int arow = wr + (lane & 15);
        int brw = wc + (lane & 15);
        int kof = (lane >> 4) * 8;
#pragma unroll
        for (int m = 0; m < 4; m++) af[m] = *(const bf16x8*)&Al[(arow + m * 16) * 32 + kof];
#pragma unroll
        for (int n = 0; n < 4; n++) bfr[n] = *(const bf16x8*)&Bl[(brw + n * 16) * 32 + kof];
#pragma unroll
        for (int m = 0; m < 4; m++)
#pragma unroll
            for (int n = 0; n < 4; n++)
                acc[m][n] = __builtin_amdgcn_mfma_f32_16x16x32_bf16(af[m], bfr[n], acc[m][n], 0, 0, 0);
        __syncthreads();
    }
    int crow0 = brow + wr + (lane >> 4) * 4;
    int ccol = bcol + wc + (lane & 15);
#pragma unroll
    for (int m = 0; m < 4; m++)
#pragma unroll
        for (int j = 0; j < 4; j++) {
            int row = crow0 + m * 16 + j;
            if (mode == 4) {
#pragma unroll
                for (int n = 0; n < 4; n += 2) {
                    int c = ccol + n * 16;
                    int colOut = (c >> 5) * 16 + (c & 15);
                    float v1 = acc[m][n][j];
                    float v3 = acc[m][n + 1][j];
                    ((ushort_t*)Cout)[(size_t)row * (N / 2) + colOut] =
                        f2bf(v1 * sigm(v1) * v3);
                }
            } else {
#pragma unroll
                for (int n = 0; n < 4; n++) {
                    int col = ccol + n * 16;
                    float v = acc[m][n][j];
                    if (mode == 0) {
                        if (add) v += add[(size_t)row * N + col];
                        ((float*)Cout)[(size_t)row * N + col] = v;
                    } else {
                        ((ushort_t*)Cout)[(size_t)row * N + col] = f2bf(v);
                    }
                }
            }
        }
}

// ---------------- bf16 MFMA GEMM 64x64 (TN), XCD-swizzled ----------------
__global__ __launch_bounds__(256) void gemm64_k(const ushort_t* __restrict__ A,
                                                const ushort_t* __restrict__ Bt,
                                                const float* __restrict__ add,
                                                void* __restrict__ Cout,
                                                int M, int N, int K, int mode,
                                                ushort_t* __restrict__ p1,
                                                ushort_t* __restrict__ p2,
                                                ushort_t* __restrict__ p3) {
    __shared__ ushort_t Al[64 * 32];
    __shared__ ushort_t Bl[64 * 32];
    int tid = threadIdx.x;
    int lane = tid & 63, wave = tid >> 6;
    int gx = gridDim.x, gy = gridDim.y;
    int nwg = gx * gy;
    int bx = blockIdx.x, by = blockIdx.y;
    if ((nwg & 7) == 0) {
        int flat = by * gx + bx;
        int cpx = nwg >> 3;
        int l = (flat & 7) * cpx + (flat >> 3);
        bx = l / gy;
        by = l % gy;
    }
    int brow = by * 64, bcol = bx * 64;
    int wr = (wave >> 1) * 32, wc = (wave & 1) * 32;
    f32x4 acc[2][2];
#pragma unroll
    for (int m = 0; m < 2; m++)
#pragma unroll
        for (int n = 0; n < 2; n++) acc[m][n] = (f32x4){0.f, 0.f, 0.f, 0.f};

    const ushort_t* Ag = A + (size_t)(brow + (tid >> 2)) * K + (tid & 3) * 8;
    const ushort_t* Bg = Bt + (size_t)(bcol + (tid >> 2)) * K + (tid & 3) * 8;
    ushort_t* Ald = &Al[wave * 512];
    ushort_t* Bld = &Bl[wave * 512];

    for (int k0 = 0; k0 < K; k0 += 32) {
        gl_lds16(Ag + k0, Ald);
        gl_lds16(Bg + k0, Bld);
        __syncthreads();
        bf16x8 af[2], bfr[2];
        int kof = (lane >> 4) * 8;
#pragma unroll
        for (int m = 0; m < 2; m++)
            af[m] = *(const bf16x8*)&Al[(wr + m * 16 + (lane & 15)) * 32 + kof];
#pragma unroll
        for (int n = 0; n < 2; n++)
            bfr[n] = *(const bf16x8*)&Bl[(wc + n * 16 + (lane & 15)) * 32 + kof];
#pragma unroll
        for (int m = 0; m < 2; m++)
#pragma unroll
            for (int n = 0; n < 2; n++)
                acc[m][n] = __builtin_amdgcn_mfma_f32_16x16x32_bf16(af[m], bfr[n], acc[m][n], 0, 0, 0);
        __syncthreads();
    }
    int crow0 = brow + wr + (lane >> 4) * 4;
    int ccol = bcol + wc + (lane & 15);
#pragma unroll
    for (int m = 0; m < 2; m++)
#pragma unroll
        for (int j = 0; j < 2 * 2; j++) {
            int row = crow0 + m * 16 + j;
#pragma unroll
            for (int n = 0; n < 2; n++) {
                int col = ccol + n * 16;
                float v = acc[m][n][j];
                if (mode == 0) {
                    if (add) v += add[(size_t)row * N + col];
                    ((float*)Cout)[(size_t)row * N + col] = v;
                } else if (mode == 1) {
                    ((ushort_t*)Cout)[(size_t)row * N + col] = f2bf(v);
                } else {
                    size_t o = (size_t)row * DMODEL;
                    if (col < DMODEL) {
                        ushort_t hb = f2bf(v);
                        ((ushort_t*)Cout)[o + col] = hb;
                        p1[o + col] = f2bf(v - bf2f(hb));
                    } else if (col < 2 * DMODEL) {
                        p2[o + col - DMODEL] = f2bf(v);
                    } else {
                        p3[o + col - 2 * DMODEL] = f2bf(v);
                    }
                }
            }
        }
}

// ---------------- MFMA scores: sc[h][il][j] = (qh+ql)_i . kb_j / 8 ----------------
__global__ __launch_bounds__(256) void scoresm_k(const ushort_t* __restrict__ qh,
                                                 const ushort_t* __restrict__ ql,
                                                 const ushort_t* __restrict__ kb,
                                                 f16* __restrict__ sc, int cb) {
    int h = blockIdx.z;
    int il0 = blockIdx.y * 64;
    int j0 = blockIdx.x * 64;
    __shared__ ushort_t Qh[64][72];
    __shared__ ushort_t Ql[64][72];
    __shared__ ushort_t Kb[64][72];
    int tid = threadIdx.x;
    {
        int r = tid >> 2, c0 = (tid & 3) * 16;
        const ushort_t* p;
        p = qh + (size_t)(cb + il0 + r) * DMODEL + h * 64 + c0;
        *(uint4*)&Qh[r][c0] = *(const uint4*)p;
        *(uint4*)&Qh[r][c0 + 8] = *(const uint4*)(p + 8);
        p = ql + (size_t)(cb + il0 + r) * DMODEL + h * 64 + c0;
        *(uint4*)&Ql[r][c0] = *(const uint4*)p;
        *(uint4*)&Ql[r][c0 + 8] = *(const uint4*)(p + 8);
        p = kb + (size_t)(j0 + r) * DMODEL + h * 64 + c0;
        *(uint4*)&Kb[r][c0] = *(const uint4*)p;
        *(uint4*)&Kb[r][c0 + 8] = *(const uint4*)(p + 8);
    }
    __syncthreads();
    int lane = tid & 63, wave = tid >> 6;
    int wr = (wave >> 1) * 32, wc = (wave & 1) * 32;
    f32x4 acc[2][2];
#pragma unroll
    for (int m = 0; m < 2; m++)
#pragma unroll
        for (int n = 0; n < 2; n++) acc[m][n] = (f32x4){0.f, 0.f, 0.f, 0.f};
#pragma unroll
    for (int ks = 0; ks < 2; ks++) {
        int kof = ks * 32 + (lane >> 4) * 8;
        bf16x8 aH[2], aL[2], bK[2];
#pragma unroll
        for (int m = 0; m < 2; m++) {
            int ar = wr + m * 16 + (lane & 15);
            aH[m] = *(const bf16x8*)&Qh[ar][kof];
            aL[m] = *(const bf16x8*)&Ql[ar][kof];
        }
#pragma unroll
        for (int n = 0; n < 2; n++) bK[n] = *(const bf16x8*)&Kb[wc + n * 16 + (lane & 15)][kof];
#pragma unroll
        for (int m = 0; m < 2; m++)
#pragma unroll
            for (int n = 0; n < 2; n++) {
                acc[m][n] = __builtin_amdgcn_mfma_f32_16x16x32_bf16(aH[m], bK[n], acc[m][n], 0, 0, 0);
                acc[m][n] = __builtin_amdgcn_mfma_f32_16x16x32_bf16(aL[m], bK[n], acc[m][n], 0, 0, 0);
            }
    }
#pragma unroll
    for (int m = 0; m < 2; m++)
#pragma unroll
        for (int j = 0; j < 4; j++) {
            int il = il0 + wr + m * 16 + (lane >> 4) * 4 + j;
#pragma unroll
            for (int n = 0; n < 2; n++) {
                int jj = j0 + wc + n * 16 + (lane & 15);
                sc[((size_t)h * CHUNK + il) * SEQ + jj] = (f16)(acc[m][n][j] * 0.125f);
            }
        }
}

// ---------------- logits_int -> f16 (reads qh+ql) ----------------
__global__ __launch_bounds__(256) void copelogits_k(const ushort_t* __restrict__ qh,
                                                    const ushort_t* __restrict__ ql,
                                                    const float* __restrict__ pe,
                                                    f16* __restrict__ li) {
    int s1 = blockIdx.x;
    int tid = threadIdx.x;
    __shared__ float PE[DHEAD * NPOSE];
    __shared__ float QR[DMODEL];
    for (int i = tid; i < DHEAD * NPOSE; i += 256) PE[i] = pe[i];
    for (int i = tid; i < DMODEL; i += 256)
        QR[i] = bf2f(qh[(size_t)s1 * DMODEL + i]) + bf2f(ql[(size_t)s1 * DMODEL + i]);
    __syncthreads();
#pragma unroll
    for (int j = 0; j < 8; j++) {
        int o = j * 256 + tid;
        int h = o >> 7, n = o & 127;
        const float* qhp = &QR[h * DHEAD];
        float acc = 0.0f;
#pragma unroll 8
        for (int d = 0; d < DHEAD; d++) acc += qhp[d] * PE[d * NPOSE + n];
        li[(size_t)s1 * (NH * NPOSE) + o] = (f16)acc;
    }
}

// ---------------- fused CoPE: scan + bias + MFMA MLP + rowstat (1024 thr, 16 waves) ----------------
#define CSTR 2050
__global__ __launch_bounds__(1024, 1) void cope_k(f16* __restrict__ sc,
                                                  const f16* __restrict__ li,
                                                  const float* __restrict__ w1,
                                                  const float* __restrict__ b1,
                                                  const float* __restrict__ w2,
                                                  const float* __restrict__ b2,
                                                  float* __restrict__ rowmax,
                                                  float* __restrict__ rowsum,
                                                  int cb) {
    __shared__ f16 C[32 * CSTR];            // 131200 B
    __shared__ f16 Lif[NH * 130];           // 4160 B
    __shared__ ushort_t HMB[16][16 * 36];   // 18432 B (hi only) -> 153792 total
    int r = blockIdx.x;
    int tid = threadIdx.x;
    int lane = tid & 63, wv = tid >> 6;     // wv in 0..15

    // stage scores: 16 rows x 1024 dwords, one dword per thread per row
    for (int h = 0; h < NH; h++) {
        const uint_t* s32 = (const uint_t*)(sc + ((size_t)h * CHUNK + r) * SEQ);
        uint_t* d32 = (uint_t*)&C[h * CSTR];
        d32[tid] = s32[tid];
    }
    {
        const f16* lsrc = li + (size_t)(cb + r) * (NH * NPOSE);
        for (int i = tid; i < NH * NPOSE; i += 1024)
            Lif[(i >> 7) * 130 + (i & 127)] = lsrc[i];
    }
    __syncthreads();

    // suffix scan + bias interp: wave wv handles head wv
    {
        f16* crow = &C[wv * CSTR];
        f16* brow = &C[(16 + wv) * CSTR];
        const f16* lrow = &Lif[wv * 130];
        float carry = 0.0f;
        for (int c = SEQ / 64 - 1; c >= 0; c--) {
            int t = c * 64 + lane;
            float g = sigm((float)crow[t]);
#pragma unroll
            for (int dd = 1; dd < 64; dd <<= 1) {
                float o = __shfl_down(g, dd, 64);
                g = (lane + dd < 64) ? g + o : g;
            }
            float total = __shfl(g, 0, 64);
            float pos = fminf(g + carry, 127.0f);
            carry += total;
            int fl = (int)pos;
            float fr = pos - (float)fl;
            float lf = (float)lrow[fl];
            float lc = (float)lrow[(fl < 127) ? fl + 1 : 127];
            brow[t] = (f16)(lc * fr + lf * (1.0f - fr));
        }
    }
    __syncthreads();

    // MLP weight fragments, hi/lo split (per wave)
    int fkg = lane >> 4;
    int fc = lane & 15;
    BF8 w1fH[2], w1fL[2], w2fH, w2fL;
    float b1v[2], b2v;
#pragma unroll
    for (int half = 0; half < 2; half++) {
#pragma unroll
        for (int j = 0; j < 8; j++) {
            float wval = w1[(fkg * 8 + j) * MLPWID + half * 16 + fc];
            ushort_t hb = f2bf(wval);
            w1fH[half].s[j] = hb;
            w1fL[half].s[j] = f2bf(wval - bf2f(hb));
        }
        b1v[half] = b1[half * 16 + fc];
    }
#pragma unroll
    for (int j = 0; j < 8; j++) {
        float wval = w2[(fkg * 8 + j) * NH + fc];
        ushort_t hb = f2bf(wval);
        w2fH.s[j] = hb;
        w2fL.s[j] = f2bf(wval - bf2f(hb));
    }
    b2v = b2[fc];

    // MFMA MLP over t-tiles of 16; wave wv does tiles wv, wv+16, ... (8 tiles)
    ushort_t* hmb = HMB[wv];
    for (int tt = wv; tt < SEQ / 16; tt += 16) {
        int t0 = tt * 16;
        BF8 afH, afL;
#pragma unroll
        for (int j = 0; j < 8; j++) {
            int f = fkg * 8 + j;
            float val = (float)C[f * CSTR + t0 + fc];
            ushort_t hb = f2bf(val);
            afH.s[j] = hb;
            afL.s[j] = f2bf(val - bf2f(hb));
        }
        f32x4 acc0 = (f32x4){b1v[0], b1v[0], b1v[0], b1v[0]};
        f32x4 acc1 = (f32x4){b1v[1], b1v[1], b1v[1], b1v[1]};
        acc0 = __builtin_amdgcn_mfma_f32_16x16x32_bf16(afH.v, w1fH[0].v, acc0, 0, 0, 0);
        acc0 = __builtin_amdgcn_mfma_f32_16x16x32_bf16(afH.v, w1fL[0].v, acc0, 0, 0, 0);
        acc0 = __builtin_amdgcn_mfma_f32_16x16x32_bf16(afL.v, w1fH[0].v, acc0, 0, 0, 0);
        acc1 = __builtin_amdgcn_mfma_f32_16x16x32_bf16(afH.v, w1fH[1].v, acc1, 0, 0, 0);
        acc1 = __builtin_amdgcn_mfma_f32_16x16x32_bf16(afH.v, w1fL[1].v, acc1, 0, 0, 0);
        acc1 = __builtin_amdgcn_mfma_f32_16x16x32_bf16(afL.v, w1fH[1].v, acc1, 0, 0, 0);
        // silu -> hm (hi only) into per-wave LDS bounce
#pragma unroll
        for (int j2 = 0; j2 < 4; j2++) {
            int p = fkg * 4 + j2;
            float h0 = acc0[j2]; h0 = h0 * sigm(h0);
            float h1 = acc1[j2]; h1 = h1 * sigm(h1);
            hmb[p * 36 + fc] = f2bf(h0);
            hmb[p * 36 + 16 + fc] = f2bf(h1);
        }
        BF8 hfH;
        hfH.u2[0] = *(const uint2*)&hmb[fc * 36 + fkg * 8];
        hfH.u2[1] = *(const uint2*)&hmb[fc * 36 + fkg * 8 + 4];
        f32x4 acc2 = (f32x4){b2v, b2v, b2v, b2v};
        acc2 = __builtin_amdgcn_mfma_f32_16x16x32_bf16(hfH.v, w2fH.v, acc2, 0, 0, 0);
        acc2 = __builtin_amdgcn_mfma_f32_16x16x32_bf16(hfH.v, w2fL.v, acc2, 0, 0, 0);
#pragma unroll
        for (int j2 = 0; j2 < 4; j2 += 2) {
            uint_t* pp = (uint_t*)&C[fc * CSTR + t0 + fkg * 4 + j2];
            U1H2 old, neu;
            old.u = *pp;
            neu.h[0] = (f16)((float)old.h[0] + acc2[j2]);
            neu.h[1] = (f16)((float)old.h[1] + acc2[j2 + 1]);
            *pp = neu.u;
        }
    }
    __syncthreads();

    // fused rowstat: wave wv -> head wv
    {
        const f16* row = &C[wv * CSTR];
        float m = -1e30f;
        for (int c = 0; c < SEQ / 64; c++) m = fmaxf(m, (float)row[c * 64 + lane]);
#pragma unroll
        for (int d = 1; d < 64; d <<= 1) m = fmaxf(m, __shfl_xor(m, d, 64));
        float s = 0.0f;
        for (int c = 0; c < SEQ / 64; c++) s += __expf((float)row[c * 64 + lane] - m);
#pragma unroll
        for (int d = 1; d < 64; d <<= 1) s += __shfl_xor(s, d, 64);
        if (lane == 0) {
            rowmax[(size_t)wv * SEQ + cb + r] = m;
            rowsum[(size_t)wv * SEQ + cb + r] = s;
        }
    }

    // write back logits
    for (int h = 0; h < NH; h++) {
        const uint_t* s32 = (const uint_t*)&C[h * CSTR];
        uint_t* d32 = (uint_t*)(sc + ((size_t)h * CHUNK + r) * SEQ);
        d32[tid] = s32[tid];
    }
}

// ---------------- MFMA softmax+PV -> aob bf16 ----------------
__global__ __launch_bounds__(256) void pvm_k(const f16* __restrict__ sc,
                                             const ushort_t* __restrict__ vt,
                                             const float* __restrict__ rowmax,
                                             const float* __restrict__ rowsum,
                                             ushort_t* __restrict__ aob, int cb) {
    int h = blockIdx.y;
    int s0 = blockIdx.x * 32;
    __shared__ ushort_t P[32][72];
    __shared__ ushort_t Vt[64][72];
    __shared__ float rm[32];
    __shared__ float ri[32];
    int tid = threadIdx.x;
    int lane = tid & 63, wave = tid >> 6;
    if (tid < 32) {
        rm[tid] = rowmax[(size_t)h * SEQ + cb + s0 + tid];
        ri[tid] = 1.0f / rowsum[(size_t)h * SEQ + cb + s0 + tid];
    }
    __syncthreads();
    int wr = (wave >> 1) * 16, wc = (wave & 1) * 32;
    f32x4 acc[2];
    acc[0] = (f32x4){0.f, 0.f, 0.f, 0.f};
    acc[1] = (f32x4){0.f, 0.f, 0.f, 0.f};
    int pr = tid >> 3, pc = (tid & 7) * 8;
    int vr = tid >> 2, vc = (tid & 3) * 16;
    for (int t0 = 0; t0 < SEQ; t0 += 64) {
        {
            U4H8 lg;
            lg.u = *(const uint4*)(sc + ((size_t)h * CHUNK + s0 + pr) * SEQ + t0 + pc);
            float rmv = rm[pr], riv = ri[pr];
            U4S8 o;
#pragma unroll
            for (int j = 0; j < 8; j++) o.s[j] = f2bf(__expf((float)lg.h[j] - rmv) * riv);
            *(uint4*)&P[pr][pc] = o.u;
            const ushort_t* vp = vt + ((size_t)h * 64 + vr) * SEQ + t0 + vc;
            *(uint4*)&Vt[vr][vc] = *(const uint4*)vp;
            *(uint4*)&Vt[vr][vc + 8] = *(const uint4*)(vp + 8);
        }
        __syncthreads();
#pragma unroll
        for (int ks = 0; ks < 2; ks++) {
            int kof = ks * 32 + (lane >> 4) * 8;
            bf16x8 pa = *(const bf16x8*)&P[wr + (lane & 15)][kof];
#pragma unroll
            for (int n = 0; n < 2; n++) {
                bf16x8 vb = *(const bf16x8*)&Vt[wc + n * 16 + (lane & 15)][kof];
                acc[n] = __builtin_amdgcn_mfma_f32_16x16x32_bf16(pa, vb, acc[n], 0, 0, 0);
            }
        }
        __syncthreads();
    }
#pragma unroll
    for (int j = 0; j < 4; j++) {
        int s = cb + s0 + wr + (lane >> 4) * 4 + j;
#pragma unroll
        for (int n = 0; n < 2; n++) {
            int d = h * 64 + wc + n * 16 + (lane & 15);
            aob[(size_t)s * DMODEL + d] = f2bf(acc[n][j]);
        }
    }
}

extern "C" void kernel_launch(void* const* d_in, const int* in_sizes, int n_in,
                              void* d_out, int out_size, void* d_ws, size_t ws_size,
                              hipStream_t stream) {
    const float* x = (const float*)d_in[0];
    const float* wq = (const float*)d_in[1];
    const float* wk = (const float*)d_in[2];
    const float* wv = (const float*)d_in[3];
    const float* wo = (const float*)d_in[4];
    const float* pos_emb = (const float*)d_in[5];
    const float* mlp_w1 = (const float*)d_in[6];
    const float* mlp_b1 = (const float*)d_in[7];
    const float* mlp_w2 = (const float*)d_in[8];
    const float* mlp_b2 = (const float*)d_in[9];
    const float* ffn_w1 = (const float*)d_in[10];
    const float* ffn_w2 = (const float*)d_in[11];
    const float* ffn_w3 = (const float*)d_in[12];
    const float* attn_norm_w = (const float*)d_in[13];
    const float* ffn_norm_w = (const float*)d_in[14];
    float* out = (float*)d_out;

    char* ws = (char*)d_ws;
    const size_t MB = 1024 * 1024;
    ushort_t* nxb = (ushort_t*)(ws + 0);             // 0-4
    ushort_t* qh = (ushort_t*)(ws + 4 * MB);         // 4-8   (phase C: nxb2)
    ushort_t* ql = (ushort_t*)(ws + 8 * MB);         // 8-12  (phase C: g1b 8-24)
    ushort_t* kb = (ushort_t*)(ws + 12 * MB);        // 12-16
    ushort_t* vb = (ushort_t*)(ws + 16 * MB);        // 16-20
    ushort_t* vt = (ushort_t*)(ws + 20 * MB);        // 20-24
    f16* li = (f16*)(ws + 24 * MB);                  // 24-32
    float* rowmax = (float*)(ws + 32 * MB);          // 128KB
    float* rowsum = (float*)(ws + 32 * MB + 512 * 1024);
    ushort_t* aob = (ushort_t*)(ws + 33 * MB);       // 33-37
    float* x1 = (float*)(ws + 37 * MB);              // 37-45
    ushort_t* wqkvt = (ushort_t*)(ws + 45 * MB);     // 45-51 (phase 1)
    f16* sc = (f16*)(ws + 45 * MB);                  // 45-77 (phase 2)
    ushort_t* wot = (ushort_t*)(ws + 45 * MB);       // 45-47 (phase B)
    ushort_t* w13t = (ushort_t*)(ws + 47 * MB);      // 47-63 (interleaved, 16MB)
    ushort_t* w2t = (ushort_t*)(ws + 63 * MB);       // 63-71 -> peak 77MB
    ushort_t* nxb2 = (ushort_t*)(ws + 4 * MB);
    ushort_t* g1b = (ushort_t*)(ws + 8 * MB);        // 8-24

    // ---- phase 1: norm + fused QKV (64-tile, 1536 blocks) ----
    transconv_k<<<dim3(DMODEL / 64, DMODEL / 64), 256, 0, stream>>>(wq, wqkvt, DMODEL, DMODEL);
    transconv_k<<<dim3(DMODEL / 64, DMODEL / 64), 256, 0, stream>>>(wk, wqkvt + 1024 * 1024, DMODEL, DMODEL);
    transconv_k<<<dim3(DMODEL / 64, DMODEL / 64), 256, 0, stream>>>(wv, wqkvt + 2 * 1024 * 1024, DMODEL, DMODEL);
    rmsnormbf_k<<<SEQ, 256, 0, stream>>>(x, attn_norm_w, nxb);
    gemm64_k<<<dim3(3 * DMODEL / 64, SEQ / 64), 256, 0, stream>>>(
        nxb, wqkvt, nullptr, qh, SEQ, 3 * DMODEL, DMODEL, 2, ql, kb, vb);
    copelogits_k<<<SEQ, 256, 0, stream>>>(qh, ql, pos_emb, li);
    tv_k<<<dim3(SEQ / 64, NH), 256, 0, stream>>>(vb, vt);

    // ---- phase 2: attention chunks ----
    for (int ch = 0; ch < NCH; ch++) {
        int cb = ch * CHUNK;
        scoresm_k<<<dim3(SEQ / 64, CHUNK / 64, NH), 256, 0, stream>>>(qh, ql, kb, sc, cb);
        cope_k<<<CHUNK, 1024, 0, stream>>>(sc, li, mlp_w1, mlp_b1, mlp_w2, mlp_b2,
                                           rowmax, rowsum, cb);
        pvm_k<<<dim3(CHUNK / 32, NH), 256, 0, stream>>>(sc, vt, rowmax, rowsum, aob, cb);
    }

    // ---- phase B: out @ wo + x (64-tile, 512 blocks) ----
    transconv_k<<<dim3(DMODEL / 64, DMODEL / 64), 256, 0, stream>>>(wo, wot, DMODEL, DMODEL);
    gemm64_k<<<dim3(DMODEL / 64, SEQ / 64), 256, 0, stream>>>(
        aob, wot, x, x1, SEQ, DMODEL, DMODEL, 0, nullptr, nullptr, nullptr);

    // ---- phase C: FFN ----
    rmsnormbf_k<<<SEQ, 256, 0, stream>>>(x1, ffn_norm_w, nxb2);
    transconv2_k<<<dim3(FFDIM / 64, DMODEL / 64), 256, 0, stream>>>(ffn_w1, ffn_w3, w13t, DMODEL, FFDIM);
    transconv_k<<<dim3(DMODEL / 64, FFDIM / 64), 256, 0, stream>>>(ffn_w2, w2t, FFDIM, DMODEL);
    gemm_bf16_k<<<dim3(2 * FFDIM / 128, SEQ / 128), 256, 0, stream>>>(
        nxb2, w13t, nullptr, g1b, SEQ, 2 * FFDIM, DMODEL, 4);
    gemm64_k<<<dim3(DMODEL / 64, SEQ / 64), 256, 0, stream>>>(
        g1b, w2t, x1, out, SEQ, DMODEL, FFDIM, 0, nullptr, nullptr, nullptr);
}

// Round 11
// 602.835 us; speedup vs baseline: 6.5674x; 1.1001x over previous
//
#include <hip/hip_runtime.h>
#include <hip/hip_bf16.h>
#include <hip/hip_fp16.h>
#include <math.h>

#define SEQ 2048
#define DMODEL 1024
#define NH 16
#define DHEAD 64
#define FFDIM 4096
#define NPOSE 128
#define MLPWID 32
#define EPSV 1e-5f
#define CHUNK 1024
#define NCH (SEQ / CHUNK)

typedef unsigned short ushort_t;
typedef unsigned int uint_t;
typedef _Float16 f16;
typedef __attribute__((ext_vector_type(8))) short bf16x8;
typedef __attribute__((ext_vector_type(4))) float f32x4;

union U2H4 { uint2 u; f16 h[4]; };
union U4S8 { uint4 u; ushort_t s[8]; };
union U4H8 { uint4 u; f16 h[8]; };
union U2S4 { uint2 u; ushort_t s[4]; };
union BF8 { bf16x8 v; ushort_t s[8]; uint2 u2[2]; };
union U1H2 { uint_t u; f16 h[2]; };

__device__ __forceinline__ float sigm(float x) {
    return 1.0f / (1.0f + __expf(-x));
}
__device__ __forceinline__ ushort_t f2bf(float f) {
    uint_t u = __float_as_uint(f);
    u += 0x7fffu + ((u >> 16) & 1u);
    return (ushort_t)(u >> 16);
}
__device__ __forceinline__ float bf2f(ushort_t u) {
    return __uint_as_float(((uint_t)u) << 16);
}
__device__ __forceinline__ void gl_lds16(const void* g, void* l) {
    __builtin_amdgcn_global_load_lds((const __attribute__((address_space(1))) uint_t*)g,
                                     (__attribute__((address_space(3))) uint_t*)l, 16, 0, 0);
}

// ---------------- RMSNorm, bf16 out ----------------
__global__ __launch_bounds__(256) void rmsnormbf_k(const float* __restrict__ x,
                                                   const float* __restrict__ w,
                                                   ushort_t* __restrict__ o) {
    int row = blockIdx.x;
    int tid = threadIdx.x;
    const float4* xr = (const float4*)(x + (size_t)row * DMODEL);
    float4 v = xr[tid];
    float ss = v.x * v.x + v.y * v.y + v.z * v.z + v.w * v.w;
#pragma unroll
    for (int d = 1; d < 64; d <<= 1) ss += __shfl_xor(ss, d, 64);
    __shared__ float red[4];
    int lane = tid & 63, wv = tid >> 6;
    if (lane == 0) red[wv] = ss;
    __syncthreads();
    float tot = red[0] + red[1] + red[2] + red[3];
    float r = rsqrtf(tot / (float)DMODEL + EPSV);
    const float4* wr = (const float4*)w;
    float4 wv4 = wr[tid];
    U2S4 ob;
    ob.s[0] = f2bf(v.x * r * wv4.x);
    ob.s[1] = f2bf(v.y * r * wv4.y);
    ob.s[2] = f2bf(v.z * r * wv4.z);
    ob.s[3] = f2bf(v.w * r * wv4.w);
    ((uint2*)(o + (size_t)row * DMODEL))[tid] = ob.u;
}

// ---------------- V transpose: vb[SEQ][DMODEL] bf16 -> vt[NH][DHEAD][SEQ] ----------------
__global__ __launch_bounds__(256) void tv_k(const ushort_t* __restrict__ vb,
                                            ushort_t* __restrict__ vt) {
    int h = blockIdx.y, t0 = blockIdx.x * 64;
    __shared__ ushort_t T[64][76];
    int tid = threadIdx.x;
#pragma unroll
    for (int it = 0; it < 2; it++) {
        int a = tid + it * 256;
        int t = a >> 3, c8 = (a & 7) * 8;
        U4S8 v;
        v.u = *(const uint4*)(vb + (size_t)(t0 + t) * DMODEL + h * 64 + c8);
#pragma unroll
        for (int j = 0; j < 8; j++) T[c8 + j][t] = v.s[j];
    }
    __syncthreads();
#pragma unroll
    for (int it = 0; it < 2; it++) {
        int a = tid + it * 256;
        int d = a >> 3, c8 = (a & 7) * 8;
        U4S8 o;
#pragma unroll
        for (int j = 0; j < 8; j++) o.s[j] = T[d][c8 + j];
        *(uint4*)(vt + ((size_t)h * 64 + d) * SEQ + t0 + c8) = o.u;
    }
}

// ---------------- weight transpose+convert: f32[K][N] -> bf16[N][K] ----------------
__global__ __launch_bounds__(256) void transconv_k(const float* __restrict__ in,
                                                   ushort_t* __restrict__ out,
                                                   int K, int N) {
    __shared__ ushort_t T[64][72];
    int k0 = blockIdx.y * 64, n0 = blockIdx.x * 64;
    int tid = threadIdx.x;
    int r = tid >> 4, c4 = (tid & 15) * 4;
#pragma unroll
    for (int i = 0; i < 4; i++) {
        float4 v = *(const float4*)(in + (size_t)(k0 + r + i * 16) * N + n0 + c4);
        T[c4 + 0][r + i * 16] = f2bf(v.x);
        T[c4 + 1][r + i * 16] = f2bf(v.y);
        T[c4 + 2][r + i * 16] = f2bf(v.z);
        T[c4 + 3][r + i * 16] = f2bf(v.w);
    }
    __syncthreads();
    int n = tid >> 2, kk = (tid & 3) * 16;
    U4S8 o0, o1;
#pragma unroll
    for (int i = 0; i < 8; i++) { o0.s[i] = T[n][kk + i]; o1.s[i] = T[n][kk + 8 + i]; }
    uint4* dst = (uint4*)(out + (size_t)(n0 + n) * K + k0 + kk);
    dst[0] = o0.u;
    dst[1] = o1.u;
}

// ---------------- w1/w3 transpose+convert, row-interleaved (16-col groups) ----------------
__global__ __launch_bounds__(256) void transconv2_k(const float* __restrict__ w1,
                                                    const float* __restrict__ w3,
                                                    ushort_t* __restrict__ out,
                                                    int K, int N) {
    __shared__ ushort_t T[64][72];
    int k0 = blockIdx.y * 64, n0 = blockIdx.x * 64;
    int tid = threadIdx.x;
    int r = tid >> 4, c4 = (tid & 15) * 4;
    int n = tid >> 2, kk = (tid & 3) * 16;
#pragma unroll
    for (int half = 0; half < 2; half++) {
        const float* in = half ? w3 : w1;
#pragma unroll
        for (int i = 0; i < 4; i++) {
            float4 v = *(const float4*)(in + (size_t)(k0 + r + i * 16) * N + n0 + c4);
            T[c4 + 0][r + i * 16] = f2bf(v.x);
            T[c4 + 1][r + i * 16] = f2bf(v.y);
            T[c4 + 2][r + i * 16] = f2bf(v.z);
            T[c4 + 3][r + i * 16] = f2bf(v.w);
        }
        __syncthreads();
        int gc = n0 + n;
        int rp = (gc >> 4) * 32 + (gc & 15) + half * 16;
        U4S8 o0, o1;
#pragma unroll
        for (int i = 0; i < 8; i++) { o0.s[i] = T[n][kk + i]; o1.s[i] = T[n][kk + 8 + i]; }
        uint4* dst = (uint4*)(out + (size_t)rp * K + k0 + kk);
        dst[0] = o0.u;
        dst[1] = o1.u;
        __syncthreads();
    }
}

// ---------------- bf16 MFMA GEMM 128x128 (TN), XCD-swizzled ----------------
// mode 0: f32 out (+add). mode 1: bf16 out. mode 4: w1w3-interleaved silu-mul.
__global__ __launch_bounds__(256) void gemm_bf16_k(const ushort_t* __restrict__ A,
                                                   const ushort_t* __restrict__ Bt,
                                                   const float* __restrict__ add,
                                                   void* __restrict__ Cout,
                                                   int M, int N, int K, int mode) {
    __shared__ ushort_t Al[128 * 32];
    __shared__ ushort_t Bl[128 * 32];
    int tid = threadIdx.x;
    int lane = tid & 63, wave = tid >> 6;
    int gx = gridDim.x, gy = gridDim.y;
    int nwg = gx * gy;
    int bx = blockIdx.x, by = blockIdx.y;
    if ((nwg & 7) == 0) {
        int flat = by * gx + bx;
        int cpx = nwg >> 3;
        int l = (flat & 7) * cpx + (flat >> 3);
        bx = l / gy;
        by = l % gy;
    }
    int brow = by * 128, bcol = bx * 128;
    int wr = (wave >> 1) * 64, wc = (wave & 1) * 64;
    f32x4 acc[4][4];
#pragma unroll
    for (int m = 0; m < 4; m++)
#pragma unroll
        for (int n = 0; n < 4; n++) acc[m][n] = (f32x4){0.f, 0.f, 0.f, 0.f};

    const ushort_t* Ag = A + (size_t)(brow + (tid >> 2)) * K + (tid & 3) * 8;
    const ushort_t* Bg = Bt + (size_t)(bcol + (tid >> 2)) * K + (tid & 3) * 8;
    ushort_t* Ald = &Al[wave * 512];
    ushort_t* Bld = &Bl[wave * 512];
    size_t rstep = (size_t)64 * K;

    for (int k0 = 0; k0 < K; k0 += 32) {
        gl_lds16(Ag + k0, Ald);
        gl_lds16(Ag + k0 + rstep, Ald + 2048);
        gl_lds16(Bg + k0, Bld);
        gl_lds16(Bg + k0 + rstep, Bld + 2048);
        __syncthreads();
        bf16x8 af[4], bfr[4];
        int arow = wr + (lane & 15);
        int brw = wc + (lane & 15);
        int kof = (lane >> 4) * 8;
#pragma unroll
        for (int m = 0; m < 4; m++) af[m] = *(const bf16x8*)&Al[(arow + m * 16) * 32 + kof];
#pragma unroll
        for (int n = 0; n < 4; n++) bfr[n] = *(const bf16x8*)&Bl[(brw + n * 16) * 32 + kof];
#pragma unroll
        for (int m = 0; m < 4; m++)
#pragma unroll
            for (int n = 0; n < 4; n++)
                acc[m][n] = __builtin_amdgcn_mfma_f32_16x16x32_bf16(af[m], bfr[n], acc[m][n], 0, 0, 0);
        __syncthreads();
    }
    int crow0 = brow + wr + (lane >> 4) * 4;
    int ccol = bcol + wc + (lane & 15);
#pragma unroll
    for (int m = 0; m < 4; m++)
#pragma unroll
        for (int j = 0; j < 4; j++) {
            int row = crow0 + m * 16 + j;
            if (mode == 4) {
#pragma unroll
                for (int n = 0; n < 4; n += 2) {
                    int c = ccol + n * 16;
                    int colOut = (c >> 5) * 16 + (c & 15);
                    float v1 = acc[m][n][j];
                    float v3 = acc[m][n + 1][j];
                    ((ushort_t*)Cout)[(size_t)row * (N / 2) + colOut] =
                        f2bf(v1 * sigm(v1) * v3);
                }
            } else {
#pragma unroll
                for (int n = 0; n < 4; n++) {
                    int col = ccol + n * 16;
                    float v = acc[m][n][j];
                    if (mode == 0) {
                        if (add) v += add[(size_t)row * N + col];
                        ((float*)Cout)[(size_t)row * N + col] = v;
                    } else {
                        ((ushort_t*)Cout)[(size_t)row * N + col] = f2bf(v);
                    }
                }
            }
        }
}

// ---------------- bf16 MFMA GEMM 64x64 (TN), XCD-swizzled ----------------
__global__ __launch_bounds__(256) void gemm64_k(const ushort_t* __restrict__ A,
                                                const ushort_t* __restrict__ Bt,
                                                const float* __restrict__ add,
                                                void* __restrict__ Cout,
                                                int M, int N, int K, int mode,
                                                ushort_t* __restrict__ p1,
                                                ushort_t* __restrict__ p2,
                                                ushort_t* __restrict__ p3) {
    __shared__ ushort_t Al[64 * 32];
    __shared__ ushort_t Bl[64 * 32];
    int tid = threadIdx.x;
    int lane = tid & 63, wave = tid >> 6;
    int gx = gridDim.x, gy = gridDim.y;
    int nwg = gx * gy;
    int bx = blockIdx.x, by = blockIdx.y;
    if ((nwg & 7) == 0) {
        int flat = by * gx + bx;
        int cpx = nwg >> 3;
        int l = (flat & 7) * cpx + (flat >> 3);
        bx = l / gy;
        by = l % gy;
    }
    int brow = by * 64, bcol = bx * 64;
    int wr = (wave >> 1) * 32, wc = (wave & 1) * 32;
    f32x4 acc[2][2];
#pragma unroll
    for (int m = 0; m < 2; m++)
#pragma unroll
        for (int n = 0; n < 2; n++) acc[m][n] = (f32x4){0.f, 0.f, 0.f, 0.f};

    const ushort_t* Ag = A + (size_t)(brow + (tid >> 2)) * K + (tid & 3) * 8;
    const ushort_t* Bg = Bt + (size_t)(bcol + (tid >> 2)) * K + (tid & 3) * 8;
    ushort_t* Ald = &Al[wave * 512];
    ushort_t* Bld = &Bl[wave * 512];

    for (int k0 = 0; k0 < K; k0 += 32) {
        gl_lds16(Ag + k0, Ald);
        gl_lds16(Bg + k0, Bld);
        __syncthreads();
        bf16x8 af[2], bfr[2];
        int kof = (lane >> 4) * 8;
#pragma unroll
        for (int m = 0; m < 2; m++)
            af[m] = *(const bf16x8*)&Al[(wr + m * 16 + (lane & 15)) * 32 + kof];
#pragma unroll
        for (int n = 0; n < 2; n++)
            bfr[n] = *(const bf16x8*)&Bl[(wc + n * 16 + (lane & 15)) * 32 + kof];
#pragma unroll
        for (int m = 0; m < 2; m++)
#pragma unroll
            for (int n = 0; n < 2; n++)
                acc[m][n] = __builtin_amdgcn_mfma_f32_16x16x32_bf16(af[m], bfr[n], acc[m][n], 0, 0, 0);
        __syncthreads();
    }
    int crow0 = brow + wr + (lane >> 4) * 4;
    int ccol = bcol + wc + (lane & 15);
#pragma unroll
    for (int m = 0; m < 2; m++)
#pragma unroll
        for (int j = 0; j < 2 * 2; j++) {
            int row = crow0 + m * 16 + j;
#pragma unroll
            for (int n = 0; n < 2; n++) {
                int col = ccol + n * 16;
                float v = acc[m][n][j];
                if (mode == 0) {
                    if (add) v += add[(size_t)row * N + col];
                    ((float*)Cout)[(size_t)row * N + col] = v;
                } else if (mode == 1) {
                    ((ushort_t*)Cout)[(size_t)row * N + col] = f2bf(v);
                } else {
                    size_t o = (size_t)row * DMODEL;
                    if (col < DMODEL) {
                        ushort_t hb = f2bf(v);
                        ((ushort_t*)Cout)[o + col] = hb;
                        p1[o + col] = f2bf(v - bf2f(hb));
                    } else if (col < 2 * DMODEL) {
                        p2[o + col - DMODEL] = f2bf(v);
                    } else {
                        p3[o + col - 2 * DMODEL] = f2bf(v);
                    }
                }
            }
        }
}

// ---------------- MFMA scores: sc[h][il][j] = (qh+ql)_i . kb_j / 8 ----------------
__global__ __launch_bounds__(256) void scoresm_k(const ushort_t* __restrict__ qh,
                                                 const ushort_t* __restrict__ ql,
                                                 const ushort_t* __restrict__ kb,
                                                 f16* __restrict__ sc, int cb) {
    int h = blockIdx.z;
    int il0 = blockIdx.y * 64;
    int j0 = blockIdx.x * 64;
    __shared__ ushort_t Qh[64][72];
    __shared__ ushort_t Ql[64][72];
    __shared__ ushort_t Kb[64][72];
    int tid = threadIdx.x;
    {
        int r = tid >> 2, c0 = (tid & 3) * 16;
        const ushort_t* p;
        p = qh + (size_t)(cb + il0 + r) * DMODEL + h * 64 + c0;
        *(uint4*)&Qh[r][c0] = *(const uint4*)p;
        *(uint4*)&Qh[r][c0 + 8] = *(const uint4*)(p + 8);
        p = ql + (size_t)(cb + il0 + r) * DMODEL + h * 64 + c0;
        *(uint4*)&Ql[r][c0] = *(const uint4*)p;
        *(uint4*)&Ql[r][c0 + 8] = *(const uint4*)(p + 8);
        p = kb + (size_t)(j0 + r) * DMODEL + h * 64 + c0;
        *(uint4*)&Kb[r][c0] = *(const uint4*)p;
        *(uint4*)&Kb[r][c0 + 8] = *(const uint4*)(p + 8);
    }
    __syncthreads();
    int lane = tid & 63, wave = tid >> 6;
    int wr = (wave >> 1) * 32, wc = (wave & 1) * 32;
    f32x4 acc[2][2];
#pragma unroll
    for (int m = 0; m < 2; m++)
#pragma unroll
        for (int n = 0; n < 2; n++) acc[m][n] = (f32x4){0.f, 0.f, 0.f, 0.f};
#pragma unroll
    for (int ks = 0; ks < 2; ks++) {
        int kof = ks * 32 + (lane >> 4) * 8;
        bf16x8 aH[2], aL[2], bK[2];
#pragma unroll
        for (int m = 0; m < 2; m++) {
            int ar = wr + m * 16 + (lane & 15);
            aH[m] = *(const bf16x8*)&Qh[ar][kof];
            aL[m] = *(const bf16x8*)&Ql[ar][kof];
        }
#pragma unroll
        for (int n = 0; n < 2; n++) bK[n] = *(const bf16x8*)&Kb[wc + n * 16 + (lane & 15)][kof];
#pragma unroll
        for (int m = 0; m < 2; m++)
#pragma unroll
            for (int n = 0; n < 2; n++) {
                acc[m][n] = __builtin_amdgcn_mfma_f32_16x16x32_bf16(aH[m], bK[n], acc[m][n], 0, 0, 0);
                acc[m][n] = __builtin_amdgcn_mfma_f32_16x16x32_bf16(aL[m], bK[n], acc[m][n], 0, 0, 0);
            }
    }
#pragma unroll
    for (int m = 0; m < 2; m++)
#pragma unroll
        for (int j = 0; j < 4; j++) {
            int il = il0 + wr + m * 16 + (lane >> 4) * 4 + j;
#pragma unroll
            for (int n = 0; n < 2; n++) {
                int jj = j0 + wc + n * 16 + (lane & 15);
                sc[((size_t)h * CHUNK + il) * SEQ + jj] = (f16)(acc[m][n][j] * 0.125f);
            }
        }
}

// ---------------- logits_int -> f16 (reads qh+ql) ----------------
__global__ __launch_bounds__(256) void copelogits_k(const ushort_t* __restrict__ qh,
                                                    const ushort_t* __restrict__ ql,
                                                    const float* __restrict__ pe,
                                                    f16* __restrict__ li) {
    int s1 = blockIdx.x;
    int tid = threadIdx.x;
    __shared__ float PE[DHEAD * NPOSE];
    __shared__ float QR[DMODEL];
    for (int i = tid; i < DHEAD * NPOSE; i += 256) PE[i] = pe[i];
    for (int i = tid; i < DMODEL; i += 256)
        QR[i] = bf2f(qh[(size_t)s1 * DMODEL + i]) + bf2f(ql[(size_t)s1 * DMODEL + i]);
    __syncthreads();
#pragma unroll
    for (int j = 0; j < 8; j++) {
        int o = j * 256 + tid;
        int h = o >> 7, n = o & 127;
        const float* qhp = &QR[h * DHEAD];
        float acc = 0.0f;
#pragma unroll 8
        for (int d = 0; d < DHEAD; d++) acc += qhp[d] * PE[d * NPOSE + n];
        li[(size_t)s1 * (NH * NPOSE) + o] = (f16)acc;
    }
}

// ---------------- fused CoPE: scan + bias + MFMA MLP + softmax -> P(bf16) ----------------
#define CSTR 2050
__global__ __launch_bounds__(1024, 1) void cope_k(f16* __restrict__ sc,
                                                  const f16* __restrict__ li,
                                                  const float* __restrict__ w1,
                                                  const float* __restrict__ b1,
                                                  const float* __restrict__ w2,
                                                  const float* __restrict__ b2,
                                                  int cb) {
    __shared__ f16 C[32 * CSTR];            // 131200 B
    __shared__ f16 Lif[NH * 130];           // 4160 B
    __shared__ ushort_t HMB[16][16 * 36];   // 18432 B -> 153792 total
    int r = blockIdx.x;
    int tid = threadIdx.x;
    int lane = tid & 63, wv = tid >> 6;     // wv in 0..15

    // stage scores: 16 rows x 1024 dwords, one dword per thread per row
    for (int h = 0; h < NH; h++) {
        const uint_t* s32 = (const uint_t*)(sc + ((size_t)h * CHUNK + r) * SEQ);
        uint_t* d32 = (uint_t*)&C[h * CSTR];
        d32[tid] = s32[tid];
    }
    {
        const f16* lsrc = li + (size_t)(cb + r) * (NH * NPOSE);
        for (int i = tid; i < NH * NPOSE; i += 1024)
            Lif[(i >> 7) * 130 + (i & 127)] = lsrc[i];
    }
    __syncthreads();

    // suffix scan + bias interp: wave wv handles head wv
    {
        f16* crow = &C[wv * CSTR];
        f16* brow = &C[(16 + wv) * CSTR];
        const f16* lrow = &Lif[wv * 130];
        float carry = 0.0f;
        for (int c = SEQ / 64 - 1; c >= 0; c--) {
            int t = c * 64 + lane;
            float g = sigm((float)crow[t]);
#pragma unroll
            for (int dd = 1; dd < 64; dd <<= 1) {
                float o = __shfl_down(g, dd, 64);
                g = (lane + dd < 64) ? g + o : g;
            }
            float total = __shfl(g, 0, 64);
            float pos = fminf(g + carry, 127.0f);
            carry += total;
            int fl = (int)pos;
            float fr = pos - (float)fl;
            float lf = (float)lrow[fl];
            float lc = (float)lrow[(fl < 127) ? fl + 1 : 127];
            brow[t] = (f16)(lc * fr + lf * (1.0f - fr));
        }
    }
    __syncthreads();

    // MLP weight fragments, hi/lo split (per wave)
    int fkg = lane >> 4;
    int fc = lane & 15;
    BF8 w1fH[2], w1fL[2], w2fH, w2fL;
    float b1v[2], b2v;
#pragma unroll
    for (int half = 0; half < 2; half++) {
#pragma unroll
        for (int j = 0; j < 8; j++) {
            float wval = w1[(fkg * 8 + j) * MLPWID + half * 16 + fc];
            ushort_t hb = f2bf(wval);
            w1fH[half].s[j] = hb;
            w1fL[half].s[j] = f2bf(wval - bf2f(hb));
        }
        b1v[half] = b1[half * 16 + fc];
    }
#pragma unroll
    for (int j = 0; j < 8; j++) {
        float wval = w2[(fkg * 8 + j) * NH + fc];
        ushort_t hb = f2bf(wval);
        w2fH.s[j] = hb;
        w2fL.s[j] = f2bf(wval - bf2f(hb));
    }
    b2v = b2[fc];

    // MFMA MLP over t-tiles of 16; wave wv does tiles wv, wv+16, ... (8 tiles)
    ushort_t* hmb = HMB[wv];
    for (int tt = wv; tt < SEQ / 16; tt += 16) {
        int t0 = tt * 16;
        BF8 afH, afL;
#pragma unroll
        for (int j = 0; j < 8; j++) {
            int f = fkg * 8 + j;
            float val = (float)C[f * CSTR + t0 + fc];
            ushort_t hb = f2bf(val);
            afH.s[j] = hb;
            afL.s[j] = f2bf(val - bf2f(hb));
        }
        f32x4 acc0 = (f32x4){b1v[0], b1v[0], b1v[0], b1v[0]};
        f32x4 acc1 = (f32x4){b1v[1], b1v[1], b1v[1], b1v[1]};
        acc0 = __builtin_amdgcn_mfma_f32_16x16x32_bf16(afH.v, w1fH[0].v, acc0, 0, 0, 0);
        acc0 = __builtin_amdgcn_mfma_f32_16x16x32_bf16(afH.v, w1fL[0].v, acc0, 0, 0, 0);
        acc0 = __builtin_amdgcn_mfma_f32_16x16x32_bf16(afL.v, w1fH[0].v, acc0, 0, 0, 0);
        acc1 = __builtin_amdgcn_mfma_f32_16x16x32_bf16(afH.v, w1fH[1].v, acc1, 0, 0, 0);
        acc1 = __builtin_amdgcn_mfma_f32_16x16x32_bf16(afH.v, w1fL[1].v, acc1, 0, 0, 0);
        acc1 = __builtin_amdgcn_mfma_f32_16x16x32_bf16(afL.v, w1fH[1].v, acc1, 0, 0, 0);
#pragma unroll
        for (int j2 = 0; j2 < 4; j2++) {
            int p = fkg * 4 + j2;
            float h0 = acc0[j2]; h0 = h0 * sigm(h0);
            float h1 = acc1[j2]; h1 = h1 * sigm(h1);
            hmb[p * 36 + fc] = f2bf(h0);
            hmb[p * 36 + 16 + fc] = f2bf(h1);
        }
        BF8 hfH;
        hfH.u2[0] = *(const uint2*)&hmb[fc * 36 + fkg * 8];
        hfH.u2[1] = *(const uint2*)&hmb[fc * 36 + fkg * 8 + 4];
        f32x4 acc2 = (f32x4){b2v, b2v, b2v, b2v};
        acc2 = __builtin_amdgcn_mfma_f32_16x16x32_bf16(hfH.v, w2fH.v, acc2, 0, 0, 0);
        acc2 = __builtin_amdgcn_mfma_f32_16x16x32_bf16(hfH.v, w2fL.v, acc2, 0, 0, 0);
#pragma unroll
        for (int j2 = 0; j2 < 4; j2 += 2) {
            uint_t* pp = (uint_t*)&C[fc * CSTR + t0 + fkg * 4 + j2];
            U1H2 old, neu;
            old.u = *pp;
            neu.h[0] = (f16)((float)old.h[0] + acc2[j2]);
            neu.h[1] = (f16)((float)old.h[1] + acc2[j2 + 1]);
            *pp = neu.u;
        }
    }
    __syncthreads();

    // fused softmax: wave wv -> head wv; write normalized P (bf16) to global
    {
        const f16* row = &C[wv * CSTR];
        float vals[32];
        float m = -1e30f;
#pragma unroll
        for (int c = 0; c < SEQ / 64; c++) {
            vals[c] = (float)row[c * 64 + lane];
            m = fmaxf(m, vals[c]);
        }
#pragma unroll
        for (int d = 1; d < 64; d <<= 1) m = fmaxf(m, __shfl_xor(m, d, 64));
        float s = 0.0f;
#pragma unroll
        for (int c = 0; c < SEQ / 64; c++) {
            vals[c] = __expf(vals[c] - m);
            s += vals[c];
        }
#pragma unroll
        for (int d = 1; d < 64; d <<= 1) s += __shfl_xor(s, d, 64);
        float ri = 1.0f / s;
        ushort_t* dst = (ushort_t*)sc + ((size_t)wv * CHUNK + r) * SEQ;
#pragma unroll
        for (int c = 0; c < SEQ / 64; c++) dst[c * 64 + lane] = f2bf(vals[c] * ri);
    }
}

// ---------------- MFMA PV (P already normalized bf16) -> aob bf16 ----------------
__global__ __launch_bounds__(256) void pvm_k(const ushort_t* __restrict__ scP,
                                             const ushort_t* __restrict__ vt,
                                             ushort_t* __restrict__ aob, int cb) {
    int h = blockIdx.y;
    int s0 = blockIdx.x * 32;
    __shared__ ushort_t P[32][72];
    __shared__ ushort_t Vt[64][72];
    int tid = threadIdx.x;
    int lane = tid & 63, wave = tid >> 6;
    int wr = (wave >> 1) * 16, wc = (wave & 1) * 32;
    f32x4 acc[2];
    acc[0] = (f32x4){0.f, 0.f, 0.f, 0.f};
    acc[1] = (f32x4){0.f, 0.f, 0.f, 0.f};
    int pr = tid >> 3, pc = (tid & 7) * 8;
    int vr = tid >> 2, vc = (tid & 3) * 16;
    for (int t0 = 0; t0 < SEQ; t0 += 64) {
        {
            *(uint4*)&P[pr][pc] =
                *(const uint4*)(scP + ((size_t)h * CHUNK + s0 + pr) * SEQ + t0 + pc);
            const ushort_t* vp = vt + ((size_t)h * 64 + vr) * SEQ + t0 + vc;
            *(uint4*)&Vt[vr][vc] = *(const uint4*)vp;
            *(uint4*)&Vt[vr][vc + 8] = *(const uint4*)(vp + 8);
        }
        __syncthreads();
#pragma unroll
        for (int ks = 0; ks < 2; ks++) {
            int kof = ks * 32 + (lane >> 4) * 8;
            bf16x8 pa = *(const bf16x8*)&P[wr + (lane & 15)][kof];
#pragma unroll
            for (int n = 0; n < 2; n++) {
                bf16x8 vb = *(const bf16x8*)&Vt[wc + n * 16 + (lane & 15)][kof];
                acc[n] = __builtin_amdgcn_mfma_f32_16x16x32_bf16(pa, vb, acc[n], 0, 0, 0);
            }
        }
        __syncthreads();
    }
#pragma unroll
    for (int j = 0; j < 4; j++) {
        int s = cb + s0 + wr + (lane >> 4) * 4 + j;
#pragma unroll
        for (int n = 0; n < 2; n++) {
            int d = h * 64 + wc + n * 16 + (lane & 15);
            aob[(size_t)s * DMODEL + d] = f2bf(acc[n][j]);
        }
    }
}

extern "C" void kernel_launch(void* const* d_in, const int* in_sizes, int n_in,
                              void* d_out, int out_size, void* d_ws, size_t ws_size,
                              hipStream_t stream) {
    const float* x = (const float*)d_in[0];
    const float* wq = (const float*)d_in[1];
    const float* wk = (const float*)d_in[2];
    const float* wv = (const float*)d_in[3];
    const float* wo = (const float*)d_in[4];
    const float* pos_emb = (const float*)d_in[5];
    const float* mlp_w1 = (const float*)d_in[6];
    const float* mlp_b1 = (const float*)d_in[7];
    const float* mlp_w2 = (const float*)d_in[8];
    const float* mlp_b2 = (const float*)d_in[9];
    const float* ffn_w1 = (const float*)d_in[10];
    const float* ffn_w2 = (const float*)d_in[11];
    const float* ffn_w3 = (const float*)d_in[12];
    const float* attn_norm_w = (const float*)d_in[13];
    const float* ffn_norm_w = (const float*)d_in[14];
    float* out = (float*)d_out;

    char* ws = (char*)d_ws;
    const size_t MB = 1024 * 1024;
    ushort_t* nxb = (ushort_t*)(ws + 0);             // 0-4
    ushort_t* qh = (ushort_t*)(ws + 4 * MB);         // 4-8   (phase C: nxb2)
    ushort_t* ql = (ushort_t*)(ws + 8 * MB);         // 8-12  (phase C: g1b 8-24)
    ushort_t* kb = (ushort_t*)(ws + 12 * MB);        // 12-16
    ushort_t* vb = (ushort_t*)(ws + 16 * MB);        // 16-20
    ushort_t* vt = (ushort_t*)(ws + 20 * MB);        // 20-24
    f16* li = (f16*)(ws + 24 * MB);                  // 24-32
    ushort_t* aob = (ushort_t*)(ws + 33 * MB);       // 33-37
    float* x1 = (float*)(ws + 37 * MB);              // 37-45
    ushort_t* wqkvt = (ushort_t*)(ws + 45 * MB);     // 45-51 (phase 1)
    f16* sc = (f16*)(ws + 45 * MB);                  // 45-109 (phase 2, CHUNK=1024)
    ushort_t* wot = (ushort_t*)(ws + 45 * MB);       // 45-47 (phase B)
    ushort_t* w13t = (ushort_t*)(ws + 47 * MB);      // 47-63 (interleaved, 16MB)
    ushort_t* w2t = (ushort_t*)(ws + 63 * MB);       // 63-71
    ushort_t* nxb2 = (ushort_t*)(ws + 4 * MB);
    ushort_t* g1b = (ushort_t*)(ws + 8 * MB);        // 8-24

    // ---- phase 1: norm + fused QKV (64-tile, 1536 blocks) ----
    transconv_k<<<dim3(DMODEL / 64, DMODEL / 64), 256, 0, stream>>>(wq, wqkvt, DMODEL, DMODEL);
    transconv_k<<<dim3(DMODEL / 64, DMODEL / 64), 256, 0, stream>>>(wk, wqkvt + 1024 * 1024, DMODEL, DMODEL);
    transconv_k<<<dim3(DMODEL / 64, DMODEL / 64), 256, 0, stream>>>(wv, wqkvt + 2 * 1024 * 1024, DMODEL, DMODEL);
    rmsnormbf_k<<<SEQ, 256, 0, stream>>>(x, attn_norm_w, nxb);
    gemm64_k<<<dim3(3 * DMODEL / 64, SEQ / 64), 256, 0, stream>>>(
        nxb, wqkvt, nullptr, qh, SEQ, 3 * DMODEL, DMODEL, 2, ql, kb, vb);
    copelogits_k<<<SEQ, 256, 0, stream>>>(qh, ql, pos_emb, li);
    tv_k<<<dim3(SEQ / 64, NH), 256, 0, stream>>>(vb, vt);

    // ---- phase 2: attention chunks ----
    for (int ch = 0; ch < NCH; ch++) {
        int cb = ch * CHUNK;
        scoresm_k<<<dim3(SEQ / 64, CHUNK / 64, NH), 256, 0, stream>>>(qh, ql, kb, sc, cb);
        cope_k<<<CHUNK, 1024, 0, stream>>>(sc, li, mlp_w1, mlp_b1, mlp_w2, mlp_b2, cb);
        pvm_k<<<dim3(CHUNK / 32, NH), 256, 0, stream>>>((const ushort_t*)sc, vt, aob, cb);
    }

    // ---- phase B: out @ wo + x (64-tile, 512 blocks) ----
    transconv_k<<<dim3(DMODEL / 64, DMODEL / 64), 256, 0, stream>>>(wo, wot, DMODEL, DMODEL);
    gemm64_k<<<dim3(DMODEL / 64, SEQ / 64), 256, 0, stream>>>(
        aob, wot, x, x1, SEQ, DMODEL, DMODEL, 0, nullptr, nullptr, nullptr);

    // ---- phase C: FFN ----
    rmsnormbf_k<<<SEQ, 256, 0, stream>>>(x1, ffn_norm_w, nxb2);
    transconv2_k<<<dim3(FFDIM / 64, DMODEL / 64), 256, 0, stream>>>(ffn_w1, ffn_w3, w13t, DMODEL, FFDIM);
    transconv_k<<<dim3(DMODEL / 64, FFDIM / 64), 256, 0, stream>>>(ffn_w2, w2t, FFDIM, DMODEL);
    gemm_bf16_k<<<dim3(2 * FFDIM / 128, SEQ / 128), 256, 0, stream>>>(
        nxb2, w13t, nullptr, g1b, SEQ, 2 * FFDIM, DMODEL, 4);
    gemm64_k<<<dim3(DMODEL / 64, SEQ / 64), 256, 0, stream>>>(
        g1b, w2t, x1, out, SEQ, DMODEL, FFDIM, 0, nullptr, nullptr, nullptr);
}

// Round 12
// 509.831 us; speedup vs baseline: 7.7654x; 1.1824x over previous
//
#include <hip/hip_runtime.h>
#include <hip/hip_bf16.h>
#include <hip/hip_fp16.h>
#include <math.h>

#define SEQ 2048
#define DMODEL 1024
#define NH 16
#define DHEAD 64
#define FFDIM 4096
#define NPOSE 128
#define MLPWID 32
#define EPSV 1e-5f
#define CHUNK 1024
#define NCH (SEQ / CHUNK)

typedef unsigned short ushort_t;
typedef unsigned int uint_t;
typedef _Float16 f16;
typedef __attribute__((ext_vector_type(8))) _Float16 f16x8;
typedef __attribute__((ext_vector_type(4))) float f32x4;

union HF8 { f16x8 v; f16 h[8]; ushort_t s[8]; uint2 u2[2]; uint4 u4; };
union U1H2 { uint_t u; f16 h[2]; };
union U2H4 { uint2 u; f16 h[4]; };

__device__ __forceinline__ float sigm(float x) {
    return 1.0f / (1.0f + __expf(-x));
}
__device__ __forceinline__ void gl_lds16(const void* g, void* l) {
    __builtin_amdgcn_global_load_lds((const __attribute__((address_space(1))) uint_t*)g,
                                     (__attribute__((address_space(3))) uint_t*)l, 16, 0, 0);
}

// ---------------- RMSNorm, f16 out ----------------
__global__ __launch_bounds__(256) void rmsnormf_k(const float* __restrict__ x,
                                                  const float* __restrict__ w,
                                                  f16* __restrict__ o) {
    int row = blockIdx.x;
    int tid = threadIdx.x;
    const float4* xr = (const float4*)(x + (size_t)row * DMODEL);
    float4 v = xr[tid];
    float ss = v.x * v.x + v.y * v.y + v.z * v.z + v.w * v.w;
#pragma unroll
    for (int d = 1; d < 64; d <<= 1) ss += __shfl_xor(ss, d, 64);
    __shared__ float red[4];
    int lane = tid & 63, wv = tid >> 6;
    if (lane == 0) red[wv] = ss;
    __syncthreads();
    float tot = red[0] + red[1] + red[2] + red[3];
    float r = rsqrtf(tot / (float)DMODEL + EPSV);
    const float4* wr = (const float4*)w;
    float4 wv4 = wr[tid];
    U2H4 ob;
    ob.h[0] = (f16)(v.x * r * wv4.x);
    ob.h[1] = (f16)(v.y * r * wv4.y);
    ob.h[2] = (f16)(v.z * r * wv4.z);
    ob.h[3] = (f16)(v.w * r * wv4.w);
    ((uint2*)(o + (size_t)row * DMODEL))[tid] = ob.u;
}

// ---------------- V transpose (bit copy): vb[SEQ][DMODEL] -> vt[NH][DHEAD][SEQ] ----------------
__global__ __launch_bounds__(256) void tv_k(const ushort_t* __restrict__ vb,
                                            ushort_t* __restrict__ vt) {
    int h = blockIdx.y, t0 = blockIdx.x * 64;
    __shared__ ushort_t T[64][76];
    int tid = threadIdx.x;
#pragma unroll
    for (int it = 0; it < 2; it++) {
        int a = tid + it * 256;
        int t = a >> 3, c8 = (a & 7) * 8;
        HF8 v;
        v.u4 = *(const uint4*)(vb + (size_t)(t0 + t) * DMODEL + h * 64 + c8);
#pragma unroll
        for (int j = 0; j < 8; j++) T[c8 + j][t] = v.s[j];
    }
    __syncthreads();
#pragma unroll
    for (int it = 0; it < 2; it++) {
        int a = tid + it * 256;
        int d = a >> 3, c8 = (a & 7) * 8;
        HF8 o;
#pragma unroll
        for (int j = 0; j < 8; j++) o.s[j] = T[d][c8 + j];
        *(uint4*)(vt + ((size_t)h * 64 + d) * SEQ + t0 + c8) = o.u4;
    }
}

// ---------------- weight transpose+convert: f32[K][N] -> f16[N][K] ----------------
__global__ __launch_bounds__(256) void transconv_k(const float* __restrict__ in,
                                                   f16* __restrict__ out,
                                                   int K, int N) {
    __shared__ f16 T[64][72];
    int k0 = blockIdx.y * 64, n0 = blockIdx.x * 64;
    int tid = threadIdx.x;
    int r = tid >> 4, c4 = (tid & 15) * 4;
#pragma unroll
    for (int i = 0; i < 4; i++) {
        float4 v = *(const float4*)(in + (size_t)(k0 + r + i * 16) * N + n0 + c4);
        T[c4 + 0][r + i * 16] = (f16)v.x;
        T[c4 + 1][r + i * 16] = (f16)v.y;
        T[c4 + 2][r + i * 16] = (f16)v.z;
        T[c4 + 3][r + i * 16] = (f16)v.w;
    }
    __syncthreads();
    int n = tid >> 2, kk = (tid & 3) * 16;
    uint4* dst = (uint4*)(out + (size_t)(n0 + n) * K + k0 + kk);
    dst[0] = *(const uint4*)&T[n][kk];
    dst[1] = *(const uint4*)&T[n][kk + 8];
}

// ---------------- w1/w3 transpose+convert, row-interleaved (16-col groups) ----------------
__global__ __launch_bounds__(256) void transconv2_k(const float* __restrict__ w1,
                                                    const float* __restrict__ w3,
                                                    f16* __restrict__ out,
                                                    int K, int N) {
    __shared__ f16 T[64][72];
    int k0 = blockIdx.y * 64, n0 = blockIdx.x * 64;
    int tid = threadIdx.x;
    int r = tid >> 4, c4 = (tid & 15) * 4;
    int n = tid >> 2, kk = (tid & 3) * 16;
#pragma unroll
    for (int half = 0; half < 2; half++) {
        const float* in = half ? w3 : w1;
#pragma unroll
        for (int i = 0; i < 4; i++) {
            float4 v = *(const float4*)(in + (size_t)(k0 + r + i * 16) * N + n0 + c4);
            T[c4 + 0][r + i * 16] = (f16)v.x;
            T[c4 + 1][r + i * 16] = (f16)v.y;
            T[c4 + 2][r + i * 16] = (f16)v.z;
            T[c4 + 3][r + i * 16] = (f16)v.w;
        }
        __syncthreads();
        int gc = n0 + n;
        int rp = (gc >> 4) * 32 + (gc & 15) + half * 16;
        uint4* dst = (uint4*)(out + (size_t)rp * K + k0 + kk);
        dst[0] = *(const uint4*)&T[n][kk];
        dst[1] = *(const uint4*)&T[n][kk + 8];
        __syncthreads();
    }
}

// ---------------- f16 MFMA GEMM 128x128 (TN), XCD-swizzled ----------------
// mode 0: f32 out (+add). mode 1: f16 out. mode 4: w1w3-interleaved silu-mul.
__global__ __launch_bounds__(256) void gemm128_k(const f16* __restrict__ A,
                                                 const f16* __restrict__ Bt,
                                                 const float* __restrict__ add,
                                                 void* __restrict__ Cout,
                                                 int M, int N, int K, int mode) {
    __shared__ f16 Al[128 * 32];
    __shared__ f16 Bl[128 * 32];
    int tid = threadIdx.x;
    int lane = tid & 63, wave = tid >> 6;
    int gx = gridDim.x, gy = gridDim.y;
    int nwg = gx * gy;
    int bx = blockIdx.x, by = blockIdx.y;
    if ((nwg & 7) == 0) {
        int flat = by * gx + bx;
        int cpx = nwg >> 3;
        int l = (flat & 7) * cpx + (flat >> 3);
        bx = l / gy;
        by = l % gy;
    }
    int brow = by * 128, bcol = bx * 128;
    int wr = (wave >> 1) * 64, wc = (wave & 1) * 64;
    f32x4 acc[4][4];
#pragma unroll
    for (int m = 0; m < 4; m++)
#pragma unroll
        for (int n = 0; n < 4; n++) acc[m][n] = (f32x4){0.f, 0.f, 0.f, 0.f};

    const f16* Ag = A + (size_t)(brow + (tid >> 2)) * K + (tid & 3) * 8;
    const f16* Bg = Bt + (size_t)(bcol + (tid >> 2)) * K + (tid & 3) * 8;
    f16* Ald = &Al[wave * 512];
    f16* Bld = &Bl[wave * 512];
    size_t rstep = (size_t)64 * K;

    for (int k0 = 0; k0 < K; k0 += 32) {
        gl_lds16(Ag + k0, Ald);
        gl_lds16(Ag + k0 + rstep, Ald + 2048);
        gl_lds16(Bg + k0, Bld);
        gl_lds16(Bg + k0 + rstep, Bld + 2048);
        __syncthreads();
        f16x8 af[4], bfr[4];
        int arow = wr + (lane & 15);
        int brw = wc + (lane & 15);
        int kof = (lane >> 4) * 8;
#pragma unroll
        for (int m = 0; m < 4; m++) af[m] = *(const f16x8*)&Al[(arow + m * 16) * 32 + kof];
#pragma unroll
        for (int n = 0; n < 4; n++) bfr[n] = *(const f16x8*)&Bl[(brw + n * 16) * 32 + kof];
#pragma unroll
        for (int m = 0; m < 4; m++)
#pragma unroll
            for (int n = 0; n < 4; n++)
                acc[m][n] = __builtin_amdgcn_mfma_f32_16x16x32_f16(af[m], bfr[n], acc[m][n], 0, 0, 0);
        __syncthreads();
    }
    int crow0 = brow + wr + (lane >> 4) * 4;
    int ccol = bcol + wc + (lane & 15);
#pragma unroll
    for (int m = 0; m < 4; m++)
#pragma unroll
        for (int j = 0; j < 4; j++) {
            int row = crow0 + m * 16 + j;
            if (mode == 4) {
#pragma unroll
                for (int n = 0; n < 4; n += 2) {
                    int c = ccol + n * 16;
                    int colOut = (c >> 5) * 16 + (c & 15);
                    float v1 = acc[m][n][j];
                    float v3 = acc[m][n + 1][j];
                    ((f16*)Cout)[(size_t)row * (N / 2) + colOut] =
                        (f16)(v1 * sigm(v1) * v3);
                }
            } else {
#pragma unroll
                for (int n = 0; n < 4; n++) {
                    int col = ccol + n * 16;
                    float v = acc[m][n][j];
                    if (mode == 0) {
                        if (add) v += add[(size_t)row * N + col];
                        ((float*)Cout)[(size_t)row * N + col] = v;
                    } else {
                        ((f16*)Cout)[(size_t)row * N + col] = (f16)v;
                    }
                }
            }
        }
}

// ---------------- f16 MFMA GEMM 64x64 (TN), XCD-swizzled ----------------
// mode 0: f32 out (+add). mode 1: f16. mode 2: qkv split (Cout=q, p2=k, p3=v).
__global__ __launch_bounds__(256) void gemm64_k(const f16* __restrict__ A,
                                                const f16* __restrict__ Bt,
                                                const float* __restrict__ add,
                                                void* __restrict__ Cout,
                                                int M, int N, int K, int mode,
                                                f16* __restrict__ p2,
                                                f16* __restrict__ p3) {
    __shared__ f16 Al[64 * 32];
    __shared__ f16 Bl[64 * 32];
    int tid = threadIdx.x;
    int lane = tid & 63, wave = tid >> 6;
    int gx = gridDim.x, gy = gridDim.y;
    int nwg = gx * gy;
    int bx = blockIdx.x, by = blockIdx.y;
    if ((nwg & 7) == 0) {
        int flat = by * gx + bx;
        int cpx = nwg >> 3;
        int l = (flat & 7) * cpx + (flat >> 3);
        bx = l / gy;
        by = l % gy;
    }
    int brow = by * 64, bcol = bx * 64;
    int wr = (wave >> 1) * 32, wc = (wave & 1) * 32;
    f32x4 acc[2][2];
#pragma unroll
    for (int m = 0; m < 2; m++)
#pragma unroll
        for (int n = 0; n < 2; n++) acc[m][n] = (f32x4){0.f, 0.f, 0.f, 0.f};

    const f16* Ag = A + (size_t)(brow + (tid >> 2)) * K + (tid & 3) * 8;
    const f16* Bg = Bt + (size_t)(bcol + (tid >> 2)) * K + (tid & 3) * 8;
    f16* Ald = &Al[wave * 512];
    f16* Bld = &Bl[wave * 512];

    for (int k0 = 0; k0 < K; k0 += 32) {
        gl_lds16(Ag + k0, Ald);
        gl_lds16(Bg + k0, Bld);
        __syncthreads();
        f16x8 af[2], bfr[2];
        int kof = (lane >> 4) * 8;
#pragma unroll
        for (int m = 0; m < 2; m++)
            af[m] = *(const f16x8*)&Al[(wr + m * 16 + (lane & 15)) * 32 + kof];
#pragma unroll
        for (int n = 0; n < 2; n++)
            bfr[n] = *(const f16x8*)&Bl[(wc + n * 16 + (lane & 15)) * 32 + kof];
#pragma unroll
        for (int m = 0; m < 2; m++)
#pragma unroll
            for (int n = 0; n < 2; n++)
                acc[m][n] = __builtin_amdgcn_mfma_f32_16x16x32_f16(af[m], bfr[n], acc[m][n], 0, 0, 0);
        __syncthreads();
    }
    int crow0 = brow + wr + (lane >> 4) * 4;
    int ccol = bcol + wc + (lane & 15);
#pragma unroll
    for (int m = 0; m < 2; m++)
#pragma unroll
        for (int j = 0; j < 4; j++) {
            int row = crow0 + m * 16 + j;
#pragma unroll
            for (int n = 0; n < 2; n++) {
                int col = ccol + n * 16;
                float v = acc[m][n][j];
                if (mode == 0) {
                    if (add) v += add[(size_t)row * N + col];
                    ((float*)Cout)[(size_t)row * N + col] = v;
                } else if (mode == 1) {
                    ((f16*)Cout)[(size_t)row * N + col] = (f16)v;
                } else {
                    size_t o = (size_t)row * DMODEL;
                    if (col < DMODEL) ((f16*)Cout)[o + col] = (f16)v;
                    else if (col < 2 * DMODEL) p2[o + col - DMODEL] = (f16)v;
                    else p3[o + col - 2 * DMODEL] = (f16)v;
                }
            }
        }
}

// ---------------- MFMA scores: sc[h][il][j] = qf_i . kf_j / 8 ----------------
__global__ __launch_bounds__(256) void scoresm_k(const f16* __restrict__ qf,
                                                 const f16* __restrict__ kf,
                                                 f16* __restrict__ sc, int cb) {
    int h = blockIdx.z;
    int il0 = blockIdx.y * 64;
    int j0 = blockIdx.x * 64;
    __shared__ f16 Qf[64][72];
    __shared__ f16 Kf[64][72];
    int tid = threadIdx.x;
    {
        int r = tid >> 2, c0 = (tid & 3) * 16;
        const f16* p;
        p = qf + (size_t)(cb + il0 + r) * DMODEL + h * 64 + c0;
        *(uint4*)&Qf[r][c0] = *(const uint4*)p;
        *(uint4*)&Qf[r][c0 + 8] = *(const uint4*)(p + 8);
        p = kf + (size_t)(j0 + r) * DMODEL + h * 64 + c0;
        *(uint4*)&Kf[r][c0] = *(const uint4*)p;
        *(uint4*)&Kf[r][c0 + 8] = *(const uint4*)(p + 8);
    }
    __syncthreads();
    int lane = tid & 63, wave = tid >> 6;
    int wr = (wave >> 1) * 32, wc = (wave & 1) * 32;
    f32x4 acc[2][2];
#pragma unroll
    for (int m = 0; m < 2; m++)
#pragma unroll
        for (int n = 0; n < 2; n++) acc[m][n] = (f32x4){0.f, 0.f, 0.f, 0.f};
#pragma unroll
    for (int ks = 0; ks < 2; ks++) {
        int kof = ks * 32 + (lane >> 4) * 8;
        f16x8 aQ[2], bK[2];
#pragma unroll
        for (int m = 0; m < 2; m++)
            aQ[m] = *(const f16x8*)&Qf[wr + m * 16 + (lane & 15)][kof];
#pragma unroll
        for (int n = 0; n < 2; n++)
            bK[n] = *(const f16x8*)&Kf[wc + n * 16 + (lane & 15)][kof];
#pragma unroll
        for (int m = 0; m < 2; m++)
#pragma unroll
            for (int n = 0; n < 2; n++)
                acc[m][n] = __builtin_amdgcn_mfma_f32_16x16x32_f16(aQ[m], bK[n], acc[m][n], 0, 0, 0);
    }
#pragma unroll
    for (int m = 0; m < 2; m++)
#pragma unroll
        for (int j = 0; j < 4; j++) {
            int il = il0 + wr + m * 16 + (lane >> 4) * 4 + j;
#pragma unroll
            for (int n = 0; n < 2; n++) {
                int jj = j0 + wc + n * 16 + (lane & 15);
                sc[((size_t)h * CHUNK + il) * SEQ + jj] = (f16)(acc[m][n][j] * 0.125f);
            }
        }
}

// ---------------- logits_int -> f16 (reads qf) ----------------
__global__ __launch_bounds__(256) void copelogits_k(const f16* __restrict__ qf,
                                                    const float* __restrict__ pe,
                                                    f16* __restrict__ li) {
    int s1 = blockIdx.x;
    int tid = threadIdx.x;
    __shared__ float PE[DHEAD * NPOSE];
    __shared__ float QR[DMODEL];
    for (int i = tid; i < DHEAD * NPOSE; i += 256) PE[i] = pe[i];
    for (int i = tid; i < DMODEL; i += 256) QR[i] = (float)qf[(size_t)s1 * DMODEL + i];
    __syncthreads();
#pragma unroll
    for (int j = 0; j < 8; j++) {
        int o = j * 256 + tid;
        int h = o >> 7, n = o & 127;
        const float* qhp = &QR[h * DHEAD];
        float acc = 0.0f;
#pragma unroll 8
        for (int d = 0; d < DHEAD; d++) acc += qhp[d] * PE[d * NPOSE + n];
        li[(size_t)s1 * (NH * NPOSE) + o] = (f16)acc;
    }
}

// ---------------- fused CoPE: scan + bias + f16 MFMA MLP + softmax -> P(f16) ----------------
#define CSTR 2052
__global__ __launch_bounds__(1024, 1) void cope_k(f16* __restrict__ sc,
                                                  const f16* __restrict__ li,
                                                  const float* __restrict__ w1,
                                                  const float* __restrict__ b1,
                                                  const float* __restrict__ w2,
                                                  const float* __restrict__ b2,
                                                  int cb) {
    __shared__ f16 C[32 * CSTR];           // 131328 B
    __shared__ uint_t Lif2[NH * 130];      // 8320 B: packed (li[n], li[n+1])
    __shared__ f16 HMB[16][16 * 36];       // 18432 B -> 158080 total
    int r = blockIdx.x;
    int tid = threadIdx.x;
    int lane = tid & 63, wv = tid >> 6;    // wv in 0..15

    // stage scores: 16 rows x 1024 dwords
    for (int h = 0; h < NH; h++) {
        const uint_t* s32 = (const uint_t*)(sc + ((size_t)h * CHUNK + r) * SEQ);
        uint_t* d32 = (uint_t*)&C[h * CSTR];
        d32[tid] = s32[tid];
    }
    {
        const f16* lsrc = li + (size_t)(cb + r) * (NH * NPOSE);
        for (int i = tid; i < NH * NPOSE; i += 1024) {
            int h = i >> 7, n = i & 127;
            U1H2 pk;
            pk.h[0] = lsrc[h * NPOSE + n];
            pk.h[1] = lsrc[h * NPOSE + ((n < NPOSE - 1) ? n + 1 : NPOSE - 1)];
            Lif2[h * 130 + n] = pk.u;
        }
    }
    __syncthreads();

    // suffix scan + bias interp: wave wv handles head wv; 4 positions per lane
    {
        f16* crow = &C[wv * CSTR];
        f16* brow = &C[(16 + wv) * CSTR];
        const uint_t* lrow = &Lif2[wv * 130];
        float carry = 0.0f;
        for (int c = SEQ / 256 - 1; c >= 0; c--) {
            int t = c * 256 + lane * 4;
            U2H4 sv;
            sv.u = *(const uint2*)&crow[t];
            float g0 = sigm((float)sv.h[0]);
            float g1 = sigm((float)sv.h[1]);
            float g2 = sigm((float)sv.h[2]);
            float g3 = sigm((float)sv.h[3]);
            float S = g0 + g1 + g2 + g3;
#pragma unroll
            for (int dd = 1; dd < 64; dd <<= 1) {
                float o = __shfl_down(S, dd, 64);
                S = (lane + dd < 64) ? S + o : S;
            }
            float total = __shfl(S, 0, 64);
            float p0 = S + carry;
            float p1 = p0 - g0;
            float p2 = p1 - g1;
            float p3 = p2 - g2;
            carry += total;
            float ps[4] = {p0, p1, p2, p3};
            U2H4 bo;
#pragma unroll
            for (int e = 0; e < 4; e++) {
                float pos = fminf(ps[e], 127.0f);
                int fl = (int)pos;
                float fr = pos - (float)fl;
                U1H2 lv;
                lv.u = lrow[fl];
                float lf = (float)lv.h[0];
                float lc = (float)lv.h[1];
                bo.h[e] = (f16)(lf + (lc - lf) * fr);
            }
            *(uint2*)&brow[t] = bo.u;
        }
    }
    __syncthreads();

    // MLP weight fragments (f16, single precision plane)
    int fkg = lane >> 4;
    int fc = lane & 15;
    HF8 w1f[2], w2f;
    float b1v[2], b2v;
#pragma unroll
    for (int half = 0; half < 2; half++) {
#pragma unroll
        for (int j = 0; j < 8; j++)
            w1f[half].h[j] = (f16)w1[(fkg * 8 + j) * MLPWID + half * 16 + fc];
        b1v[half] = b1[half * 16 + fc];
    }
#pragma unroll
    for (int j = 0; j < 8; j++) w2f.h[j] = (f16)w2[(fkg * 8 + j) * NH + fc];
    b2v = b2[fc];

    // f16 MFMA MLP over t-tiles of 16; wave wv does tiles wv, wv+16, ... (8 tiles)
    f16* hmb = HMB[wv];
    for (int tt = wv; tt < SEQ / 16; tt += 16) {
        int t0 = tt * 16;
        HF8 af;
#pragma unroll
        for (int j = 0; j < 8; j++) af.h[j] = C[(fkg * 8 + j) * CSTR + t0 + fc];
        f32x4 acc0 = (f32x4){b1v[0], b1v[0], b1v[0], b1v[0]};
        f32x4 acc1 = (f32x4){b1v[1], b1v[1], b1v[1], b1v[1]};
        acc0 = __builtin_amdgcn_mfma_f32_16x16x32_f16(af.v, w1f[0].v, acc0, 0, 0, 0);
        acc1 = __builtin_amdgcn_mfma_f32_16x16x32_f16(af.v, w1f[1].v, acc1, 0, 0, 0);
#pragma unroll
        for (int j2 = 0; j2 < 4; j2++) {
            int p = fkg * 4 + j2;
            float h0 = acc0[j2]; h0 = h0 * sigm(h0);
            float h1 = acc1[j2]; h1 = h1 * sigm(h1);
            hmb[p * 36 + fc] = (f16)h0;
            hmb[p * 36 + 16 + fc] = (f16)h1;
        }
        HF8 hf;
        hf.u2[0] = *(const uint2*)&hmb[fc * 36 + fkg * 8];
        hf.u2[1] = *(const uint2*)&hmb[fc * 36 + fkg * 8 + 4];
        f32x4 acc2 = (f32x4){b2v, b2v, b2v, b2v};
        acc2 = __builtin_amdgcn_mfma_f32_16x16x32_f16(hf.v, w2f.v, acc2, 0, 0, 0);
#pragma unroll
        for (int j2 = 0; j2 < 4; j2 += 2) {
            uint_t* pp = (uint_t*)&C[fc * CSTR + t0 + fkg * 4 + j2];
            U1H2 old, neu;
            old.u = *pp;
            neu.h[0] = (f16)((float)old.h[0] + acc2[j2]);
            neu.h[1] = (f16)((float)old.h[1] + acc2[j2 + 1]);
            *pp = neu.u;
        }
    }
    __syncthreads();

    // fused softmax: wave wv -> head wv; write normalized P (f16) to global
    {
        const f16* row = &C[wv * CSTR];
        float vals[32];
        float m = -1e30f;
#pragma unroll
        for (int c = 0; c < 8; c++) {
            U2H4 sv;
            sv.u = *(const uint2*)&row[c * 256 + lane * 4];
#pragma unroll
            for (int e = 0; e < 4; e++) {
                vals[c * 4 + e] = (float)sv.h[e];
                m = fmaxf(m, vals[c * 4 + e]);
            }
        }
#pragma unroll
        for (int d = 1; d < 64; d <<= 1) m = fmaxf(m, __shfl_xor(m, d, 64));
        float s = 0.0f;
#pragma unroll
        for (int c = 0; c < 32; c++) {
            vals[c] = __expf(vals[c] - m);
            s += vals[c];
        }
#pragma unroll
        for (int d = 1; d < 64; d <<= 1) s += __shfl_xor(s, d, 64);
        float ri = 1.0f / s;
        f16* dst = sc + ((size_t)wv * CHUNK + r) * SEQ;
#pragma unroll
        for (int c = 0; c < 8; c++) {
            U2H4 po;
#pragma unroll
            for (int e = 0; e < 4; e++) po.h[e] = (f16)(vals[c * 4 + e] * ri);
            *(uint2*)&dst[c * 256 + lane * 4] = po.u;
        }
    }
}

// ---------------- f16 MFMA PV (P normalized) -> aob f16 ----------------
__global__ __launch_bounds__(256) void pvm_k(const f16* __restrict__ scP,
                                             const ushort_t* __restrict__ vt,
                                             f16* __restrict__ aob, int cb) {
    int h = blockIdx.y;
    int s0 = blockIdx.x * 32;
    __shared__ f16 P[32][72];
    __shared__ f16 Vt[64][72];
    int tid = threadIdx.x;
    int lane = tid & 63, wave = tid >> 6;
    int wr = (wave >> 1) * 16, wc = (wave & 1) * 32;
    f32x4 acc[2];
    acc[0] = (f32x4){0.f, 0.f, 0.f, 0.f};
    acc[1] = (f32x4){0.f, 0.f, 0.f, 0.f};
    int pr = tid >> 3, pc = (tid & 7) * 8;
    int vr = tid >> 2, vc = (tid & 3) * 16;
    for (int t0 = 0; t0 < SEQ; t0 += 64) {
        {
            *(uint4*)&P[pr][pc] =
                *(const uint4*)(scP + ((size_t)h * CHUNK + s0 + pr) * SEQ + t0 + pc);
            const ushort_t* vp = vt + ((size_t)h * 64 + vr) * SEQ + t0 + vc;
            *(uint4*)&Vt[vr][vc] = *(const uint4*)vp;
            *(uint4*)&Vt[vr][vc + 8] = *(const uint4*)(vp + 8);
        }
        __syncthreads();
#pragma unroll
        for (int ks = 0; ks < 2; ks++) {
            int kof = ks * 32 + (lane >> 4) * 8;
            f16x8 pa = *(const f16x8*)&P[wr + (lane & 15)][kof];
#pragma unroll
            for (int n = 0; n < 2; n++) {
                f16x8 vb = *(const f16x8*)&Vt[wc + n * 16 + (lane & 15)][kof];
                acc[n] = __builtin_amdgcn_mfma_f32_16x16x32_f16(pa, vb, acc[n], 0, 0, 0);
            }
        }
        __syncthreads();
    }
#pragma unroll
    for (int j = 0; j < 4; j++) {
        int s = cb + s0 + wr + (lane >> 4) * 4 + j;
#pragma unroll
        for (int n = 0; n < 2; n++) {
            int d = h * 64 + wc + n * 16 + (lane & 15);
            aob[(size_t)s * DMODEL + d] = (f16)acc[n][j];
        }
    }
}

extern "C" void kernel_launch(void* const* d_in, const int* in_sizes, int n_in,
                              void* d_out, int out_size, void* d_ws, size_t ws_size,
                              hipStream_t stream) {
    const float* x = (const float*)d_in[0];
    const float* wq = (const float*)d_in[1];
    const float* wk = (const float*)d_in[2];
    const float* wv = (const float*)d_in[3];
    const float* wo = (const float*)d_in[4];
    const float* pos_emb = (const float*)d_in[5];
    const float* mlp_w1 = (const float*)d_in[6];
    const float* mlp_b1 = (const float*)d_in[7];
    const float* mlp_w2 = (const float*)d_in[8];
    const float* mlp_b2 = (const float*)d_in[9];
    const float* ffn_w1 = (const float*)d_in[10];
    const float* ffn_w2 = (const float*)d_in[11];
    const float* ffn_w3 = (const float*)d_in[12];
    const float* attn_norm_w = (const float*)d_in[13];
    const float* ffn_norm_w = (const float*)d_in[14];
    float* out = (float*)d_out;

    char* ws = (char*)d_ws;
    const size_t MB = 1024 * 1024;
    f16* nxb = (f16*)(ws + 0);               // 0-4
    f16* qf = (f16*)(ws + 4 * MB);           // 4-8   (phase C: nxb2)
    f16* kf = (f16*)(ws + 8 * MB);           // 8-12  (phase C: g1b 8-24)
    f16* vb = (f16*)(ws + 12 * MB);          // 12-16
    f16* vt = (f16*)(ws + 16 * MB);          // 16-20
    f16* li = (f16*)(ws + 20 * MB);          // 20-28
    f16* aob = (f16*)(ws + 28 * MB);         // 28-32
    float* x1 = (float*)(ws + 32 * MB);      // 32-40
    f16* wqkvt = (f16*)(ws + 40 * MB);       // 40-46 (phase 1)
    f16* sc = (f16*)(ws + 40 * MB);          // 40-104 (phase 2, CHUNK=1024)
    f16* wot = (f16*)(ws + 40 * MB);         // 40-42 (phase B)
    f16* w13t = (f16*)(ws + 40 * MB);        // 40-56 (phase C, interleaved)
    f16* w2t = (f16*)(ws + 56 * MB);         // 56-64
    f16* nxb2 = (f16*)(ws + 4 * MB);
    f16* g1b = (f16*)(ws + 8 * MB);          // 8-24

    // ---- phase 1: norm + fused QKV (64-tile, 1536 blocks) ----
    transconv_k<<<dim3(DMODEL / 64, DMODEL / 64), 256, 0, stream>>>(wq, wqkvt, DMODEL, DMODEL);
    transconv_k<<<dim3(DMODEL / 64, DMODEL / 64), 256, 0, stream>>>(wk, wqkvt + 1024 * 1024, DMODEL, DMODEL);
    transconv_k<<<dim3(DMODEL / 64, DMODEL / 64), 256, 0, stream>>>(wv, wqkvt + 2 * 1024 * 1024, DMODEL, DMODEL);
    rmsnormf_k<<<SEQ, 256, 0, stream>>>(x, attn_norm_w, nxb);
    gemm64_k<<<dim3(3 * DMODEL / 64, SEQ / 64), 256, 0, stream>>>(
        nxb, wqkvt, nullptr, qf, SEQ, 3 * DMODEL, DMODEL, 2, kf, vb);
    copelogits_k<<<SEQ, 256, 0, stream>>>(qf, pos_emb, li);
    tv_k<<<dim3(SEQ / 64, NH), 256, 0, stream>>>((const ushort_t*)vb, (ushort_t*)vt);

    // ---- phase 2: attention chunks ----
    for (int ch = 0; ch < NCH; ch++) {
        int cb = ch * CHUNK;
        scoresm_k<<<dim3(SEQ / 64, CHUNK / 64, NH), 256, 0, stream>>>(qf, kf, sc, cb);
        cope_k<<<CHUNK, 1024, 0, stream>>>(sc, li, mlp_w1, mlp_b1, mlp_w2, mlp_b2, cb);
        pvm_k<<<dim3(CHUNK / 32, NH), 256, 0, stream>>>(sc, (const ushort_t*)vt, aob, cb);
    }

    // ---- phase B: out @ wo + x (64-tile, 512 blocks) ----
    transconv_k<<<dim3(DMODEL / 64, DMODEL / 64), 256, 0, stream>>>(wo, wot, DMODEL, DMODEL);
    gemm64_k<<<dim3(DMODEL / 64, SEQ / 64), 256, 0, stream>>>(
        aob, wot, x, x1, SEQ, DMODEL, DMODEL, 0, nullptr, nullptr);

    // ---- phase C: FFN ----
    rmsnormf_k<<<SEQ, 256, 0, stream>>>(x1, ffn_norm_w, nxb2);
    transconv2_k<<<dim3(FFDIM / 64, DMODEL / 64), 256, 0, stream>>>(ffn_w1, ffn_w3, w13t, DMODEL, FFDIM);
    transconv_k<<<dim3(DMODEL / 64, FFDIM / 64), 256, 0, stream>>>(ffn_w2, w2t, FFDIM, DMODEL);
    gemm128_k<<<dim3(2 * FFDIM / 128, SEQ / 128), 256, 0, stream>>>(
        nxb2, w13t, nullptr, g1b, SEQ, 2 * FFDIM, DMODEL, 4);
    gemm64_k<<<dim3(DMODEL / 64, SEQ / 64), 256, 0, stream>>>(
        g1b, w2t, x1, out, SEQ, DMODEL, FFDIM, 0, nullptr, nullptr);
}

// Round 13
// 494.078 us; speedup vs baseline: 8.0130x; 1.0319x over previous
//
#include <hip/hip_runtime.h>
#include <hip/hip_bf16.h>
#include <hip/hip_fp16.h>
#include <math.h>

#define SEQ 2048
#define DMODEL 1024
#define NH 16
#define DHEAD 64
#define FFDIM 4096
#define NPOSE 128
#define MLPWID 32
#define EPSV 1e-5f
#define CHUNK 1024
#define NCH (SEQ / CHUNK)

typedef unsigned short ushort_t;
typedef unsigned int uint_t;
typedef _Float16 f16;
typedef __attribute__((ext_vector_type(8))) _Float16 f16x8;
typedef __attribute__((ext_vector_type(4))) float f32x4;

union HF8 { f16x8 v; f16 h[8]; ushort_t s[8]; uint2 u2[2]; uint4 u4; };
union U1H2 { uint_t u; f16 h[2]; };
union U2H4 { uint2 u; f16 h[4]; };

__device__ __forceinline__ float sigm(float x) {
    return 1.0f / (1.0f + __expf(-x));
}
__device__ __forceinline__ void gl_lds16(const void* g, void* l) {
    __builtin_amdgcn_global_load_lds((const __attribute__((address_space(1))) uint_t*)g,
                                     (__attribute__((address_space(3))) uint_t*)l, 16, 0, 0);
}

// ---------------- RMSNorm, f16 out ----------------
__global__ __launch_bounds__(256) void rmsnormf_k(const float* __restrict__ x,
                                                  const float* __restrict__ w,
                                                  f16* __restrict__ o) {
    int row = blockIdx.x;
    int tid = threadIdx.x;
    const float4* xr = (const float4*)(x + (size_t)row * DMODEL);
    float4 v = xr[tid];
    float ss = v.x * v.x + v.y * v.y + v.z * v.z + v.w * v.w;
#pragma unroll
    for (int d = 1; d < 64; d <<= 1) ss += __shfl_xor(ss, d, 64);
    __shared__ float red[4];
    int lane = tid & 63, wv = tid >> 6;
    if (lane == 0) red[wv] = ss;
    __syncthreads();
    float tot = red[0] + red[1] + red[2] + red[3];
    float r = rsqrtf(tot / (float)DMODEL + EPSV);
    const float4* wr = (const float4*)w;
    float4 wv4 = wr[tid];
    U2H4 ob;
    ob.h[0] = (f16)(v.x * r * wv4.x);
    ob.h[1] = (f16)(v.y * r * wv4.y);
    ob.h[2] = (f16)(v.z * r * wv4.z);
    ob.h[3] = (f16)(v.w * r * wv4.w);
    ((uint2*)(o + (size_t)row * DMODEL))[tid] = ob.u;
}

// ---------------- V transpose (bit copy): vb[SEQ][DMODEL] -> vt[NH][DHEAD][SEQ] ----------------
__global__ __launch_bounds__(256) void tv_k(const ushort_t* __restrict__ vb,
                                            ushort_t* __restrict__ vt) {
    int h = blockIdx.y, t0 = blockIdx.x * 64;
    __shared__ ushort_t T[64][76];
    int tid = threadIdx.x;
#pragma unroll
    for (int it = 0; it < 2; it++) {
        int a = tid + it * 256;
        int t = a >> 3, c8 = (a & 7) * 8;
        HF8 v;
        v.u4 = *(const uint4*)(vb + (size_t)(t0 + t) * DMODEL + h * 64 + c8);
#pragma unroll
        for (int j = 0; j < 8; j++) T[c8 + j][t] = v.s[j];
    }
    __syncthreads();
#pragma unroll
    for (int it = 0; it < 2; it++) {
        int a = tid + it * 256;
        int d = a >> 3, c8 = (a & 7) * 8;
        HF8 o;
#pragma unroll
        for (int j = 0; j < 8; j++) o.s[j] = T[d][c8 + j];
        *(uint4*)(vt + ((size_t)h * 64 + d) * SEQ + t0 + c8) = o.u4;
    }
}

// ---------------- weight transpose+convert: f32[K][N] -> f16[N][K] ----------------
__global__ __launch_bounds__(256) void transconv_k(const float* __restrict__ in,
                                                   f16* __restrict__ out,
                                                   int K, int N) {
    __shared__ f16 T[64][72];
    int k0 = blockIdx.y * 64, n0 = blockIdx.x * 64;
    int tid = threadIdx.x;
    int r = tid >> 4, c4 = (tid & 15) * 4;
#pragma unroll
    for (int i = 0; i < 4; i++) {
        float4 v = *(const float4*)(in + (size_t)(k0 + r + i * 16) * N + n0 + c4);
        T[c4 + 0][r + i * 16] = (f16)v.x;
        T[c4 + 1][r + i * 16] = (f16)v.y;
        T[c4 + 2][r + i * 16] = (f16)v.z;
        T[c4 + 3][r + i * 16] = (f16)v.w;
    }
    __syncthreads();
    int n = tid >> 2, kk = (tid & 3) * 16;
    uint4* dst = (uint4*)(out + (size_t)(n0 + n) * K + k0 + kk);
    dst[0] = *(const uint4*)&T[n][kk];
    dst[1] = *(const uint4*)&T[n][kk + 8];
}

// ---------------- w1/w3 transpose+convert, row-interleaved (16-col groups) ----------------
__global__ __launch_bounds__(256) void transconv2_k(const float* __restrict__ w1,
                                                    const float* __restrict__ w3,
                                                    f16* __restrict__ out,
                                                    int K, int N) {
    __shared__ f16 T[64][72];
    int k0 = blockIdx.y * 64, n0 = blockIdx.x * 64;
    int tid = threadIdx.x;
    int r = tid >> 4, c4 = (tid & 15) * 4;
    int n = tid >> 2, kk = (tid & 3) * 16;
#pragma unroll
    for (int half = 0; half < 2; half++) {
        const float* in = half ? w3 : w1;
#pragma unroll
        for (int i = 0; i < 4; i++) {
            float4 v = *(const float4*)(in + (size_t)(k0 + r + i * 16) * N + n0 + c4);
            T[c4 + 0][r + i * 16] = (f16)v.x;
            T[c4 + 1][r + i * 16] = (f16)v.y;
            T[c4 + 2][r + i * 16] = (f16)v.z;
            T[c4 + 3][r + i * 16] = (f16)v.w;
        }
        __syncthreads();
        int gc = n0 + n;
        int rp = (gc >> 4) * 32 + (gc & 15) + half * 16;
        uint4* dst = (uint4*)(out + (size_t)rp * K + k0 + kk);
        dst[0] = *(const uint4*)&T[n][kk];
        dst[1] = *(const uint4*)&T[n][kk + 8];
        __syncthreads();
    }
}

// ---------------- f16 MFMA GEMM 128x128 (TN), XCD-swizzled ----------------
// mode 0: f32 out (+add). mode 1: f16 out. mode 4: w1w3-interleaved silu-mul.
__global__ __launch_bounds__(256) void gemm128_k(const f16* __restrict__ A,
                                                 const f16* __restrict__ Bt,
                                                 const float* __restrict__ add,
                                                 void* __restrict__ Cout,
                                                 int M, int N, int K, int mode) {
    __shared__ f16 Al[128 * 32];
    __shared__ f16 Bl[128 * 32];
    int tid = threadIdx.x;
    int lane = tid & 63, wave = tid >> 6;
    int gx = gridDim.x, gy = gridDim.y;
    int nwg = gx * gy;
    int bx = blockIdx.x, by = blockIdx.y;
    if ((nwg & 7) == 0) {
        int flat = by * gx + bx;
        int cpx = nwg >> 3;
        int l = (flat & 7) * cpx + (flat >> 3);
        bx = l / gy;
        by = l % gy;
    }
    int brow = by * 128, bcol = bx * 128;
    int wr = (wave >> 1) * 64, wc = (wave & 1) * 64;
    f32x4 acc[4][4];
#pragma unroll
    for (int m = 0; m < 4; m++)
#pragma unroll
        for (int n = 0; n < 4; n++) acc[m][n] = (f32x4){0.f, 0.f, 0.f, 0.f};

    const f16* Ag = A + (size_t)(brow + (tid >> 2)) * K + (tid & 3) * 8;
    const f16* Bg = Bt + (size_t)(bcol + (tid >> 2)) * K + (tid & 3) * 8;
    f16* Ald = &Al[wave * 512];
    f16* Bld = &Bl[wave * 512];
    size_t rstep = (size_t)64 * K;

    for (int k0 = 0; k0 < K; k0 += 32) {
        gl_lds16(Ag + k0, Ald);
        gl_lds16(Ag + k0 + rstep, Ald + 2048);
        gl_lds16(Bg + k0, Bld);
        gl_lds16(Bg + k0 + rstep, Bld + 2048);
        __syncthreads();
        f16x8 af[4], bfr[4];
        int arow = wr + (lane & 15);
        int brw = wc + (lane & 15);
        int kof = (lane >> 4) * 8;
#pragma unroll
        for (int m = 0; m < 4; m++) af[m] = *(const f16x8*)&Al[(arow + m * 16) * 32 + kof];
#pragma unroll
        for (int n = 0; n < 4; n++) bfr[n] = *(const f16x8*)&Bl[(brw + n * 16) * 32 + kof];
#pragma unroll
        for (int m = 0; m < 4; m++)
#pragma unroll
            for (int n = 0; n < 4; n++)
                acc[m][n] = __builtin_amdgcn_mfma_f32_16x16x32_f16(af[m], bfr[n], acc[m][n], 0, 0, 0);
        __syncthreads();
    }
    int crow0 = brow + wr + (lane >> 4) * 4;
    int ccol = bcol + wc + (lane & 15);
#pragma unroll
    for (int m = 0; m < 4; m++)
#pragma unroll
        for (int j = 0; j < 4; j++) {
            int row = crow0 + m * 16 + j;
            if (mode == 4) {
#pragma unroll
                for (int n = 0; n < 4; n += 2) {
                    int c = ccol + n * 16;
                    int colOut = (c >> 5) * 16 + (c & 15);
                    float v1 = acc[m][n][j];
                    float v3 = acc[m][n + 1][j];
                    ((f16*)Cout)[(size_t)row * (N / 2) + colOut] =
                        (f16)(v1 * sigm(v1) * v3);
                }
            } else {
#pragma unroll
                for (int n = 0; n < 4; n++) {
                    int col = ccol + n * 16;
                    float v = acc[m][n][j];
                    if (mode == 0) {
                        if (add) v += add[(size_t)row * N + col];
                        ((float*)Cout)[(size_t)row * N + col] = v;
                    } else {
                        ((f16*)Cout)[(size_t)row * N + col] = (f16)v;
                    }
                }
            }
        }
}

// ---------------- f16 MFMA GEMM 64x64 (TN), XCD-swizzled ----------------
// mode 0: f32 out (+add). mode 1: f16. mode 2: qkv split (Cout=q, p2=k, p3=v).
__global__ __launch_bounds__(256) void gemm64_k(const f16* __restrict__ A,
                                                const f16* __restrict__ Bt,
                                                const float* __restrict__ add,
                                                void* __restrict__ Cout,
                                                int M, int N, int K, int mode,
                                                f16* __restrict__ p2,
                                                f16* __restrict__ p3) {
    __shared__ f16 Al[64 * 32];
    __shared__ f16 Bl[64 * 32];
    int tid = threadIdx.x;
    int lane = tid & 63, wave = tid >> 6;
    int gx = gridDim.x, gy = gridDim.y;
    int nwg = gx * gy;
    int bx = blockIdx.x, by = blockIdx.y;
    if ((nwg & 7) == 0) {
        int flat = by * gx + bx;
        int cpx = nwg >> 3;
        int l = (flat & 7) * cpx + (flat >> 3);
        bx = l / gy;
        by = l % gy;
    }
    int brow = by * 64, bcol = bx * 64;
    int wr = (wave >> 1) * 32, wc = (wave & 1) * 32;
    f32x4 acc[2][2];
#pragma unroll
    for (int m = 0; m < 2; m++)
#pragma unroll
        for (int n = 0; n < 2; n++) acc[m][n] = (f32x4){0.f, 0.f, 0.f, 0.f};

    const f16* Ag = A + (size_t)(brow + (tid >> 2)) * K + (tid & 3) * 8;
    const f16* Bg = Bt + (size_t)(bcol + (tid >> 2)) * K + (tid & 3) * 8;
    f16* Ald = &Al[wave * 512];
    f16* Bld = &Bl[wave * 512];

    for (int k0 = 0; k0 < K; k0 += 32) {
        gl_lds16(Ag + k0, Ald);
        gl_lds16(Bg + k0, Bld);
        __syncthreads();
        f16x8 af[2], bfr[2];
        int kof = (lane >> 4) * 8;
#pragma unroll
        for (int m = 0; m < 2; m++)
            af[m] = *(const f16x8*)&Al[(wr + m * 16 + (lane & 15)) * 32 + kof];
#pragma unroll
        for (int n = 0; n < 2; n++)
            bfr[n] = *(const f16x8*)&Bl[(wc + n * 16 + (lane & 15)) * 32 + kof];
#pragma unroll
        for (int m = 0; m < 2; m++)
#pragma unroll
            for (int n = 0; n < 2; n++)
                acc[m][n] = __builtin_amdgcn_mfma_f32_16x16x32_f16(af[m], bfr[n], acc[m][n], 0, 0, 0);
        __syncthreads();
    }
    int crow0 = brow + wr + (lane >> 4) * 4;
    int ccol = bcol + wc + (lane & 15);
#pragma unroll
    for (int m = 0; m < 2; m++)
#pragma unroll
        for (int j = 0; j < 4; j++) {
            int row = crow0 + m * 16 + j;
#pragma unroll
            for (int n = 0; n < 2; n++) {
                int col = ccol + n * 16;
                float v = acc[m][n][j];
                if (mode == 0) {
                    if (add) v += add[(size_t)row * N + col];
                    ((float*)Cout)[(size_t)row * N + col] = v;
                } else if (mode == 1) {
                    ((f16*)Cout)[(size_t)row * N + col] = (f16)v;
                } else {
                    size_t o = (size_t)row * DMODEL;
                    if (col < DMODEL) ((f16*)Cout)[o + col] = (f16)v;
                    else if (col < 2 * DMODEL) p2[o + col - DMODEL] = (f16)v;
                    else p3[o + col - 2 * DMODEL] = (f16)v;
                }
            }
        }
}

// ---------------- MFMA scores: sc[h][il][j] = qf_i . kf_j / 8 ----------------
__global__ __launch_bounds__(256) void scoresm_k(const f16* __restrict__ qf,
                                                 const f16* __restrict__ kf,
                                                 f16* __restrict__ sc, int cb) {
    int h = blockIdx.z;
    int il0 = blockIdx.y * 64;
    int j0 = blockIdx.x * 64;
    __shared__ f16 Qf[64][72];
    __shared__ f16 Kf[64][72];
    int tid = threadIdx.x;
    {
        int r = tid >> 2, c0 = (tid & 3) * 16;
        const f16* p;
        p = qf + (size_t)(cb + il0 + r) * DMODEL + h * 64 + c0;
        *(uint4*)&Qf[r][c0] = *(const uint4*)p;
        *(uint4*)&Qf[r][c0 + 8] = *(const uint4*)(p + 8);
        p = kf + (size_t)(j0 + r) * DMODEL + h * 64 + c0;
        *(uint4*)&Kf[r][c0] = *(const uint4*)p;
        *(uint4*)&Kf[r][c0 + 8] = *(const uint4*)(p + 8);
    }
    __syncthreads();
    int lane = tid & 63, wave = tid >> 6;
    int wr = (wave >> 1) * 32, wc = (wave & 1) * 32;
    f32x4 acc[2][2];
#pragma unroll
    for (int m = 0; m < 2; m++)
#pragma unroll
        for (int n = 0; n < 2; n++) acc[m][n] = (f32x4){0.f, 0.f, 0.f, 0.f};
#pragma unroll
    for (int ks = 0; ks < 2; ks++) {
        int kof = ks * 32 + (lane >> 4) * 8;
        f16x8 aQ[2], bK[2];
#pragma unroll
        for (int m = 0; m < 2; m++)
            aQ[m] = *(const f16x8*)&Qf[wr + m * 16 + (lane & 15)][kof];
#pragma unroll
        for (int n = 0; n < 2; n++)
            bK[n] = *(const f16x8*)&Kf[wc + n * 16 + (lane & 15)][kof];
#pragma unroll
        for (int m = 0; m < 2; m++)
#pragma unroll
            for (int n = 0; n < 2; n++)
                acc[m][n] = __builtin_amdgcn_mfma_f32_16x16x32_f16(aQ[m], bK[n], acc[m][n], 0, 0, 0);
    }
#pragma unroll
    for (int m = 0; m < 2; m++)
#pragma unroll
        for (int j = 0; j < 4; j++) {
            int il = il0 + wr + m * 16 + (lane >> 4) * 4 + j;
#pragma unroll
            for (int n = 0; n < 2; n++) {
                int jj = j0 + wc + n * 16 + (lane & 15);
                sc[((size_t)h * CHUNK + il) * SEQ + jj] = (f16)(acc[m][n][j] * 0.125f);
            }
        }
}

// ---------------- logits_int -> f16 (reads qf) ----------------
__global__ __launch_bounds__(256) void copelogits_k(const f16* __restrict__ qf,
                                                    const float* __restrict__ pe,
                                                    f16* __restrict__ li) {
    int s1 = blockIdx.x;
    int tid = threadIdx.x;
    __shared__ float PE[DHEAD * NPOSE];
    __shared__ float QR[DMODEL];
    for (int i = tid; i < DHEAD * NPOSE; i += 256) PE[i] = pe[i];
    for (int i = tid; i < DMODEL; i += 256) QR[i] = (float)qf[(size_t)s1 * DMODEL + i];
    __syncthreads();
#pragma unroll
    for (int j = 0; j < 8; j++) {
        int o = j * 256 + tid;
        int h = o >> 7, n = o & 127;
        const float* qhp = &QR[h * DHEAD];
        float acc = 0.0f;
#pragma unroll 8
        for (int d = 0; d < DHEAD; d++) acc += qhp[d] * PE[d * NPOSE + n];
        li[(size_t)s1 * (NH * NPOSE) + o] = (f16)acc;
    }
}

// ---------------- fused CoPE: reg-prefetch scan + bias + f16 MFMA MLP + softmax -> P ----------------
#define CSTR 2052
__global__ __launch_bounds__(1024, 1) void cope_k(f16* __restrict__ sc,
                                                  const f16* __restrict__ li,
                                                  const float* __restrict__ w1,
                                                  const float* __restrict__ b1,
                                                  const float* __restrict__ w2,
                                                  const float* __restrict__ b2,
                                                  int cb) {
    __shared__ f16 C[32 * CSTR];           // 131328 B
    __shared__ uint_t Lif2[NH * 130];      // 8320 B: packed (li[n], li[n+1])
    __shared__ f16 HMB[16][16 * 36];       // 18432 B -> 158080 total
    int r = blockIdx.x;
    int tid = threadIdx.x;
    int lane = tid & 63, wv = tid >> 6;    // wv in 0..15; wave wv owns head wv

    // prefetch own head's score row into registers (4 x uint4 = 32 f16)
    const f16* srow = sc + ((size_t)wv * CHUNK + r) * SEQ;
    HF8 rv[4];
#pragma unroll
    for (int c = 0; c < 4; c++) rv[c].u4 = *(const uint4*)&srow[c * 512 + lane * 8];

    // per-wave Lif2 staging (own head only -> no cross-wave barrier needed)
    {
        const f16* lh = li + (size_t)(cb + r) * (NH * NPOSE) + wv * NPOSE;
#pragma unroll
        for (int e = 0; e < 2; e++) {
            int n = lane + e * 64;
            U1H2 pk;
            pk.h[0] = lh[n];
            pk.h[1] = lh[(n < NPOSE - 1) ? n + 1 : NPOSE - 1];
            Lif2[wv * 130 + n] = pk.u;
        }
    }

    // suffix scan + bias interp (8 positions/lane, 4 chunks right-to-left);
    // writes score row + bias row into LDS as a side effect.
    {
        f16* crow = &C[wv * CSTR];
        f16* brow = &C[(16 + wv) * CSTR];
        const uint_t* lrow = &Lif2[wv * 130];
        float carry = 0.0f;
        for (int c = 3; c >= 0; c--) {
            HF8 sv = rv[c];
            float g[8];
            float S = 0.0f;
#pragma unroll
            for (int e = 0; e < 8; e++) {
                g[e] = sigm((float)sv.h[e]);
                S += g[e];
            }
#pragma unroll
            for (int dd = 1; dd < 64; dd <<= 1) {
                float o = __shfl_down(S, dd, 64);
                S = (lane + dd < 64) ? S + o : S;
            }
            float total = __shfl(S, 0, 64);
            float p = S + carry;
            carry += total;
            HF8 bo;
#pragma unroll
            for (int e = 0; e < 8; e++) {
                float pos = fminf(p, 127.0f);
                int fl = (int)pos;
                float fr = pos - (float)fl;
                U1H2 lv;
                lv.u = lrow[fl];
                float lf = (float)lv.h[0];
                bo.h[e] = (f16)(lf + ((float)lv.h[1] - lf) * fr);
                p -= g[e];
            }
            int t = c * 512 + lane * 8;
            *(uint4*)&crow[t] = sv.u4;
            *(uint4*)&brow[t] = bo.u4;
        }
    }
    __syncthreads();

    // MLP weight fragments (f16)
    int fkg = lane >> 4;
    int fc = lane & 15;
    HF8 w1f[2], w2f;
    float b1v[2], b2v;
#pragma unroll
    for (int half = 0; half < 2; half++) {
#pragma unroll
        for (int j = 0; j < 8; j++)
            w1f[half].h[j] = (f16)w1[(fkg * 8 + j) * MLPWID + half * 16 + fc];
        b1v[half] = b1[half * 16 + fc];
    }
#pragma unroll
    for (int j = 0; j < 8; j++) w2f.h[j] = (f16)w2[(fkg * 8 + j) * NH + fc];
    b2v = b2[fc];

    // f16 MFMA MLP over t-tiles of 16; wave wv does tiles wv, wv+16, ... (8 tiles)
    f16* hmb = HMB[wv];
    for (int tt = wv; tt < SEQ / 16; tt += 16) {
        int t0 = tt * 16;
        HF8 af;
#pragma unroll
        for (int j = 0; j < 8; j++) af.h[j] = C[(fkg * 8 + j) * CSTR + t0 + fc];
        f32x4 acc0 = (f32x4){b1v[0], b1v[0], b1v[0], b1v[0]};
        f32x4 acc1 = (f32x4){b1v[1], b1v[1], b1v[1], b1v[1]};
        acc0 = __builtin_amdgcn_mfma_f32_16x16x32_f16(af.v, w1f[0].v, acc0, 0, 0, 0);
        acc1 = __builtin_amdgcn_mfma_f32_16x16x32_f16(af.v, w1f[1].v, acc1, 0, 0, 0);
#pragma unroll
        for (int j2 = 0; j2 < 4; j2++) {
            int p = fkg * 4 + j2;
            float h0 = acc0[j2]; h0 = h0 * sigm(h0);
            float h1 = acc1[j2]; h1 = h1 * sigm(h1);
            hmb[p * 36 + fc] = (f16)h0;
            hmb[p * 36 + 16 + fc] = (f16)h1;
        }
        HF8 hf;
        hf.u2[0] = *(const uint2*)&hmb[fc * 36 + fkg * 8];
        hf.u2[1] = *(const uint2*)&hmb[fc * 36 + fkg * 8 + 4];
        f32x4 acc2 = (f32x4){b2v, b2v, b2v, b2v};
        acc2 = __builtin_amdgcn_mfma_f32_16x16x32_f16(hf.v, w2f.v, acc2, 0, 0, 0);
#pragma unroll
        for (int j2 = 0; j2 < 4; j2 += 2) {
            uint_t* pp = (uint_t*)&C[fc * CSTR + t0 + fkg * 4 + j2];
            U1H2 old, neu;
            old.u = *pp;
            neu.h[0] = (f16)((float)old.h[0] + acc2[j2]);
            neu.h[1] = (f16)((float)old.h[1] + acc2[j2 + 1]);
            *pp = neu.u;
        }
    }
    __syncthreads();

    // fused softmax: wave wv -> head wv; write normalized P (f16, uint4) to global
    {
        const f16* row = &C[wv * CSTR];
        float vals[32];
        float m = -1e30f;
#pragma unroll
        for (int c = 0; c < 4; c++) {
            HF8 sv;
            sv.u4 = *(const uint4*)&row[c * 512 + lane * 8];
#pragma unroll
            for (int e = 0; e < 8; e++) {
                vals[c * 8 + e] = (float)sv.h[e];
                m = fmaxf(m, vals[c * 8 + e]);
            }
        }
#pragma unroll
        for (int d = 1; d < 64; d <<= 1) m = fmaxf(m, __shfl_xor(m, d, 64));
        float s = 0.0f;
#pragma unroll
        for (int c = 0; c < 32; c++) {
            vals[c] = __expf(vals[c] - m);
            s += vals[c];
        }
#pragma unroll
        for (int d = 1; d < 64; d <<= 1) s += __shfl_xor(s, d, 64);
        float ri = 1.0f / s;
        f16* dst = sc + ((size_t)wv * CHUNK + r) * SEQ;
#pragma unroll
        for (int c = 0; c < 4; c++) {
            HF8 po;
#pragma unroll
            for (int e = 0; e < 8; e++) po.h[e] = (f16)(vals[c * 8 + e] * ri);
            *(uint4*)&dst[c * 512 + lane * 8] = po.u4;
        }
    }
}

// ---------------- f16 MFMA PV (P normalized) -> aob f16 ----------------
__global__ __launch_bounds__(256) void pvm_k(const f16* __restrict__ scP,
                                             const ushort_t* __restrict__ vt,
                                             f16* __restrict__ aob, int cb) {
    int h = blockIdx.y;
    int s0 = blockIdx.x * 32;
    __shared__ f16 P[32][72];
    __shared__ f16 Vt[64][72];
    int tid = threadIdx.x;
    int lane = tid & 63, wave = tid >> 6;
    int wr = (wave >> 1) * 16, wc = (wave & 1) * 32;
    f32x4 acc[2];
    acc[0] = (f32x4){0.f, 0.f, 0.f, 0.f};
    acc[1] = (f32x4){0.f, 0.f, 0.f, 0.f};
    int pr = tid >> 3, pc = (tid & 7) * 8;
    int vr = tid >> 2, vc = (tid & 3) * 16;
    for (int t0 = 0; t0 < SEQ; t0 += 64) {
        {
            *(uint4*)&P[pr][pc] =
                *(const uint4*)(scP + ((size_t)h * CHUNK + s0 + pr) * SEQ + t0 + pc);
            const ushort_t* vp = vt + ((size_t)h * 64 + vr) * SEQ + t0 + vc;
            *(uint4*)&Vt[vr][vc] = *(const uint4*)vp;
            *(uint4*)&Vt[vr][vc + 8] = *(const uint4*)(vp + 8);
        }
        __syncthreads();
#pragma unroll
        for (int ks = 0; ks < 2; ks++) {
            int kof = ks * 32 + (lane >> 4) * 8;
            f16x8 pa = *(const f16x8*)&P[wr + (lane & 15)][kof];
#pragma unroll
            for (int n = 0; n < 2; n++) {
                f16x8 vb = *(const f16x8*)&Vt[wc + n * 16 + (lane & 15)][kof];
                acc[n] = __builtin_amdgcn_mfma_f32_16x16x32_f16(pa, vb, acc[n], 0, 0, 0);
            }
        }
        __syncthreads();
    }
#pragma unroll
    for (int j = 0; j < 4; j++) {
        int s = cb + s0 + wr + (lane >> 4) * 4 + j;
#pragma unroll
        for (int n = 0; n < 2; n++) {
            int d = h * 64 + wc + n * 16 + (lane & 15);
            aob[(size_t)s * DMODEL + d] = (f16)acc[n][j];
        }
    }
}

extern "C" void kernel_launch(void* const* d_in, const int* in_sizes, int n_in,
                              void* d_out, int out_size, void* d_ws, size_t ws_size,
                              hipStream_t stream) {
    const float* x = (const float*)d_in[0];
    const float* wq = (const float*)d_in[1];
    const float* wk = (const float*)d_in[2];
    const float* wv = (const float*)d_in[3];
    const float* wo = (const float*)d_in[4];
    const float* pos_emb = (const float*)d_in[5];
    const float* mlp_w1 = (const float*)d_in[6];
    const float* mlp_b1 = (const float*)d_in[7];
    const float* mlp_w2 = (const float*)d_in[8];
    const float* mlp_b2 = (const float*)d_in[9];
    const float* ffn_w1 = (const float*)d_in[10];
    const float* ffn_w2 = (const float*)d_in[11];
    const float* ffn_w3 = (const float*)d_in[12];
    const float* attn_norm_w = (const float*)d_in[13];
    const float* ffn_norm_w = (const float*)d_in[14];
    float* out = (float*)d_out;

    char* ws = (char*)d_ws;
    const size_t MB = 1024 * 1024;
    f16* nxb = (f16*)(ws + 0);               // 0-4
    f16* qf = (f16*)(ws + 4 * MB);           // 4-8   (phase C: nxb2)
    f16* kf = (f16*)(ws + 8 * MB);           // 8-12  (phase C: g1b 8-24)
    f16* vb = (f16*)(ws + 12 * MB);          // 12-16
    f16* vt = (f16*)(ws + 16 * MB);          // 16-20
    f16* li = (f16*)(ws + 20 * MB);          // 20-28
    f16* aob = (f16*)(ws + 28 * MB);         // 28-32
    float* x1 = (float*)(ws + 32 * MB);      // 32-40
    f16* wqkvt = (f16*)(ws + 40 * MB);       // 40-46 (phase 1)
    f16* sc = (f16*)(ws + 40 * MB);          // 40-104 (phase 2, CHUNK=1024)
    f16* wot = (f16*)(ws + 40 * MB);         // 40-42 (phase B)
    f16* w13t = (f16*)(ws + 40 * MB);        // 40-56 (phase C, interleaved)
    f16* w2t = (f16*)(ws + 56 * MB);         // 56-64
    f16* nxb2 = (f16*)(ws + 4 * MB);
    f16* g1b = (f16*)(ws + 8 * MB);          // 8-24

    // ---- phase 1: norm + fused QKV (64-tile, 1536 blocks) ----
    transconv_k<<<dim3(DMODEL / 64, DMODEL / 64), 256, 0, stream>>>(wq, wqkvt, DMODEL, DMODEL);
    transconv_k<<<dim3(DMODEL / 64, DMODEL / 64), 256, 0, stream>>>(wk, wqkvt + 1024 * 1024, DMODEL, DMODEL);
    transconv_k<<<dim3(DMODEL / 64, DMODEL / 64), 256, 0, stream>>>(wv, wqkvt + 2 * 1024 * 1024, DMODEL, DMODEL);
    rmsnormf_k<<<SEQ, 256, 0, stream>>>(x, attn_norm_w, nxb);
    gemm64_k<<<dim3(3 * DMODEL / 64, SEQ / 64), 256, 0, stream>>>(
        nxb, wqkvt, nullptr, qf, SEQ, 3 * DMODEL, DMODEL, 2, kf, vb);
    copelogits_k<<<SEQ, 256, 0, stream>>>(qf, pos_emb, li);
    tv_k<<<dim3(SEQ / 64, NH), 256, 0, stream>>>((const ushort_t*)vb, (ushort_t*)vt);

    // ---- phase 2: attention chunks ----
    for (int ch = 0; ch < NCH; ch++) {
        int cb = ch * CHUNK;
        scoresm_k<<<dim3(SEQ / 64, CHUNK / 64, NH), 256, 0, stream>>>(qf, kf, sc, cb);
        cope_k<<<CHUNK, 1024, 0, stream>>>(sc, li, mlp_w1, mlp_b1, mlp_w2, mlp_b2, cb);
        pvm_k<<<dim3(CHUNK / 32, NH), 256, 0, stream>>>(sc, (const ushort_t*)vt, aob, cb);
    }

    // ---- phase B: out @ wo + x (64-tile, 512 blocks) ----
    transconv_k<<<dim3(DMODEL / 64, DMODEL / 64), 256, 0, stream>>>(wo, wot, DMODEL, DMODEL);
    gemm64_k<<<dim3(DMODEL / 64, SEQ / 64), 256, 0, stream>>>(
        aob, wot, x, x1, SEQ, DMODEL, DMODEL, 0, nullptr, nullptr);

    // ---- phase C: FFN ----
    rmsnormf_k<<<SEQ, 256, 0, stream>>>(x1, ffn_norm_w, nxb2);
    transconv2_k<<<dim3(FFDIM / 64, DMODEL / 64), 256, 0, stream>>>(ffn_w1, ffn_w3, w13t, DMODEL, FFDIM);
    transconv_k<<<dim3(DMODEL / 64, FFDIM / 64), 256, 0, stream>>>(ffn_w2, w2t, FFDIM, DMODEL);
    gemm128_k<<<dim3(2 * FFDIM / 128, SEQ / 128), 256, 0, stream>>>(
        nxb2, w13t, nullptr, g1b, SEQ, 2 * FFDIM, DMODEL, 4);
    gemm64_k<<<dim3(DMODEL / 64, SEQ / 64), 256, 0, stream>>>(
        g1b, w2t, x1, out, SEQ, DMODEL, FFDIM, 0, nullptr, nullptr);
}

// Round 14
// 446.601 us; speedup vs baseline: 8.8648x; 1.1063x over previous
//
#include <hip/hip_runtime.h>
#include <hip/hip_bf16.h>
#include <hip/hip_fp16.h>
#include <math.h>

#define SEQ 2048
#define DMODEL 1024
#define NH 16
#define DHEAD 64
#define FFDIM 4096
#define NPOSE 128
#define MLPWID 32
#define EPSV 1e-5f
#define CHUNK 1024
#define NCH (SEQ / CHUNK)

typedef unsigned short ushort_t;
typedef unsigned int uint_t;
typedef _Float16 f16;
typedef __attribute__((ext_vector_type(8))) _Float16 f16x8;
typedef __attribute__((ext_vector_type(4))) float f32x4;

union HF8 { f16x8 v; f16 h[8]; ushort_t s[8]; uint2 u2[2]; uint4 u4; };
union U1H2 { uint_t u; f16 h[2]; };
union U2H4 { uint2 u; f16 h[4]; };

__device__ __forceinline__ float sigm(float x) {
    // v_rcp_f32 (+-1 ulp) instead of the correctly-rounded div sequence (~9 ops)
    return __builtin_amdgcn_rcpf(1.0f + __expf(-x));
}
__device__ __forceinline__ void gl_lds16(const void* g, void* l) {
    __builtin_amdgcn_global_load_lds((const __attribute__((address_space(1))) uint_t*)g,
                                     (__attribute__((address_space(3))) uint_t*)l, 16, 0, 0);
}

// ---------------- RMSNorm, f16 out ----------------
__global__ __launch_bounds__(256) void rmsnormf_k(const float* __restrict__ x,
                                                  const float* __restrict__ w,
                                                  f16* __restrict__ o) {
    int row = blockIdx.x;
    int tid = threadIdx.x;
    const float4* xr = (const float4*)(x + (size_t)row * DMODEL);
    float4 v = xr[tid];
    float ss = v.x * v.x + v.y * v.y + v.z * v.z + v.w * v.w;
#pragma unroll
    for (int d = 1; d < 64; d <<= 1) ss += __shfl_xor(ss, d, 64);
    __shared__ float red[4];
    int lane = tid & 63, wv = tid >> 6;
    if (lane == 0) red[wv] = ss;
    __syncthreads();
    float tot = red[0] + red[1] + red[2] + red[3];
    float r = rsqrtf(tot / (float)DMODEL + EPSV);
    const float4* wr = (const float4*)w;
    float4 wv4 = wr[tid];
    U2H4 ob;
    ob.h[0] = (f16)(v.x * r * wv4.x);
    ob.h[1] = (f16)(v.y * r * wv4.y);
    ob.h[2] = (f16)(v.z * r * wv4.z);
    ob.h[3] = (f16)(v.w * r * wv4.w);
    ((uint2*)(o + (size_t)row * DMODEL))[tid] = ob.u;
}

// ---------------- V transpose (bit copy): vb[SEQ][DMODEL] -> vt[NH][DHEAD][SEQ] ----------------
__global__ __launch_bounds__(256) void tv_k(const ushort_t* __restrict__ vb,
                                            ushort_t* __restrict__ vt) {
    int h = blockIdx.y, t0 = blockIdx.x * 64;
    __shared__ ushort_t T[64][76];
    int tid = threadIdx.x;
#pragma unroll
    for (int it = 0; it < 2; it++) {
        int a = tid + it * 256;
        int t = a >> 3, c8 = (a & 7) * 8;
        HF8 v;
        v.u4 = *(const uint4*)(vb + (size_t)(t0 + t) * DMODEL + h * 64 + c8);
#pragma unroll
        for (int j = 0; j < 8; j++) T[c8 + j][t] = v.s[j];
    }
    __syncthreads();
#pragma unroll
    for (int it = 0; it < 2; it++) {
        int a = tid + it * 256;
        int d = a >> 3, c8 = (a & 7) * 8;
        HF8 o;
#pragma unroll
        for (int j = 0; j < 8; j++) o.s[j] = T[d][c8 + j];
        *(uint4*)(vt + ((size_t)h * 64 + d) * SEQ + t0 + c8) = o.u4;
    }
}

// ---------------- weight transpose+convert: f32[K][N] -> f16[N][K] ----------------
__global__ __launch_bounds__(256) void transconv_k(const float* __restrict__ in,
                                                   f16* __restrict__ out,
                                                   int K, int N) {
    __shared__ f16 T[64][72];
    int k0 = blockIdx.y * 64, n0 = blockIdx.x * 64;
    int tid = threadIdx.x;
    int r = tid >> 4, c4 = (tid & 15) * 4;
#pragma unroll
    for (int i = 0; i < 4; i++) {
        float4 v = *(const float4*)(in + (size_t)(k0 + r + i * 16) * N + n0 + c4);
        T[c4 + 0][r + i * 16] = (f16)v.x;
        T[c4 + 1][r + i * 16] = (f16)v.y;
        T[c4 + 2][r + i * 16] = (f16)v.z;
        T[c4 + 3][r + i * 16] = (f16)v.w;
    }
    __syncthreads();
    int n = tid >> 2, kk = (tid & 3) * 16;
    uint4* dst = (uint4*)(out + (size_t)(n0 + n) * K + k0 + kk);
    dst[0] = *(const uint4*)&T[n][kk];
    dst[1] = *(const uint4*)&T[n][kk + 8];
}

// ---------------- w1/w3 transpose+convert, row-interleaved (16-col groups) ----------------
__global__ __launch_bounds__(256) void transconv2_k(const float* __restrict__ w1,
                                                    const float* __restrict__ w3,
                                                    f16* __restrict__ out,
                                                    int K, int N) {
    __shared__ f16 T[64][72];
    int k0 = blockIdx.y * 64, n0 = blockIdx.x * 64;
    int tid = threadIdx.x;
    int r = tid >> 4, c4 = (tid & 15) * 4;
    int n = tid >> 2, kk = (tid & 3) * 16;
#pragma unroll
    for (int half = 0; half < 2; half++) {
        const float* in = half ? w3 : w1;
#pragma unroll
        for (int i = 0; i < 4; i++) {
            float4 v = *(const float4*)(in + (size_t)(k0 + r + i * 16) * N + n0 + c4);
            T[c4 + 0][r + i * 16] = (f16)v.x;
            T[c4 + 1][r + i * 16] = (f16)v.y;
            T[c4 + 2][r + i * 16] = (f16)v.z;
            T[c4 + 3][r + i * 16] = (f16)v.w;
        }
        __syncthreads();
        int gc = n0 + n;
        int rp = (gc >> 4) * 32 + (gc & 15) + half * 16;
        uint4* dst = (uint4*)(out + (size_t)rp * K + k0 + kk);
        dst[0] = *(const uint4*)&T[n][kk];
        dst[1] = *(const uint4*)&T[n][kk + 8];
        __syncthreads();
    }
}

// ---------------- f16 MFMA GEMM 128x128 (TN), XCD-swizzled ----------------
// mode 0: f32 out (+add). mode 1: f16 out. mode 4: w1w3-interleaved silu-mul.
__global__ __launch_bounds__(256) void gemm128_k(const f16* __restrict__ A,
                                                 const f16* __restrict__ Bt,
                                                 const float* __restrict__ add,
                                                 void* __restrict__ Cout,
                                                 int M, int N, int K, int mode) {
    __shared__ f16 Al[128 * 32];
    __shared__ f16 Bl[128 * 32];
    int tid = threadIdx.x;
    int lane = tid & 63, wave = tid >> 6;
    int gx = gridDim.x, gy = gridDim.y;
    int nwg = gx * gy;
    int bx = blockIdx.x, by = blockIdx.y;
    if ((nwg & 7) == 0) {
        int flat = by * gx + bx;
        int cpx = nwg >> 3;
        int l = (flat & 7) * cpx + (flat >> 3);
        bx = l / gy;
        by = l % gy;
    }
    int brow = by * 128, bcol = bx * 128;
    int wr = (wave >> 1) * 64, wc = (wave & 1) * 64;
    f32x4 acc[4][4];
#pragma unroll
    for (int m = 0; m < 4; m++)
#pragma unroll
        for (int n = 0; n < 4; n++) acc[m][n] = (f32x4){0.f, 0.f, 0.f, 0.f};

    const f16* Ag = A + (size_t)(brow + (tid >> 2)) * K + (tid & 3) * 8;
    const f16* Bg = Bt + (size_t)(bcol + (tid >> 2)) * K + (tid & 3) * 8;
    f16* Ald = &Al[wave * 512];
    f16* Bld = &Bl[wave * 512];
    size_t rstep = (size_t)64 * K;

    for (int k0 = 0; k0 < K; k0 += 32) {
        gl_lds16(Ag + k0, Ald);
        gl_lds16(Ag + k0 + rstep, Ald + 2048);
        gl_lds16(Bg + k0, Bld);
        gl_lds16(Bg + k0 + rstep, Bld + 2048);
        __syncthreads();
        f16x8 af[4], bfr[4];
        int arow = wr + (lane & 15);
        int brw = wc + (lane & 15);
        int kof = (lane >> 4) * 8;
#pragma unroll
        for (int m = 0; m < 4; m++) af[m] = *(const f16x8*)&Al[(arow + m * 16) * 32 + kof];
#pragma unroll
        for (int n = 0; n < 4; n++) bfr[n] = *(const f16x8*)&Bl[(brw + n * 16) * 32 + kof];
#pragma unroll
        for (int m = 0; m < 4; m++)
#pragma unroll
            for (int n = 0; n < 4; n++)
                acc[m][n] = __builtin_amdgcn_mfma_f32_16x16x32_f16(af[m], bfr[n], acc[m][n], 0, 0, 0);
        __syncthreads();
    }
    int crow0 = brow + wr + (lane >> 4) * 4;
    int ccol = bcol + wc + (lane & 15);
#pragma unroll
    for (int m = 0; m < 4; m++)
#pragma unroll
        for (int j = 0; j < 4; j++) {
            int row = crow0 + m * 16 + j;
            if (mode == 4) {
#pragma unroll
                for (int n = 0; n < 4; n += 2) {
                    int c = ccol + n * 16;
                    int colOut = (c >> 5) * 16 + (c & 15);
                    float v1 = acc[m][n][j];
                    float v3 = acc[m][n + 1][j];
                    ((f16*)Cout)[(size_t)row * (N / 2) + colOut] =
                        (f16)(v1 * sigm(v1) * v3);
                }
            } else {
#pragma unroll
                for (int n = 0; n < 4; n++) {
                    int col = ccol + n * 16;
                    float v = acc[m][n][j];
                    if (mode == 0) {
                        if (add) v += add[(size_t)row * N + col];
                        ((float*)Cout)[(size_t)row * N + col] = v;
                    } else {
                        ((f16*)Cout)[(size_t)row * N + col] = (f16)v;
                    }
                }
            }
        }
}

// ---------------- f16 MFMA GEMM 64x64 (TN), XCD-swizzled ----------------
// mode 0: f32 out (+add). mode 1: f16. mode 2: qkv split (Cout=q, p2=k, p3=v).
__global__ __launch_bounds__(256) void gemm64_k(const f16* __restrict__ A,
                                                const f16* __restrict__ Bt,
                                                const float* __restrict__ add,
                                                void* __restrict__ Cout,
                                                int M, int N, int K, int mode,
                                                f16* __restrict__ p2,
                                                f16* __restrict__ p3) {
    __shared__ f16 Al[64 * 32];
    __shared__ f16 Bl[64 * 32];
    int tid = threadIdx.x;
    int lane = tid & 63, wave = tid >> 6;
    int gx = gridDim.x, gy = gridDim.y;
    int nwg = gx * gy;
    int bx = blockIdx.x, by = blockIdx.y;
    if ((nwg & 7) == 0) {
        int flat = by * gx + bx;
        int cpx = nwg >> 3;
        int l = (flat & 7) * cpx + (flat >> 3);
        bx = l / gy;
        by = l % gy;
    }
    int brow = by * 64, bcol = bx * 64;
    int wr = (wave >> 1) * 32, wc = (wave & 1) * 32;
    f32x4 acc[2][2];
#pragma unroll
    for (int m = 0; m < 2; m++)
#pragma unroll
        for (int n = 0; n < 2; n++) acc[m][n] = (f32x4){0.f, 0.f, 0.f, 0.f};

    const f16* Ag = A + (size_t)(brow + (tid >> 2)) * K + (tid & 3) * 8;
    const f16* Bg = Bt + (size_t)(bcol + (tid >> 2)) * K + (tid & 3) * 8;
    f16* Ald = &Al[wave * 512];
    f16* Bld = &Bl[wave * 512];

    for (int k0 = 0; k0 < K; k0 += 32) {
        gl_lds16(Ag + k0, Ald);
        gl_lds16(Bg + k0, Bld);
        __syncthreads();
        f16x8 af[2], bfr[2];
        int kof = (lane >> 4) * 8;
#pragma unroll
        for (int m = 0; m < 2; m++)
            af[m] = *(const f16x8*)&Al[(wr + m * 16 + (lane & 15)) * 32 + kof];
#pragma unroll
        for (int n = 0; n < 2; n++)
            bfr[n] = *(const f16x8*)&Bl[(wc + n * 16 + (lane & 15)) * 32 + kof];
#pragma unroll
        for (int m = 0; m < 2; m++)
#pragma unroll
            for (int n = 0; n < 2; n++)
                acc[m][n] = __builtin_amdgcn_mfma_f32_16x16x32_f16(af[m], bfr[n], acc[m][n], 0, 0, 0);
        __syncthreads();
    }
    int crow0 = brow + wr + (lane >> 4) * 4;
    int ccol = bcol + wc + (lane & 15);
#pragma unroll
    for (int m = 0; m < 2; m++)
#pragma unroll
        for (int j = 0; j < 4; j++) {
            int row = crow0 + m * 16 + j;
#pragma unroll
            for (int n = 0; n < 2; n++) {
                int col = ccol + n * 16;
                float v = acc[m][n][j];
                if (mode == 0) {
                    if (add) v += add[(size_t)row * N + col];
                    ((float*)Cout)[(size_t)row * N + col] = v;
                } else if (mode == 1) {
                    ((f16*)Cout)[(size_t)row * N + col] = (f16)v;
                } else {
                    size_t o = (size_t)row * DMODEL;
                    if (col < DMODEL) ((f16*)Cout)[o + col] = (f16)v;
                    else if (col < 2 * DMODEL) p2[o + col - DMODEL] = (f16)v;
                    else p3[o + col - 2 * DMODEL] = (f16)v;
                }
            }
        }
}

// ---------------- MFMA scores: sc[h][il][j] = qf_i . kf_j / 8 ----------------
__global__ __launch_bounds__(256) void scoresm_k(const f16* __restrict__ qf,
                                                 const f16* __restrict__ kf,
                                                 f16* __restrict__ sc, int cb) {
    int h = blockIdx.z;
    int il0 = blockIdx.y * 64;
    int j0 = blockIdx.x * 64;
    __shared__ f16 Qf[64][72];
    __shared__ f16 Kf[64][72];
    int tid = threadIdx.x;
    {
        int r = tid >> 2, c0 = (tid & 3) * 16;
        const f16* p;
        p = qf + (size_t)(cb + il0 + r) * DMODEL + h * 64 + c0;
        *(uint4*)&Qf[r][c0] = *(const uint4*)p;
        *(uint4*)&Qf[r][c0 + 8] = *(const uint4*)(p + 8);
        p = kf + (size_t)(j0 + r) * DMODEL + h * 64 + c0;
        *(uint4*)&Kf[r][c0] = *(const uint4*)p;
        *(uint4*)&Kf[r][c0 + 8] = *(const uint4*)(p + 8);
    }
    __syncthreads();
    int lane = tid & 63, wave = tid >> 6;
    int wr = (wave >> 1) * 32, wc = (wave & 1) * 32;
    f32x4 acc[2][2];
#pragma unroll
    for (int m = 0; m < 2; m++)
#pragma unroll
        for (int n = 0; n < 2; n++) acc[m][n] = (f32x4){0.f, 0.f, 0.f, 0.f};
#pragma unroll
    for (int ks = 0; ks < 2; ks++) {
        int kof = ks * 32 + (lane >> 4) * 8;
        f16x8 aQ[2], bK[2];
#pragma unroll
        for (int m = 0; m < 2; m++)
            aQ[m] = *(const f16x8*)&Qf[wr + m * 16 + (lane & 15)][kof];
#pragma unroll
        for (int n = 0; n < 2; n++)
            bK[n] = *(const f16x8*)&Kf[wc + n * 16 + (lane & 15)][kof];
#pragma unroll
        for (int m = 0; m < 2; m++)
#pragma unroll
            for (int n = 0; n < 2; n++)
                acc[m][n] = __builtin_amdgcn_mfma_f32_16x16x32_f16(aQ[m], bK[n], acc[m][n], 0, 0, 0);
    }
#pragma unroll
    for (int m = 0; m < 2; m++)
#pragma unroll
        for (int j = 0; j < 4; j++) {
            int il = il0 + wr + m * 16 + (lane >> 4) * 4 + j;
#pragma unroll
            for (int n = 0; n < 2; n++) {
                int jj = j0 + wc + n * 16 + (lane & 15);
                sc[((size_t)h * CHUNK + il) * SEQ + jj] = (f16)(acc[m][n][j] * 0.125f);
            }
        }
}

// ---------------- logits_int -> f16 (reads qf) ----------------
__global__ __launch_bounds__(256) void copelogits_k(const f16* __restrict__ qf,
                                                    const float* __restrict__ pe,
                                                    f16* __restrict__ li) {
    int s1 = blockIdx.x;
    int tid = threadIdx.x;
    __shared__ float PE[DHEAD * NPOSE];
    __shared__ float QR[DMODEL];
    for (int i = tid; i < DHEAD * NPOSE; i += 256) PE[i] = pe[i];
    for (int i = tid; i < DMODEL; i += 256) QR[i] = (float)qf[(size_t)s1 * DMODEL + i];
    __syncthreads();
#pragma unroll
    for (int j = 0; j < 8; j++) {
        int o = j * 256 + tid;
        int h = o >> 7, n = o & 127;
        const float* qhp = &QR[h * DHEAD];
        float acc = 0.0f;
#pragma unroll 8
        for (int d = 0; d < DHEAD; d++) acc += qhp[d] * PE[d * NPOSE + n];
        li[(size_t)s1 * (NH * NPOSE) + o] = (f16)acc;
    }
}

// ---------------- fused CoPE: reg-prefetch scan + bias + f16 MFMA MLP + softmax -> P ----------------
#define CSTR 2052
__global__ __launch_bounds__(1024, 1) void cope_k(f16* __restrict__ sc,
                                                  const f16* __restrict__ li,
                                                  const float* __restrict__ w1,
                                                  const float* __restrict__ b1,
                                                  const float* __restrict__ w2,
                                                  const float* __restrict__ b2,
                                                  int cb) {
    __shared__ f16 C[32 * CSTR];           // 131328 B
    __shared__ uint_t Lif2[NH * 130];      // 8320 B: packed (li[n], li[n+1])
    __shared__ f16 HMB[16][16 * 36];       // 18432 B -> 158080 total
    int r = blockIdx.x;
    int tid = threadIdx.x;
    int lane = tid & 63, wv = tid >> 6;    // wv in 0..15; wave wv owns head wv

    // prefetch own head's score row into registers (4 x uint4 = 32 f16)
    const f16* srow = sc + ((size_t)wv * CHUNK + r) * SEQ;
    HF8 rv[4];
#pragma unroll
    for (int c = 0; c < 4; c++) rv[c].u4 = *(const uint4*)&srow[c * 512 + lane * 8];

    // per-wave Lif2 staging (own head only -> no cross-wave barrier needed)
    {
        const f16* lh = li + (size_t)(cb + r) * (NH * NPOSE) + wv * NPOSE;
#pragma unroll
        for (int e = 0; e < 2; e++) {
            int n = lane + e * 64;
            U1H2 pk;
            pk.h[0] = lh[n];
            pk.h[1] = lh[(n < NPOSE - 1) ? n + 1 : NPOSE - 1];
            Lif2[wv * 130 + n] = pk.u;
        }
    }

    // suffix scan + bias interp (8 positions/lane, 4 chunks right-to-left);
    // writes score row + bias row into LDS as a side effect.
    {
        f16* crow = &C[wv * CSTR];
        f16* brow = &C[(16 + wv) * CSTR];
        const uint_t* lrow = &Lif2[wv * 130];
        float carry = 0.0f;
        for (int c = 3; c >= 0; c--) {
            HF8 sv = rv[c];
            float g[8];
            float S = 0.0f;
#pragma unroll
            for (int e = 0; e < 8; e++) {
                g[e] = sigm((float)sv.h[e]);
                S += g[e];
            }
#pragma unroll
            for (int dd = 1; dd < 64; dd <<= 1) {
                float o = __shfl_down(S, dd, 64);
                S = (lane + dd < 64) ? S + o : S;
            }
            float total = __shfl(S, 0, 64);
            float p = S + carry;
            carry += total;
            HF8 bo;
#pragma unroll
            for (int e = 0; e < 8; e++) {
                float pos = fminf(p, 127.0f);
                int fl = (int)pos;
                float fr = pos - (float)fl;
                U1H2 lv;
                lv.u = lrow[fl];
                float lf = (float)lv.h[0];
                bo.h[e] = (f16)(lf + ((float)lv.h[1] - lf) * fr);
                p -= g[e];
            }
            int t = c * 512 + lane * 8;
            *(uint4*)&crow[t] = sv.u4;
            *(uint4*)&brow[t] = bo.u4;
        }
    }
    __syncthreads();

    // MLP weight fragments (f16)
    int fkg = lane >> 4;
    int fc = lane & 15;
    HF8 w1f[2], w2f;
    float b1v[2], b2v;
#pragma unroll
    for (int half = 0; half < 2; half++) {
#pragma unroll
        for (int j = 0; j < 8; j++)
            w1f[half].h[j] = (f16)w1[(fkg * 8 + j) * MLPWID + half * 16 + fc];
        b1v[half] = b1[half * 16 + fc];
    }
#pragma unroll
    for (int j = 0; j < 8; j++) w2f.h[j] = (f16)w2[(fkg * 8 + j) * NH + fc];
    b2v = b2[fc];

    // f16 MFMA MLP over t-tiles of 16; wave wv does tiles wv, wv+16, ... (8 tiles)
    f16* hmb = HMB[wv];
    for (int tt = wv; tt < SEQ / 16; tt += 16) {
        int t0 = tt * 16;
        HF8 af;
#pragma unroll
        for (int j = 0; j < 8; j++) af.h[j] = C[(fkg * 8 + j) * CSTR + t0 + fc];
        f32x4 acc0 = (f32x4){b1v[0], b1v[0], b1v[0], b1v[0]};
        f32x4 acc1 = (f32x4){b1v[1], b1v[1], b1v[1], b1v[1]};
        acc0 = __builtin_amdgcn_mfma_f32_16x16x32_f16(af.v, w1f[0].v, acc0, 0, 0, 0);
        acc1 = __builtin_amdgcn_mfma_f32_16x16x32_f16(af.v, w1f[1].v, acc1, 0, 0, 0);
#pragma unroll
        for (int j2 = 0; j2 < 4; j2++) {
            int p = fkg * 4 + j2;
            float h0 = acc0[j2]; h0 = h0 * sigm(h0);
            float h1 = acc1[j2]; h1 = h1 * sigm(h1);
            hmb[p * 36 + fc] = (f16)h0;
            hmb[p * 36 + 16 + fc] = (f16)h1;
        }
        HF8 hf;
        hf.u2[0] = *(const uint2*)&hmb[fc * 36 + fkg * 8];
        hf.u2[1] = *(const uint2*)&hmb[fc * 36 + fkg * 8 + 4];
        f32x4 acc2 = (f32x4){b2v, b2v, b2v, b2v};
        acc2 = __builtin_amdgcn_mfma_f32_16x16x32_f16(hf.v, w2f.v, acc2, 0, 0, 0);
#pragma unroll
        for (int j2 = 0; j2 < 4; j2 += 2) {
            uint_t* pp = (uint_t*)&C[fc * CSTR + t0 + fkg * 4 + j2];
            U1H2 old, neu;
            old.u = *pp;
            neu.h[0] = (f16)((float)old.h[0] + acc2[j2]);
            neu.h[1] = (f16)((float)old.h[1] + acc2[j2 + 1]);
            *pp = neu.u;
        }
    }
    __syncthreads();

    // fused softmax: wave wv -> head wv; write normalized P (f16, uint4) to global
    {
        const f16* row = &C[wv * CSTR];
        float vals[32];
        float m = -1e30f;
#pragma unroll
        for (int c = 0; c < 4; c++) {
            HF8 sv;
            sv.u4 = *(const uint4*)&row[c * 512 + lane * 8];
#pragma unroll
            for (int e = 0; e < 8; e++) {
                vals[c * 8 + e] = (float)sv.h[e];
                m = fmaxf(m, vals[c * 8 + e]);
            }
        }
#pragma unroll
        for (int d = 1; d < 64; d <<= 1) m = fmaxf(m, __shfl_xor(m, d, 64));
        float s = 0.0f;
#pragma unroll
        for (int c = 0; c < 32; c++) {
            vals[c] = __expf(vals[c] - m);
            s += vals[c];
        }
#pragma unroll
        for (int d = 1; d < 64; d <<= 1) s += __shfl_xor(s, d, 64);
        float ri = __builtin_amdgcn_rcpf(s);
        f16* dst = sc + ((size_t)wv * CHUNK + r) * SEQ;
#pragma unroll
        for (int c = 0; c < 4; c++) {
            HF8 po;
#pragma unroll
            for (int e = 0; e < 8; e++) po.h[e] = (f16)(vals[c * 8 + e] * ri);
            *(uint4*)&dst[c * 512 + lane * 8] = po.u4;
        }
    }
}

// ---------------- f16 MFMA PV (P normalized) -> aob f16 ----------------
__global__ __launch_bounds__(256) void pvm_k(const f16* __restrict__ scP,
                                             const ushort_t* __restrict__ vt,
                                             f16* __restrict__ aob, int cb) {
    int h = blockIdx.y;
    int s0 = blockIdx.x * 32;
    __shared__ f16 P[32][72];
    __shared__ f16 Vt[64][72];
    int tid = threadIdx.x;
    int lane = tid & 63, wave = tid >> 6;
    int wr = (wave >> 1) * 16, wc = (wave & 1) * 32;
    f32x4 acc[2];
    acc[0] = (f32x4){0.f, 0.f, 0.f, 0.f};
    acc[1] = (f32x4){0.f, 0.f, 0.f, 0.f};
    int pr = tid >> 3, pc = (tid & 7) * 8;
    int vr = tid >> 2, vc = (tid & 3) * 16;
    for (int t0 = 0; t0 < SEQ; t0 += 64) {
        {
            *(uint4*)&P[pr][pc] =
                *(const uint4*)(scP + ((size_t)h * CHUNK + s0 + pr) * SEQ + t0 + pc);
            const ushort_t* vp = vt + ((size_t)h * 64 + vr) * SEQ + t0 + vc;
            *(uint4*)&Vt[vr][vc] = *(const uint4*)vp;
            *(uint4*)&Vt[vr][vc + 8] = *(const uint4*)(vp + 8);
        }
        __syncthreads();
#pragma unroll
        for (int ks = 0; ks < 2; ks++) {
            int kof = ks * 32 + (lane >> 4) * 8;
            f16x8 pa = *(const f16x8*)&P[wr + (lane & 15)][kof];
#pragma unroll
            for (int n = 0; n < 2; n++) {
                f16x8 vb = *(const f16x8*)&Vt[wc + n * 16 + (lane & 15)][kof];
                acc[n] = __builtin_amdgcn_mfma_f32_16x16x32_f16(pa, vb, acc[n], 0, 0, 0);
            }
        }
        __syncthreads();
    }
#pragma unroll
    for (int j = 0; j < 4; j++) {
        int s = cb + s0 + wr + (lane >> 4) * 4 + j;
#pragma unroll
        for (int n = 0; n < 2; n++) {
            int d = h * 64 + wc + n * 16 + (lane & 15);
            aob[(size_t)s * DMODEL + d] = (f16)acc[n][j];
        }
    }
}

extern "C" void kernel_launch(void* const* d_in, const int* in_sizes, int n_in,
                              void* d_out, int out_size, void* d_ws, size_t ws_size,
                              hipStream_t stream) {
    const float* x = (const float*)d_in[0];
    const float* wq = (const float*)d_in[1];
    const float* wk = (const float*)d_in[2];
    const float* wv = (const float*)d_in[3];
    const float* wo = (const float*)d_in[4];
    const float* pos_emb = (const float*)d_in[5];
    const float* mlp_w1 = (const float*)d_in[6];
    const float* mlp_b1 = (const float*)d_in[7];
    const float* mlp_w2 = (const float*)d_in[8];
    const float* mlp_b2 = (const float*)d_in[9];
    const float* ffn_w1 = (const float*)d_in[10];
    const float* ffn_w2 = (const float*)d_in[11];
    const float* ffn_w3 = (const float*)d_in[12];
    const float* attn_norm_w = (const float*)d_in[13];
    const float* ffn_norm_w = (const float*)d_in[14];
    float* out = (float*)d_out;

    char* ws = (char*)d_ws;
    const size_t MB = 1024 * 1024;
    f16* nxb = (f16*)(ws + 0);               // 0-4
    f16* qf = (f16*)(ws + 4 * MB);           // 4-8   (phase C: nxb2)
    f16* kf = (f16*)(ws + 8 * MB);           // 8-12  (phase C: g1b 8-24)
    f16* vb = (f16*)(ws + 12 * MB);          // 12-16
    f16* vt = (f16*)(ws + 16 * MB);          // 16-20
    f16* li = (f16*)(ws + 20 * MB);          // 20-28
    f16* aob = (f16*)(ws + 28 * MB);         // 28-32
    float* x1 = (float*)(ws + 32 * MB);      // 32-40
    f16* wqkvt = (f16*)(ws + 40 * MB);       // 40-46 (phase 1)
    f16* sc = (f16*)(ws + 40 * MB);          // 40-104 (phase 2, CHUNK=1024)
    f16* wot = (f16*)(ws + 40 * MB);         // 40-42 (phase B)
    f16* w13t = (f16*)(ws + 40 * MB);        // 40-56 (phase C, interleaved)
    f16* w2t = (f16*)(ws + 56 * MB);         // 56-64
    f16* nxb2 = (f16*)(ws + 4 * MB);
    f16* g1b = (f16*)(ws + 8 * MB);          // 8-24

    // ---- phase 1: norm + fused QKV (64-tile, 1536 blocks) ----
    transconv_k<<<dim3(DMODEL / 64, DMODEL / 64), 256, 0, stream>>>(wq, wqkvt, DMODEL, DMODEL);
    transconv_k<<<dim3(DMODEL / 64, DMODEL / 64), 256, 0, stream>>>(wk, wqkvt + 1024 * 1024, DMODEL, DMODEL);
    transconv_k<<<dim3(DMODEL / 64, DMODEL / 64), 256, 0, stream>>>(wv, wqkvt + 2 * 1024 * 1024, DMODEL, DMODEL);
    rmsnormf_k<<<SEQ, 256, 0, stream>>>(x, attn_norm_w, nxb);
    gemm64_k<<<dim3(3 * DMODEL / 64, SEQ / 64), 256, 0, stream>>>(
        nxb, wqkvt, nullptr, qf, SEQ, 3 * DMODEL, DMODEL, 2, kf, vb);
    copelogits_k<<<SEQ, 256, 0, stream>>>(qf, pos_emb, li);
    tv_k<<<dim3(SEQ / 64, NH), 256, 0, stream>>>((const ushort_t*)vb, (ushort_t*)vt);

    // ---- phase 2: attention chunks ----
    for (int ch = 0; ch < NCH; ch++) {
        int cb = ch * CHUNK;
        scoresm_k<<<dim3(SEQ / 64, CHUNK / 64, NH), 256, 0, stream>>>(qf, kf, sc, cb);
        cope_k<<<CHUNK, 1024, 0, stream>>>(sc, li, mlp_w1, mlp_b1, mlp_w2, mlp_b2, cb);
        pvm_k<<<dim3(CHUNK / 32, NH), 256, 0, stream>>>(sc, (const ushort_t*)vt, aob, cb);
    }

    // ---- phase B: out @ wo + x (64-tile, 512 blocks) ----
    transconv_k<<<dim3(DMODEL / 64, DMODEL / 64), 256, 0, stream>>>(wo, wot, DMODEL, DMODEL);
    gemm64_k<<<dim3(DMODEL / 64, SEQ / 64), 256, 0, stream>>>(
        aob, wot, x, x1, SEQ, DMODEL, DMODEL, 0, nullptr, nullptr);

    // ---- phase C: FFN ----
    rmsnormf_k<<<SEQ, 256, 0, stream>>>(x1, ffn_norm_w, nxb2);
    transconv2_k<<<dim3(FFDIM / 64, DMODEL / 64), 256, 0, stream>>>(ffn_w1, ffn_w3, w13t, DMODEL, FFDIM);
    transconv_k<<<dim3(DMODEL / 64, FFDIM / 64), 256, 0, stream>>>(ffn_w2, w2t, FFDIM, DMODEL);
    gemm128_k<<<dim3(2 * FFDIM / 128, SEQ / 128), 256, 0, stream>>>(
        nxb2, w13t, nullptr, g1b, SEQ, 2 * FFDIM, DMODEL, 4);
    gemm64_k<<<dim3(DMODEL / 64, SEQ / 64), 256, 0, stream>>>(
        g1b, w2t, x1, out, SEQ, DMODEL, FFDIM, 0, nullptr, nullptr);
}